// Round 6
// baseline (453.831 us; speedup 1.0000x reference)
//
#include <hip/hip_runtime.h>
#include <hip/hip_bf16.h>
#include <math.h>

#define E_EDGES 131072
#define NN1 8192
#define NN2 6560          // 16*410
#define NG 16
#define NP1 512
#define KP1 410
#define KP2 205
#define F1 1536
#define EMB 512
#define MAXDEG 256

typedef __hip_bfloat16 bf16;
typedef __attribute__((ext_vector_type(8))) short short8;
typedef __attribute__((ext_vector_type(4))) float f32x4;
typedef __attribute__((ext_vector_type(4))) unsigned short us4;

__device__ inline float wred64(float v){
  #pragma unroll
  for (int o = 32; o; o >>= 1) v += __shfl_down(v, o);
  return v;
}
__device__ inline float b2f_raw(unsigned short u){
  return __uint_as_float((unsigned)u << 16);
}
union BFU { bf16 b; unsigned short u; };
__device__ inline unsigned short f2u(float v){ BFU x; x.b = __float2bfloat16(v); return x.u; }

__device__ __forceinline__ void gld16(const void* g, void* l){
  __builtin_amdgcn_global_load_lds(
      (const __attribute__((address_space(1))) void*)g,
      (__attribute__((address_space(3))) void*)l, 16, 0, 0);
}

__device__ inline void split_store(float v, bf16* __restrict__ ph, bf16* __restrict__ pl){
  bf16 hi = __float2bfloat16(v);
  *ph = hi;
  *pl = __float2bfloat16(v - __bfloat162float(hi));
}

// inline BN stats from raw sums
__device__ inline void bn_from_acc(const float* __restrict__ bnacc, int c, float fM,
                                   float& mean, float& inv){
  mean = bnacc[c] / fM;
  float var = fmaxf(bnacc[512+c]/fM - mean*mean, 0.f);
  inv = 1.f / sqrtf(var + 1e-5f);
}

// order-preserving float->uint key for atomicMax
__device__ inline unsigned fkey(float v){
  unsigned u = __float_as_uint(v);
  return (u & 0x80000000u) ? ~u : (u | 0x80000000u);
}
__device__ inline float fkey_inv(unsigned k){
  return (k & 0x80000000u) ? __uint_as_float(k & 0x7fffffffu) : __uint_as_float(~k);
}

// ======================= mega precompute =======================
// [0,24): M1 partials  [24,56): cvec partials  [56,152): watt2
// [152,170): watt1     [170,236): init (bnacc zero / cnt2=1 / map=-1)
// [236,428): gemm_s 64x64 split-bf16 MFMA tiles (W2@Wh2 -> M2T split)
__global__ __launch_bounds__(256) void k_pre(
    const float* __restrict__ W1, const float* __restrict__ as1, const float* __restrict__ ad1,
    const float* __restrict__ Wh1, const float* __restrict__ bc1, const float* __restrict__ bh1,
    const float* __restrict__ W2, const float* __restrict__ as2, const float* __restrict__ ad2,
    const float* __restrict__ Wh2, const float* __restrict__ bc2, const float* __restrict__ bh2,
    float* __restrict__ was1, float* __restrict__ wad1, float* __restrict__ M1p,
    float* __restrict__ cvp,
    float* __restrict__ was2, float* __restrict__ wad2,
    float* __restrict__ Zb, int* __restrict__ cnt2, int* __restrict__ map,
    bf16* __restrict__ Th, bf16* __restrict__ Tl){
  int b = blockIdx.x, t = threadIdx.x;
  if (b < 24){                               // M1 partials
    int h = b / 8, rem = b % 8, jh = rem >> 2, kc = rem & 3;
    int j = jh*256 + t, c0 = kc*128;
    __shared__ float w1s[3][128];
    for (int i = t; i < 384; i += 256)
      w1s[i>>7][i&127] = W1[(i>>7)*1536 + h*512 + c0 + (i&127)];
    __syncthreads();
    const float* whc = Wh1 + (size_t)(h*512 + c0)*512 + j;
    float a0=0.f, a1=0.f, a2=0.f;
    #pragma unroll 8
    for (int c = 0; c < 128; c++){
      float v = whc[(size_t)c*512];
      a0 += w1s[0][c]*v; a1 += w1s[1][c]*v; a2 += w1s[2][c]*v;
    }
    float* dst = M1p + (size_t)kc*4608;
    dst[(h*3+0)*512 + j] = a0;
    dst[(h*3+1)*512 + j] = a1;
    dst[(h*3+2)*512 + j] = a2;
  } else if (b < 56){                        // cvec partials
    int b2 = b - 24;
    int which = b2 >> 4, rem = b2 & 15, jh = rem >> 3, kc = rem & 7;
    const float* bc = which ? bc2 : bc1;
    const float* Wh = which ? Wh2 : Wh1;
    const float* bh = which ? bh2 : bh1;
    int j = jh*256 + t, i0 = kc*192;
    float acc = (kc == 0) ? bh[j] : 0.f;
    #pragma unroll 8
    for (int i = 0; i < 192; i++)
      acc += bc[i0+i] * Wh[(size_t)(i0+i)*512 + j];
    cvp[(size_t)(which*8 + kc)*512 + j] = acc;
  } else if (b < 152){                       // watt2
    int b3 = b - 56;
    int y = b3 >> 4, et = b3 & 15;
    int kind = y / 3, h = y % 3;
    int w = t >> 6, lane = t & 63;
    const float* att = kind ? ad2 : as2;
    float a[8];
    #pragma unroll
    for (int u = 0; u < 8; u++) a[u] = att[h*512 + lane*8 + u];
    for (int r = w; r < 32; r += 4){
      int e = et*32 + r;
      const float4* row = (const float4*)(W2 + (size_t)e*1536 + h*512) + lane*2;
      float4 v0 = row[0], v1 = row[1];
      float d = v0.x*a[0]+v0.y*a[1]+v0.z*a[2]+v0.w*a[3]
              + v1.x*a[4]+v1.y*a[5]+v1.z*a[6]+v1.w*a[7];
      d = wred64(d);
      if (lane == 0) (kind ? wad2 : was2)[h*512 + e] = d;
    }
  } else if (b < 170){                       // watt1
    if (t < 64){
      int bb = b - 152;
      int kind = bb / 9, r = bb % 9, h = r / 3, f = r % 3;
      const float* att = kind ? ad1 : as1;
      float s = 0.f;
      for (int c = t; c < 512; c += 64) s += W1[f*1536 + h*512 + c] * att[h*512 + c];
      s = wred64(s);
      if (t == 0) (kind ? wad1 : was1)[h*3 + f] = s;
    }
  } else if (b < 236){                       // init
    int i = (b - 170)*256 + t;
    if (i < 2048){ Zb[i] = 0.f; }                         // bnacc1|bnacc
    else if (i < 2048 + NN2){ cnt2[i - 2048] = 1; }
    else if (i < 2048 + NN2 + NN1){ map[i - 2048 - NN2] = -1; }
  } else {                                   // gemm_s tiles
    int bb = b - 236;
    int z = bb % 3; int rr = bb / 3; int by = rr >> 3, bx = rr & 7;
    const float* A = W2 + (size_t)z*512;            // row stride 1536
    const float* B = Wh2 + (size_t)z*512*512;       // row stride 512
    __shared__ __align__(16) short sAh[4096], sAl[4096], sBh[4096], sBl[4096];
    int w = t >> 6, lane = t & 63;
    int l16 = lane & 15, q = lane >> 4;
    int bm = by*64, bn = bx*64;
    int am  = t >> 2, akw = (t & 3)*16;
    int bnl = t & 63, bkq = (t >> 6)*16;
    f32x4 acc[4];
    #pragma unroll
    for (int nf = 0; nf < 4; nf++) acc[nf] = (f32x4){0.f,0.f,0.f,0.f};
    float va[16], vb[16];
    #define GS_LOAD(K0) do { \
      _Pragma("unroll") for (int u = 0; u < 4; u++){ \
        float4 v4 = *(const float4*)(A + (size_t)(bm+am)*1536 + (K0) + akw + u*4); \
        va[u*4]=v4.x; va[u*4+1]=v4.y; va[u*4+2]=v4.z; va[u*4+3]=v4.w; } \
      _Pragma("unroll") for (int u = 0; u < 16; u++) \
        vb[u] = B[(size_t)((K0) + bkq + u)*512 + bn + bnl]; \
    } while(0)
    GS_LOAD(0);
    for (int it = 0; it < 8; it++){
      #pragma unroll
      for (int hh = 0; hh < 2; hh++){
        short8 ah_, al_, bh_, bl_;
        #pragma unroll
        for (int jj = 0; jj < 8; jj++){
          float v = va[hh*8+jj];
          unsigned short hu = f2u(v);
          ah_[jj] = (short)hu; al_[jj] = (short)f2u(v - b2f_raw(hu));
          v = vb[hh*8+jj];
          hu = f2u(v);
          bh_[jj] = (short)hu; bl_[jj] = (short)f2u(v - b2f_raw(hu));
        }
        int aoff = am*64  + ((((akw>>3) + hh) ^ (am  & 7)) << 3);
        *(short8*)(sAh + aoff) = ah_;
        *(short8*)(sAl + aoff) = al_;
        int boff = bnl*64 + ((((bkq>>3) + hh) ^ (bnl & 7)) << 3);
        *(short8*)(sBh + boff) = bh_;
        *(short8*)(sBl + boff) = bl_;
      }
      __syncthreads();
      if (it < 7) GS_LOAD((it+1)*64);
      #pragma unroll
      for (int ks = 0; ks < 2; ks++){
        int gc = ks*4 + q;
        int ar = w*16 + l16;
        int ao = ar*64 + ((gc ^ (ar & 7)) << 3);
        short8 afh = *(const short8*)(sAh + ao);
        short8 afl = *(const short8*)(sAl + ao);
        #pragma unroll
        for (int nf = 0; nf < 4; nf++){
          int br = nf*16 + l16;
          int bo = br*64 + ((gc ^ (br & 7)) << 3);
          short8 bfh = *(const short8*)(sBh + bo);
          short8 bfl = *(const short8*)(sBl + bo);
          acc[nf] = __builtin_amdgcn_mfma_f32_16x16x32_bf16(afh, bfh, acc[nf], 0, 0, 0);
          acc[nf] = __builtin_amdgcn_mfma_f32_16x16x32_bf16(afh, bfl, acc[nf], 0, 0, 0);
          acc[nf] = __builtin_amdgcn_mfma_f32_16x16x32_bf16(afl, bfh, acc[nf], 0, 0, 0);
        }
      }
      __syncthreads();
    }
    #undef GS_LOAD
    int m0 = bm + w*16 + q*4;
    #pragma unroll
    for (int nf = 0; nf < 4; nf++){
      int n = bn + nf*16 + l16;
      size_t base = (size_t)n*1536 + (size_t)z*512 + m0;
      #pragma unroll
      for (int e = 0; e < 4; e++)
        split_store(acc[nf][e], &Th[base+e], &Tl[base+e]);
    }
  }
}

// ======================= layer-1 segment softmax, LDS-resident (1 block/graph) =======================
// Edges are grouped by graph (8192/graph); per-graph state (mkey/den/num for 512 nodes)
// fits in LDS -> no global atomics at all. Self-loops appended as items [8192, 8704).
__global__ __launch_bounds__(1024) void k_edge(
    const int* __restrict__ src0, const int* __restrict__ tgt0, const float* __restrict__ x,
    const float* __restrict__ was, const float* __restrict__ wad,
    float* __restrict__ den, float* __restrict__ num){
  int g = blockIdx.x, t = threadIdx.x;
  __shared__ unsigned lmk[1536];
  __shared__ float lden[1536];
  __shared__ float lnum[4608];
  for (int i = t; i < 1536; i += 1024){ lmk[i] = 0u; lden[i] = 0.f; }
  for (int i = t; i < 4608; i += 1024) lnum[i] = 0.f;
  __syncthreads();
  int base = g*8192;
  // pass 1: per-(node,head) max
  for (int it = t; it < 8704; it += 1024){
    int s, tl;
    if (it < 8192){ s = src0[base+it]; tl = tgt0[base+it] & 511; }
    else { tl = it - 8192; s = g*512 + tl; }
    float xs0 = x[s*3], xs1 = x[s*3+1], xs2 = x[s*3+2];
    int tg = g*512 + tl;
    float xt0 = x[tg*3], xt1 = x[tg*3+1], xt2 = x[tg*3+2];
    #pragma unroll
    for (int h = 0; h < 3; h++){
      float v = xs0*was[h*3]+xs1*was[h*3+1]+xs2*was[h*3+2]
              + xt0*wad[h*3]+xt1*wad[h*3+1]+xt2*wad[h*3+2];
      v = v > 0.f ? v : 0.2f*v;
      atomicMax(&lmk[tl*3 + h], fkey(v));
    }
  }
  __syncthreads();
  // pass 2: exp sums + weighted source features
  for (int it = t; it < 8704; it += 1024){
    int s, tl;
    if (it < 8192){ s = src0[base+it]; tl = tgt0[base+it] & 511; }
    else { tl = it - 8192; s = g*512 + tl; }
    float xs0 = x[s*3], xs1 = x[s*3+1], xs2 = x[s*3+2];
    int tg = g*512 + tl;
    float xt0 = x[tg*3], xt1 = x[tg*3+1], xt2 = x[tg*3+2];
    #pragma unroll
    for (int h = 0; h < 3; h++){
      float v = xs0*was[h*3]+xs1*was[h*3+1]+xs2*was[h*3+2]
              + xt0*wad[h*3]+xt1*wad[h*3+1]+xt2*wad[h*3+2];
      v = v > 0.f ? v : 0.2f*v;
      float m = fkey_inv(lmk[tl*3 + h]);
      float pe = expf(v - m);
      atomicAdd(&lden[tl*3 + h], pe);
      atomicAdd(&lnum[tl*9 + h*3 + 0], pe * xs0);
      atomicAdd(&lnum[tl*9 + h*3 + 1], pe * xs1);
      atomicAdd(&lnum[tl*9 + h*3 + 2], pe * xs2);
    }
  }
  __syncthreads();
  // write out (plain coalesced stores; layouts match k_h1)
  for (int i = t; i < 4608; i += 1024) num[(size_t)g*4608 + i] = lnum[i];
  for (int i = t; i < 1536; i += 1024) den[(size_t)g*1536 + i] = lden[i];
}

// h1[n,j] = relu(cvec[j] + sum_q (num/den)[n,q]*M1[q,j]) -> bf16 ; fused BN partials
__global__ __launch_bounds__(256) void k_h1(
    const float* __restrict__ num, const float* __restrict__ den,
    const float* __restrict__ M1p, const float* __restrict__ cvp1, bf16* __restrict__ hout,
    float* __restrict__ bnacc1){
  __shared__ float sM[9*512];
  __shared__ float sC[512];
  __shared__ float sA[32*9];
  int t = threadIdx.x; int n0 = blockIdx.x*32;
  for (int i = t; i < 9*512; i += 256)
    sM[i] = M1p[i] + M1p[4608 + i] + M1p[2*4608 + i] + M1p[3*4608 + i];
  for (int i = t; i < 512; i += 256){
    float s = 0.f;
    #pragma unroll
    for (int kc = 0; kc < 8; kc++) s += cvp1[kc*512 + i];
    sC[i] = s;
  }
  for (int i = t; i < 288; i += 256){
    int node = i / 9, q = i % 9, hh = q / 3;
    float d = fmaxf(den[(size_t)(n0+node)*3 + hh], 1e-16f);
    sA[i] = num[(size_t)n0*9 + i] / d;
  }
  __syncthreads();
  float c0v = sC[t], c1v = sC[t+256];
  float ls0=0.f, lq0=0.f, ls1=0.f, lq1=0.f;
  #pragma unroll 4
  for (int i = 0; i < 32; i++){
    float a0 = c0v, a1 = c1v;
    #pragma unroll
    for (int q = 0; q < 9; q++){
      float av = sA[i*9+q];
      a0 += av * sM[q*512 + t];
      a1 += av * sM[q*512 + t + 256];
    }
    a0 = fmaxf(a0, 0.f); a1 = fmaxf(a1, 0.f);
    hout[(size_t)(n0+i)*512 + t]       = __float2bfloat16(a0);
    hout[(size_t)(n0+i)*512 + t + 256] = __float2bfloat16(a1);
    ls0 += a0; lq0 += a0*a0; ls1 += a1; lq1 += a1*a1;
  }
  atomicAdd(&bnacc1[t],           ls0);
  atomicAdd(&bnacc1[t+256],       ls1);
  atomicAdd(&bnacc1[512 + t],     lq0);
  atomicAdd(&bnacc1[512 + t+256], lq1);
}

// ======================= fused score + top-k sort (one block per graph) =======================
__global__ __launch_bounds__(512) void k_scoresort(
    const bf16* __restrict__ h, const float* __restrict__ bnacc, int M,
    const float* __restrict__ g_, const float* __restrict__ be, const float* __restrict__ p,
    int n_per, int K, int* __restrict__ map,
    int* __restrict__ topi, float* __restrict__ tops){
  int g = blockIdx.x, t = threadIdx.x;
  __shared__ float w[512];
  __shared__ float redb[8], redp[8];
  __shared__ float sk[512];
  __shared__ int si[512];
  float fM = (float)M;
  float mean, inv; bn_from_acc(bnacc, t, fM, mean, inv);
  float gc = g_[t], pc = p[t];
  float ig = inv * gc;
  w[t] = ig * pc;
  float bt = (be[t] - mean * ig) * pc;
  float b_ = wred64(bt);
  float pp = wred64(pc * pc);
  int lane = t & 63, wv = t >> 6;
  if (lane == 0){ redb[wv] = b_; redp[wv] = pp; }
  __syncthreads();
  float B0 = 0.f, pn2 = 0.f;
  #pragma unroll
  for (int u = 0; u < 8; u++){ B0 += redb[u]; pn2 += redp[u]; }
  float pn = sqrtf(pn2);
  float score = -INFINITY; int idx = 0x7fffffff;
  if (t < n_per){
    const unsigned short* hr = (const unsigned short*)h + (size_t)(g*n_per + t)*EMB;
    float dot = 0.f;
    #pragma unroll 4
    for (int c = 0; c < 512; c += 8){
      us4 v0 = *(const us4*)(hr + c);
      us4 v1 = *(const us4*)(hr + c + 4);
      dot += b2f_raw(v0.x)*w[c]   + b2f_raw(v0.y)*w[c+1]
           + b2f_raw(v0.z)*w[c+2] + b2f_raw(v0.w)*w[c+3]
           + b2f_raw(v1.x)*w[c+4] + b2f_raw(v1.y)*w[c+5]
           + b2f_raw(v1.z)*w[c+6] + b2f_raw(v1.w)*w[c+7];
    }
    score = tanhf((dot + B0) / pn);
    idx = t;
  }
  sk[t] = score; si[t] = idx;
  __syncthreads();
  for (int k = 2; k <= 512; k <<= 1){
    for (int j = k >> 1; j > 0; j >>= 1){
      int l = t ^ j;
      if (l > t){
        float ki = sk[t], kl = sk[l]; int ii = si[t], il = si[l];
        bool before_l = (kl > ki) || (kl == ki && il < ii);
        bool up = ((t & k) == 0);
        if (up == before_l){ sk[t]=kl; sk[l]=ki; si[t]=il; si[l]=ii; }
      }
      __syncthreads();
    }
  }
  if (t < K){
    if (map) map[g*n_per + si[t]] = g*K + t;
    topi[g*K + t] = si[t];
    tops[g*K + t] = sk[t];
  }
}

// gather + inline BN + scale -> bf16; fused layer-2 attention dots; fused count2 tail
__global__ __launch_bounds__(256) void k_gather_c2(
    const bf16* __restrict__ h, const float* __restrict__ bnacc, int M,
    const float* __restrict__ gm, const float* __restrict__ be,
    const int* __restrict__ topi, const float* __restrict__ tops,
    bf16* __restrict__ xn, int n_per, int K,
    const float* __restrict__ was2, const float* __restrict__ wad2,
    float* __restrict__ aso, float* __restrict__ ado,
    const int* __restrict__ src0, const int* __restrict__ tgt0,
    const int* __restrict__ map, int* __restrict__ cnt2, int nblk_g){
  int row = blockIdx.x, t = threadIdx.x;
  if (row >= nblk_g){                      // count2 tail
    int i = (row - nblk_g)*256 + t;
    if (i < E_EDGES){
      int s = map[src0[i]], tg = map[tgt0[i]];
      if (s >= 0 && tg >= 0) atomicAdd(&cnt2[tg], 1);
    }
    return;
  }
  int gr = row / K, i = row - gr*K;
  int sidx = topi[gr*K + i];
  float s = tops[gr*K + i];
  const bf16* src = h + ((size_t)(gr*n_per + sidx))*EMB;
  bf16* dst = xn + (size_t)row*EMB;
  int c0 = t, c1 = t + 256;
  float fM = (float)M;
  float mean0, inv0, mean1, inv1;
  bn_from_acc(bnacc, c0, fM, mean0, inv0);
  bn_from_acc(bnacc, c1, fM, mean1, inv1);
  float v0 = ((__bfloat162float(src[c0]) - mean0) * inv0 * gm[c0] + be[c0]) * s;
  float v1 = ((__bfloat162float(src[c1]) - mean1) * inv1 * gm[c1] + be[c1]) * s;
  dst[c0] = __float2bfloat16(v0);
  dst[c1] = __float2bfloat16(v1);
  {
    float a[6];
    #pragma unroll
    for (int hh = 0; hh < 3; hh++){
      a[hh]   = v0*was2[hh*512 + c0] + v1*was2[hh*512 + c1];
      a[3+hh] = v0*wad2[hh*512 + c0] + v1*wad2[hh*512 + c1];
    }
    __shared__ float red[6][4];
    int lane = t & 63, wv = t >> 6;
    #pragma unroll
    for (int q = 0; q < 6; q++){ float v = wred64(a[q]); if (lane==0) red[q][wv]=v; }
    __syncthreads();
    if (t < 6){
      float sm = red[t][0]+red[t][1]+red[t][2]+red[t][3];
      if (t < 3) aso[row*3+t] = sm; else ado[row*3+(t-3)] = sm;
    }
  }
}

// ======================= CSR (layer 2) =======================
__device__ inline void scan_body(const int* __restrict__ counts, int* __restrict__ off,
                                 int* __restrict__ cur, int n, int* __restrict__ sh){
  int t = threadIdx.x;
  int chunk = (n + 1023) >> 10;
  int b = t * chunk; int e = b + chunk; if (e > n) e = n;
  int s = 0;
  for (int i = b; i < e; i++) s += counts[i];
  sh[t] = s; __syncthreads();
  for (int o = 1; o < 1024; o <<= 1){
    int v = (t >= o) ? sh[t-o] : 0;
    __syncthreads();
    sh[t] += v;
    __syncthreads();
  }
  int run = (t > 0) ? sh[t-1] : 0;
  for (int i = b; i < e; i++){ int c = counts[i]; off[i] = run; cur[i] = run; run += c; }
  if (t == 1023) off[n] = sh[1023];
}
__global__ void k_fill2(const int* __restrict__ src0, const int* __restrict__ tgt0,
                        const int* __restrict__ map, int* __restrict__ cur,
                        int* __restrict__ esrc, int E, int nn){
  int i = blockIdx.x*blockDim.x + threadIdx.x;
  if (i >= E + nn) return;
  int s, tg;
  if (i < E){
    s = map[src0[i]]; tg = map[tgt0[i]];
    if (s < 0 || tg < 0) return;
  } else { s = i - E; tg = s; }
  int pos = atomicAdd(&cur[tg], 1);
  esrc[pos] = s;
}

// ======================= pooling =======================
// blocks [0,64): poolA over xn1; block 64: scan(cnt2)
__global__ __launch_bounds__(1024) void k_poolA_scan(const bf16* __restrict__ xn,
    float* __restrict__ cat, int K,
    const int* __restrict__ cnt2, int* __restrict__ off2, int* __restrict__ cur2){
  __shared__ int shi[1024];
  __shared__ float smax[8][128];
  __shared__ float ssum[8][128];
  int b = blockIdx.x, t = threadIdx.x;
  if (b == 64){ scan_body(cnt2, off2, cur2, NN2, shi); return; }
  int g = b >> 2, cb = b & 3;
  int c = t & 127, rg = t >> 7;
  int col = cb*128 + c;
  const unsigned short* p = (const unsigned short*)xn + (size_t)g*K*EMB + col;
  float mx = -INFINITY, sm = 0.f;
  for (int r = rg; r < K; r += 8){
    float v = b2f_raw(p[(size_t)r*EMB]);
    mx = fmaxf(mx, v); sm += v;
  }
  smax[rg][c] = mx; ssum[rg][c] = sm;
  __syncthreads();
  if (rg == 0){
    #pragma unroll
    for (int u = 1; u < 8; u++){ mx = fmaxf(mx, smax[u][c]); sm += ssum[u][c]; }
    cat[g*1024 + col] = mx;
    cat[g*1024 + 512 + col] = sm / (float)K;
  }
}
// layer-2: fused gather + inline BN + scale + max/mean pool directly from Cc
__global__ __launch_bounds__(1024) void k_poolB(const bf16* __restrict__ h,
    const float* __restrict__ bnacc, int M,
    const float* __restrict__ gm, const float* __restrict__ be,
    const int* __restrict__ topi, const float* __restrict__ tops,
    float* __restrict__ cat, int n_per, int K){
  __shared__ int sti[256];
  __shared__ float sts[256];
  __shared__ float smax[8][128];
  __shared__ float ssum[8][128];
  int b = blockIdx.x, t = threadIdx.x;
  int g = b >> 2, cb = b & 3;
  for (int r = t; r < K; r += 1024){ sti[r] = topi[g*K + r]; sts[r] = tops[g*K + r]; }
  __syncthreads();
  int c = t & 127, rg = t >> 7;
  int col = cb*128 + c;
  float fM = (float)M;
  float mean, inv; bn_from_acc(bnacc, col, fM, mean, inv);
  float gg = gm[col], bb = be[col];
  const unsigned short* hp = (const unsigned short*)h;
  float mx = -INFINITY, sm = 0.f;
  for (int r = rg; r < K; r += 8){
    float v = (b2f_raw(hp[(size_t)(g*n_per + sti[r])*EMB + col]) - mean) * inv * gg + bb;
    v *= sts[r];
    mx = fmaxf(mx, v); sm += v;
  }
  smax[rg][c] = mx; ssum[rg][c] = sm;
  __syncthreads();
  if (rg == 0){
    #pragma unroll
    for (int u = 1; u < 8; u++){ mx = fmaxf(mx, smax[u][c]); sm += ssum[u][c]; }
    cat[g*1024 + col] = mx;
    cat[g*1024 + 512 + col] = sm / (float)K;
  }
}

// ======================= layer 2 aggregation =======================
__global__ __launch_bounds__(256) void k_agg2(
    const bf16* __restrict__ xn, const float* __restrict__ aso, const float* __restrict__ ado,
    const int* __restrict__ off, const int* __restrict__ esrc,
    bf16* __restrict__ oh){
  int n = blockIdx.x, t = threadIdx.x;
  __shared__ int srcs[MAXDEG];
  __shared__ float al[MAXDEG*3];
  __shared__ float mh[3], dh[3];
  int s0 = off[n]; int deg = off[n+1] - s0; if (deg > MAXDEG) deg = MAXDEG;
  for (int e = t; e < deg; e += 256) srcs[e] = esrc[s0 + e];
  __syncthreads();
  float ad0 = ado[n*3+0], ad1 = ado[n*3+1], ad2 = ado[n*3+2];
  for (int e = t; e < deg; e += 256){
    int s = srcs[e];
    float v0 = aso[s*3+0] + ad0, v1 = aso[s*3+1] + ad1, v2 = aso[s*3+2] + ad2;
    al[e*3+0] = v0 > 0.f ? v0 : 0.2f*v0;
    al[e*3+1] = v1 > 0.f ? v1 : 0.2f*v1;
    al[e*3+2] = v2 > 0.f ? v2 : 0.2f*v2;
  }
  __syncthreads();
  if (t < 3){
    float m = -INFINITY;
    for (int e = 0; e < deg; e++) m = fmaxf(m, al[e*3+t]);
    float d = 0.f;
    for (int e = 0; e < deg; e++) d += expf(al[e*3+t] - m);
    mh[t] = m; dh[t] = 1.f / fmaxf(d, 1e-16f);
  }
  __syncthreads();
  for (int e = t; e < deg; e += 256){
    al[e*3+0] = expf(al[e*3+0]-mh[0])*dh[0];
    al[e*3+1] = expf(al[e*3+1]-mh[1])*dh[1];
    al[e*3+2] = expf(al[e*3+2]-mh[2])*dh[2];
  }
  __syncthreads();
  float acc[2][3] = {};
  for (int e = 0; e < deg; e++){
    int s = srcs[e];
    float a0 = al[e*3], a1 = al[e*3+1], a2 = al[e*3+2];
    #pragma unroll
    for (int k = 0; k < 2; k++){
      float v = __bfloat162float(xn[(size_t)s*512 + t + k*256]);
      acc[k][0] += a0*v; acc[k][1] += a1*v; acc[k][2] += a2*v;
    }
  }
  #pragma unroll
  for (int k = 0; k < 2; k++){
    int c = t + k*256;
    #pragma unroll
    for (int h = 0; h < 3; h++)
      oh[(size_t)n*1536 + h*512 + c] = __float2bfloat16(acc[k][h]);
  }
}

// ======================= bf16-A x split-bf16-B MFMA GEMM (XCD-swizzled) =======================
__global__ __launch_bounds__(256, 2) void k_gemm_mfma(
    const bf16* __restrict__ Ah,
    const bf16* __restrict__ Bh, const bf16* __restrict__ Bl,   // [N][K] row-major
    const float* __restrict__ bias, bf16* __restrict__ C,
    float* __restrict__ bnacc,
    int M, int N, int K, int Mtiles){
  // XCD-aware mapping: all 8 bn-tiles of a given bm land on the same XCD,
  // so the A-tile is fetched ~once into that XCD's L2.
  int xcd = (int)blockIdx.x & 7;
  int ii  = (int)blockIdx.x >> 3;
  int bni = ii & 7;
  int bmi = xcd + 8*(ii >> 3);
  if (bmi >= Mtiles) return;
  __shared__ __align__(16) unsigned short lds[2][16384];   // 64 KB total
  int t = threadIdx.x, w = t >> 6, lane = t & 63;
  int q = lane >> 4, l16 = lane & 15;
  int bm = bmi * 128, bn = bni * 64;

  int lr = lane >> 3, lc = lane & 7;
  int kg = ((lc ^ lr) & 7) * 8;
  int ro = w*8 + lr;
  int m0 = bm + ro, m1 = bm + 32 + ro, m2 = bm + 64 + ro, m3 = bm + 96 + ro;
  if (m0 >= M) m0 = M-1;  if (m1 >= M) m1 = M-1;
  if (m2 >= M) m2 = M-1;  if (m3 >= M) m3 = M-1;
  int n0 = bn + ro, n1 = bn + 32 + ro;
  const bf16* ptr[8];
  ptr[0] = Ah + (size_t)m0*K + kg;
  ptr[1] = Ah + (size_t)m1*K + kg;
  ptr[2] = Ah + (size_t)m2*K + kg;
  ptr[3] = Ah + (size_t)m3*K + kg;
  ptr[4] = Bh + (size_t)n0*K + kg;
  ptr[5] = Bh + (size_t)n1*K + kg;
  ptr[6] = Bl + (size_t)n0*K + kg;
  ptr[7] = Bl + (size_t)n1*K + kg;
  const int dof[8] = {0, 2048, 4096, 6144, 8192, 10240, 12288, 14336};

  int wm = (w >> 1) * 64, wn = (w & 1) * 32;
  f32x4 acc[4][2];
  #pragma unroll
  for (int i = 0; i < 4; i++)
    #pragma unroll
    for (int j = 0; j < 2; j++)
      acc[i][j] = (f32x4){0.f, 0.f, 0.f, 0.f};

  #pragma unroll
  for (int u = 0; u < 8; u++){
    gld16(ptr[u], &lds[0][dof[u] + w*512]);
    ptr[u] += 64;
  }

  int nit = K >> 6;
  for (int it = 0; it < nit; it++){
    __syncthreads();
    int cur = it & 1;
    if (it + 1 < nit){
      int nxt = cur ^ 1;
      #pragma unroll
      for (int u = 0; u < 8; u++){
        gld16(ptr[u], &lds[nxt][dof[u] + w*512]);
        ptr[u] += 64;
      }
    }
    const unsigned short* L = lds[cur];
    #pragma unroll
    for (int ks = 0; ks < 2; ks++){
      short8 ah[4], bh2[2], bl2[2];
      int gc = ks*4 + q;
      #pragma unroll
      for (int i = 0; i < 4; i++){
        int r = wm + i*16 + l16;
        ah[i] = *(const short8*)(L + r*64 + ((gc ^ (r & 7)) << 3));
      }
      #pragma unroll
      for (int j = 0; j < 2; j++){
        int r = wn + j*16 + l16;
        int so = ((gc ^ (r & 7)) << 3);
        bh2[j] = *(const short8*)(L + 8192  + r*64 + so);
        bl2[j] = *(const short8*)(L + 12288 + r*64 + so);
      }
      #pragma unroll
      for (int i = 0; i < 4; i++)
        #pragma unroll
        for (int j = 0; j < 2; j++){
          acc[i][j] = __builtin_amdgcn_mfma_f32_16x16x32_bf16(ah[i], bh2[j], acc[i][j], 0, 0, 0);
          acc[i][j] = __builtin_amdgcn_mfma_f32_16x16x32_bf16(ah[i], bl2[j], acc[i][j], 0, 0, 0);
        }
    }
  }

  __syncthreads();
  float* cs = (float*)&lds[0][0];
  float* cq = cs + 128;
  int slot = w >> 1;
  #pragma unroll
  for (int j = 0; j < 2; j++){
    int c_local = wn + j*16 + l16;
    int c = bn + c_local;
    float bv = 0.f;
    if (bias){
      #pragma unroll
      for (int kc = 0; kc < 8; kc++) bv += bias[kc*512 + c];
    }
    float ls = 0.f, lq = 0.f;
    #pragma unroll
    for (int i = 0; i < 4; i++){
      int rb = bm + wm + i*16 + q*4;
      #pragma unroll
      for (int e = 0; e < 4; e++){
        int r = rb + e;
        if (r < M){
          float v = fmaxf(acc[i][j][e] + bv, 0.f);
          C[(size_t)r*N + c] = __float2bfloat16(v);
          ls += v; lq += v*v;
        }
      }
    }
    ls += __shfl_xor(ls, 16); ls += __shfl_xor(ls, 32);
    lq += __shfl_xor(lq, 16); lq += __shfl_xor(lq, 32);
    if (q == 0){ cs[slot*64 + c_local] = ls; cq[slot*64 + c_local] = lq; }
  }
  __syncthreads();
  if (t < 64){
    atomicAdd(&bnacc[bn + t],        cs[t] + cs[64 + t]);
    atomicAdd(&bnacc[512 + bn + t],  cq[t] + cq[64 + t]);
  }
}

// ======================= fused head (one block per graph) =======================
__global__ __launch_bounds__(1024) void k_head(const float* __restrict__ c1,
    const float* __restrict__ c2, const float* __restrict__ Wl1,
    const float* __restrict__ bl1, const float* __restrict__ Wl2,
    const float* __restrict__ bl2, float* __restrict__ out){
  int g = blockIdx.x, t = threadIdx.x;
  __shared__ float xg[1024];
  __shared__ float t1[512];
  __shared__ float part[2][512];
  xg[t] = c1[g*1024 + t] + c2[g*1024 + t];
  __syncthreads();
  int c = t & 511, kc = t >> 9;
  float acc = 0.f;
  #pragma unroll 8
  for (int k = kc*512; k < kc*512 + 512; k++)
    acc += xg[k] * Wl1[(size_t)k*512 + c];
  part[kc][c] = acc;
  __syncthreads();
  if (kc == 0) t1[c] = fmaxf(part[0][c] + part[1][c] + bl1[c], 0.f);
  __syncthreads();
  if (t < 512){
    int c2i = t & 255, k2 = t >> 8;
    float a = 0.f;
    #pragma unroll 8
    for (int k = k2*256; k < k2*256 + 256; k++)
      a += t1[k] * Wl2[(size_t)k*256 + c2i];
    part[k2][c2i] = a;
  }
  __syncthreads();
  if (t < 256)
    out[g*256 + t] = part[0][t] + part[1][t] + bl2[t];
}

extern "C" void kernel_launch(void* const* d_in, const int* in_sizes, int n_in,
                              void* d_out, int out_size, void* d_ws, size_t ws_size,
                              hipStream_t stream){
  const float* x   = (const float*)d_in[0];
  const int*   ei  = (const int*)d_in[1];
  const float* W1  = (const float*)d_in[2];
  const float* as1 = (const float*)d_in[3];
  const float* ad1 = (const float*)d_in[4];
  const float* bc1 = (const float*)d_in[5];
  const float* Wh1 = (const float*)d_in[6];
  const float* bh1 = (const float*)d_in[7];
  const float* g1  = (const float*)d_in[8];
  const float* be1 = (const float*)d_in[9];
  const float* p1  = (const float*)d_in[10];
  const float* W2  = (const float*)d_in[11];
  const float* as2 = (const float*)d_in[12];
  const float* ad2 = (const float*)d_in[13];
  const float* bc2 = (const float*)d_in[14];
  const float* Wh2 = (const float*)d_in[15];
  const float* bh2 = (const float*)d_in[16];
  const float* g2  = (const float*)d_in[17];
  const float* be2 = (const float*)d_in[18];
  const float* p2  = (const float*)d_in[19];
  const float* Wl1 = (const float*)d_in[20];
  const float* bl1 = (const float*)d_in[21];
  const float* Wl2 = (const float*)d_in[22];
  const float* bl2 = (const float*)d_in[23];
  float* out = (float*)d_out;

  const int* src0 = ei;
  const int* tgt0 = ei + E_EDGES;

  // ---- workspace layout ----
  bf16* Cc      = (bf16*)d_ws;                       // NN1*EMB
  bf16* xn1     = Cc + (size_t)NN1*EMB;              // NN2*EMB
  bf16* aggx2h  = xn1 + (size_t)NN2*EMB;             // NN2*F1
  bf16* M2Th    = aggx2h + (size_t)NN2*F1;           // EMB*F1
  bf16* M2Tl    = M2Th + (size_t)EMB*F1;             // EMB*F1
  float* num    = (float*)(M2Tl + (size_t)EMB*F1);   // NN1*9 = 73728
  float* den    = num + (size_t)NN1*9;               // NN1*3 = 24576
  unsigned* mkey= (unsigned*)(den + (size_t)NN1*3);  // (unused hole, 24576)
  float* bnacc1 = (float*)(mkey + (size_t)NN1*3);    // 1024
  float* bnacc  = bnacc1 + 1024;                     // 1024
  float* M1p    = bnacc + 1024;                      // 4*4608
  float* cvp    = M1p + 4*4608;                      // 16*512 (cvp2 = cvp + 8*512)
  float* was2   = cvp + 16*512;                      // 3*512
  float* wad2   = was2 + 3*512;                      // 3*512
  float* was1   = wad2 + 3*512;                      // 16
  float* wad1   = was1 + 16;                         // 16
  float* aso2   = wad1 + 16;                         // NN2*3
  float* ado2   = aso2 + (size_t)NN2*3;              // NN2*3
  float* tops   = ado2 + (size_t)NN2*3;              // NG*KP1
  float* cat1   = tops + NG*KP1;                     // 16*1024
  float* cat2   = cat1 + NG*1024;                    // 16*1024
  int* topi     = (int*)(cat2 + NG*1024);            // NG*KP1
  int* map      = topi + NG*KP1;                     // NN1
  int* cnt2     = map + NN1;                         // NN2
  int* off2     = cnt2 + NN2;                        // NN2+8
  int* cur2     = off2 + NN2 + 8;                    // NN2
  int* esrc2    = cur2 + NN2;                        // E+NN2 (+pad)
  float* cvp2   = cvp + 8*512;

  // 1. mega precompute: init + watt + M1p/cvp + gemm_s
  k_pre<<<428,256,0,stream>>>(W1,as1,ad1,Wh1,bc1,bh1, W2,as2,ad2,Wh2,bc2,bh2,
                              was1,wad1,M1p,cvp,was2,wad2,
                              bnacc1,cnt2,map,M2Th,M2Tl);
  // 2. layer-1 segment softmax, LDS-resident (no global atomics)
  k_edge<<<NG,1024,0,stream>>>(src0,tgt0,x,was1,wad1,den,num);
  // 3. h1 + BN partials
  k_h1<<<NN1/32,256,0,stream>>>(num,den,M1p,cvp,Cc,bnacc1);
  // 4. fused score+sort (layer 1)
  k_scoresort<<<NG,512,0,stream>>>(Cc,bnacc1,NN1,g1,be1,p1,NP1,KP1,map,topi,tops);
  // 5. gather + attention dots + count2
  k_gather_c2<<<NG*KP1+512,256,0,stream>>>(Cc,bnacc1,NN1,g1,be1,topi,tops,xn1,NP1,KP1,
      was2,wad2,aso2,ado2, src0,tgt0,map,cnt2,NG*KP1);
  // 6. poolA + scan2
  k_poolA_scan<<<65,1024,0,stream>>>(xn1,cat1,KP1, cnt2,off2,cur2);
  // 7. fill2
  k_fill2<<<(E_EDGES+NN2+255)/256,256,0,stream>>>(src0,tgt0,map,cur2,esrc2,E_EDGES,NN2);
  // 8. agg2
  k_agg2<<<NN2,256,0,stream>>>(xn1,aso2,ado2,off2,esrc2,aggx2h);
  // 9. big GEMM (XCD-swizzled, grid 56*8 with guard)
  k_gemm_mfma<<<448,256,0,stream>>>(aggx2h,M2Th,M2Tl,cvp2,Cc,bnacc,NN2,EMB,F1,52);
  // 10. fused score+sort (layer 2)
  k_scoresort<<<NG,512,0,stream>>>(Cc,bnacc,NN2,g2,be2,p2,KP1,KP2,(int*)nullptr,topi,tops);
  // 11. poolB
  k_poolB<<<64,1024,0,stream>>>(Cc,bnacc,NN2,g2,be2,topi,tops,cat2,KP1,KP2);
  // 12. fused head
  k_head<<<NG,1024,0,stream>>>(cat1,cat2,Wl1,bl1,Wl2,bl2,out);
}

// Round 7
// 330.399 us; speedup vs baseline: 1.3736x; 1.3736x over previous
//
#include <hip/hip_runtime.h>
#include <hip/hip_bf16.h>
#include <math.h>

#define E_EDGES 131072
#define NN1 8192
#define NN2 6560          // 16*410
#define NG 16
#define NP1 512
#define KP1 410
#define KP2 205
#define F1 1536
#define EMB 512
#define MAXDEG 256

typedef __hip_bfloat16 bf16;
typedef __attribute__((ext_vector_type(8))) short short8;
typedef __attribute__((ext_vector_type(4))) float f32x4;
typedef __attribute__((ext_vector_type(4))) unsigned short us4;

__device__ inline float wred64(float v){
  #pragma unroll
  for (int o = 32; o; o >>= 1) v += __shfl_down(v, o);
  return v;
}
__device__ inline float b2f_raw(unsigned short u){
  return __uint_as_float((unsigned)u << 16);
}
union BFU { bf16 b; unsigned short u; };
__device__ inline unsigned short f2u(float v){ BFU x; x.b = __float2bfloat16(v); return x.u; }

__device__ __forceinline__ void gld16(const void* g, void* l){
  __builtin_amdgcn_global_load_lds(
      (const __attribute__((address_space(1))) void*)g,
      (__attribute__((address_space(3))) void*)l, 16, 0, 0);
}

__device__ inline void split_store(float v, bf16* __restrict__ ph, bf16* __restrict__ pl){
  bf16 hi = __float2bfloat16(v);
  *ph = hi;
  *pl = __float2bfloat16(v - __bfloat162float(hi));
}

// inline BN stats from raw sums
__device__ inline void bn_from_acc(const float* __restrict__ bnacc, int c, float fM,
                                   float& mean, float& inv){
  mean = bnacc[c] / fM;
  float var = fmaxf(bnacc[512+c]/fM - mean*mean, 0.f);
  inv = 1.f / sqrtf(var + 1e-5f);
}

// ======================= mega precompute =======================
// [0,24): M1 partials  [24,56): cvec partials  [56,152): watt2
// [152,170): watt1     [170,236): init (bnacc zero / cnt2=1 / map=-1)
// [236,428): gemm_s 64x64 split-bf16 MFMA tiles (W2@Wh2 -> M2T split)
__global__ __launch_bounds__(256) void k_pre(
    const float* __restrict__ W1, const float* __restrict__ as1, const float* __restrict__ ad1,
    const float* __restrict__ Wh1, const float* __restrict__ bc1, const float* __restrict__ bh1,
    const float* __restrict__ W2, const float* __restrict__ as2, const float* __restrict__ ad2,
    const float* __restrict__ Wh2, const float* __restrict__ bc2, const float* __restrict__ bh2,
    float* __restrict__ was1, float* __restrict__ wad1, float* __restrict__ M1p,
    float* __restrict__ cvp,
    float* __restrict__ was2, float* __restrict__ wad2,
    float* __restrict__ Zb, int* __restrict__ cnt2, int* __restrict__ map,
    bf16* __restrict__ Th, bf16* __restrict__ Tl){
  int b = blockIdx.x, t = threadIdx.x;
  if (b < 24){                               // M1 partials
    int h = b / 8, rem = b % 8, jh = rem >> 2, kc = rem & 3;
    int j = jh*256 + t, c0 = kc*128;
    __shared__ float w1s[3][128];
    for (int i = t; i < 384; i += 256)
      w1s[i>>7][i&127] = W1[(i>>7)*1536 + h*512 + c0 + (i&127)];
    __syncthreads();
    const float* whc = Wh1 + (size_t)(h*512 + c0)*512 + j;
    float a0=0.f, a1=0.f, a2=0.f;
    #pragma unroll 8
    for (int c = 0; c < 128; c++){
      float v = whc[(size_t)c*512];
      a0 += w1s[0][c]*v; a1 += w1s[1][c]*v; a2 += w1s[2][c]*v;
    }
    float* dst = M1p + (size_t)kc*4608;
    dst[(h*3+0)*512 + j] = a0;
    dst[(h*3+1)*512 + j] = a1;
    dst[(h*3+2)*512 + j] = a2;
  } else if (b < 56){                        // cvec partials
    int b2 = b - 24;
    int which = b2 >> 4, rem = b2 & 15, jh = rem >> 3, kc = rem & 7;
    const float* bc = which ? bc2 : bc1;
    const float* Wh = which ? Wh2 : Wh1;
    const float* bh = which ? bh2 : bh1;
    int j = jh*256 + t, i0 = kc*192;
    float acc = (kc == 0) ? bh[j] : 0.f;
    #pragma unroll 8
    for (int i = 0; i < 192; i++)
      acc += bc[i0+i] * Wh[(size_t)(i0+i)*512 + j];
    cvp[(size_t)(which*8 + kc)*512 + j] = acc;
  } else if (b < 152){                       // watt2
    int b3 = b - 56;
    int y = b3 >> 4, et = b3 & 15;
    int kind = y / 3, h = y % 3;
    int w = t >> 6, lane = t & 63;
    const float* att = kind ? ad2 : as2;
    float a[8];
    #pragma unroll
    for (int u = 0; u < 8; u++) a[u] = att[h*512 + lane*8 + u];
    for (int r = w; r < 32; r += 4){
      int e = et*32 + r;
      const float4* row = (const float4*)(W2 + (size_t)e*1536 + h*512) + lane*2;
      float4 v0 = row[0], v1 = row[1];
      float d = v0.x*a[0]+v0.y*a[1]+v0.z*a[2]+v0.w*a[3]
              + v1.x*a[4]+v1.y*a[5]+v1.z*a[6]+v1.w*a[7];
      d = wred64(d);
      if (lane == 0) (kind ? wad2 : was2)[h*512 + e] = d;
    }
  } else if (b < 170){                       // watt1
    if (t < 64){
      int bb = b - 152;
      int kind = bb / 9, r = bb % 9, h = r / 3, f = r % 3;
      const float* att = kind ? ad1 : as1;
      float s = 0.f;
      for (int c = t; c < 512; c += 64) s += W1[f*1536 + h*512 + c] * att[h*512 + c];
      s = wred64(s);
      if (t == 0) (kind ? wad1 : was1)[h*3 + f] = s;
    }
  } else if (b < 236){                       // init
    int i = (b - 170)*256 + t;
    if (i < 2048){ Zb[i] = 0.f; }                         // bnacc1|bnacc
    else if (i < 2048 + NN2){ cnt2[i - 2048] = 1; }
    else if (i < 2048 + NN2 + NN1){ map[i - 2048 - NN2] = -1; }
  } else {                                   // gemm_s tiles
    int bb = b - 236;
    int z = bb % 3; int rr = bb / 3; int by = rr >> 3, bx = rr & 7;
    const float* A = W2 + (size_t)z*512;            // row stride 1536
    const float* B = Wh2 + (size_t)z*512*512;       // row stride 512
    __shared__ __align__(16) short sAh[4096], sAl[4096], sBh[4096], sBl[4096];
    int w = t >> 6, lane = t & 63;
    int l16 = lane & 15, q = lane >> 4;
    int bm = by*64, bn = bx*64;
    int am  = t >> 2, akw = (t & 3)*16;
    int bnl = t & 63, bkq = (t >> 6)*16;
    f32x4 acc[4];
    #pragma unroll
    for (int nf = 0; nf < 4; nf++) acc[nf] = (f32x4){0.f,0.f,0.f,0.f};
    float va[16], vb[16];
    #define GS_LOAD(K0) do { \
      _Pragma("unroll") for (int u = 0; u < 4; u++){ \
        float4 v4 = *(const float4*)(A + (size_t)(bm+am)*1536 + (K0) + akw + u*4); \
        va[u*4]=v4.x; va[u*4+1]=v4.y; va[u*4+2]=v4.z; va[u*4+3]=v4.w; } \
      _Pragma("unroll") for (int u = 0; u < 16; u++) \
        vb[u] = B[(size_t)((K0) + bkq + u)*512 + bn + bnl]; \
    } while(0)
    GS_LOAD(0);
    for (int it = 0; it < 8; it++){
      #pragma unroll
      for (int hh = 0; hh < 2; hh++){
        short8 ah_, al_, bh_, bl_;
        #pragma unroll
        for (int jj = 0; jj < 8; jj++){
          float v = va[hh*8+jj];
          unsigned short hu = f2u(v);
          ah_[jj] = (short)hu; al_[jj] = (short)f2u(v - b2f_raw(hu));
          v = vb[hh*8+jj];
          hu = f2u(v);
          bh_[jj] = (short)hu; bl_[jj] = (short)f2u(v - b2f_raw(hu));
        }
        int aoff = am*64  + ((((akw>>3) + hh) ^ (am  & 7)) << 3);
        *(short8*)(sAh + aoff) = ah_;
        *(short8*)(sAl + aoff) = al_;
        int boff = bnl*64 + ((((bkq>>3) + hh) ^ (bnl & 7)) << 3);
        *(short8*)(sBh + boff) = bh_;
        *(short8*)(sBl + boff) = bl_;
      }
      __syncthreads();
      if (it < 7) GS_LOAD((it+1)*64);
      #pragma unroll
      for (int ks = 0; ks < 2; ks++){
        int gc = ks*4 + q;
        int ar = w*16 + l16;
        int ao = ar*64 + ((gc ^ (ar & 7)) << 3);
        short8 afh = *(const short8*)(sAh + ao);
        short8 afl = *(const short8*)(sAl + ao);
        #pragma unroll
        for (int nf = 0; nf < 4; nf++){
          int br = nf*16 + l16;
          int bo = br*64 + ((gc ^ (br & 7)) << 3);
          short8 bfh = *(const short8*)(sBh + bo);
          short8 bfl = *(const short8*)(sBl + bo);
          acc[nf] = __builtin_amdgcn_mfma_f32_16x16x32_bf16(afh, bfh, acc[nf], 0, 0, 0);
          acc[nf] = __builtin_amdgcn_mfma_f32_16x16x32_bf16(afh, bfl, acc[nf], 0, 0, 0);
          acc[nf] = __builtin_amdgcn_mfma_f32_16x16x32_bf16(afl, bfh, acc[nf], 0, 0, 0);
        }
      }
      __syncthreads();
    }
    #undef GS_LOAD
    int m0 = bm + w*16 + q*4;
    #pragma unroll
    for (int nf = 0; nf < 4; nf++){
      int n = bn + nf*16 + l16;
      size_t base = (size_t)n*1536 + (size_t)z*512 + m0;
      #pragma unroll
      for (int e = 0; e < 4; e++)
        split_store(acc[nf][e], &Th[base+e], &Tl[base+e]);
    }
  }
}

// ======================= layer-1 segment softmax, chunked LDS-private =======================
// 16 chunks per graph (256 blocks, 1/CU). Single pass: logits are
// leaky_relu of tiny dot products (|v| < ~1) so exp without max-subtraction is
// exactly equivalent (the max cancels in the softmax ratio) and numerically safe.
// Each block accumulates into PRIVATE LDS, then plain-stores its partial
// (no global atomics). k_h1 reduces the 16 chunk-partials.
__global__ __launch_bounds__(256) void k_edge(
    const int* __restrict__ src0, const int* __restrict__ tgt0, const float* __restrict__ x,
    const float* __restrict__ was, const float* __restrict__ wad,
    float* __restrict__ denp, float* __restrict__ nump){
  int b = blockIdx.x, t = threadIdx.x;
  int g = b >> 4, ch = b & 15;
  __shared__ float lden[1536];
  __shared__ float lnum[4608];
  for (int i = t; i < 1536; i += 256) lden[i] = 0.f;
  for (int i = t; i < 4608; i += 256) lnum[i] = 0.f;
  __syncthreads();
  int base = g*8192;
  int it0 = ch*544;                       // 16*544 = 8704 items (8192 edges + 512 self-loops)
  for (int k = t; k < 544; k += 256){
    int it = it0 + k;
    int s, tl;
    if (it < 8192){ s = src0[base+it]; tl = tgt0[base+it] & 511; }
    else { tl = it - 8192; s = g*512 + tl; }
    float xs0 = x[s*3], xs1 = x[s*3+1], xs2 = x[s*3+2];
    int tg = g*512 + tl;
    float xt0 = x[tg*3], xt1 = x[tg*3+1], xt2 = x[tg*3+2];
    #pragma unroll
    for (int h = 0; h < 3; h++){
      float v = xs0*was[h*3]+xs1*was[h*3+1]+xs2*was[h*3+2]
              + xt0*wad[h*3]+xt1*wad[h*3+1]+xt2*wad[h*3+2];
      v = v > 0.f ? v : 0.2f*v;
      float pe = expf(v);
      atomicAdd(&lden[tl*3 + h], pe);
      atomicAdd(&lnum[tl*9 + h*3 + 0], pe * xs0);
      atomicAdd(&lnum[tl*9 + h*3 + 1], pe * xs1);
      atomicAdd(&lnum[tl*9 + h*3 + 2], pe * xs2);
    }
  }
  __syncthreads();
  for (int i = t; i < 4608; i += 256) nump[(size_t)b*4608 + i] = lnum[i];
  for (int i = t; i < 1536; i += 256) denp[(size_t)b*1536 + i] = lden[i];
}

// h1[n,j] = relu(cvec[j] + sum_q (num/den)[n,q]*M1[q,j]) -> bf16 ; fused BN partials.
// num/den arrive as 16 chunk-partials per graph; reduce during LDS load.
__global__ __launch_bounds__(256) void k_h1(
    const float* __restrict__ nump, const float* __restrict__ denp,
    const float* __restrict__ M1p, const float* __restrict__ cvp1, bf16* __restrict__ hout,
    float* __restrict__ bnacc1){
  __shared__ float sM[9*512];
  __shared__ float sC[512];
  __shared__ float sA[32*9];
  int t = threadIdx.x; int n0 = blockIdx.x*32;
  for (int i = t; i < 9*512; i += 256)
    sM[i] = M1p[i] + M1p[4608 + i] + M1p[2*4608 + i] + M1p[3*4608 + i];
  for (int i = t; i < 512; i += 256){
    float s = 0.f;
    #pragma unroll
    for (int kc = 0; kc < 8; kc++) s += cvp1[kc*512 + i];
    sC[i] = s;
  }
  for (int i = t; i < 288; i += 256){
    int node = i / 9, q = i % 9, hh = q / 3;
    int gn = n0 + node;
    int g = gn >> 9, nl = gn & 511;
    float ns = 0.f, ds = 0.f;
    #pragma unroll 4
    for (int ch = 0; ch < 16; ch++){
      ns += nump[(size_t)(g*16 + ch)*4608 + nl*9 + q];
      ds += denp[(size_t)(g*16 + ch)*1536 + nl*3 + hh];
    }
    sA[i] = ns / fmaxf(ds, 1e-16f);
  }
  __syncthreads();
  float c0v = sC[t], c1v = sC[t+256];
  float ls0=0.f, lq0=0.f, ls1=0.f, lq1=0.f;
  #pragma unroll 4
  for (int i = 0; i < 32; i++){
    float a0 = c0v, a1 = c1v;
    #pragma unroll
    for (int q = 0; q < 9; q++){
      float av = sA[i*9+q];
      a0 += av * sM[q*512 + t];
      a1 += av * sM[q*512 + t + 256];
    }
    a0 = fmaxf(a0, 0.f); a1 = fmaxf(a1, 0.f);
    hout[(size_t)(n0+i)*512 + t]       = __float2bfloat16(a0);
    hout[(size_t)(n0+i)*512 + t + 256] = __float2bfloat16(a1);
    ls0 += a0; lq0 += a0*a0; ls1 += a1; lq1 += a1*a1;
  }
  atomicAdd(&bnacc1[t],           ls0);
  atomicAdd(&bnacc1[t+256],       ls1);
  atomicAdd(&bnacc1[512 + t],     lq0);
  atomicAdd(&bnacc1[512 + t+256], lq1);
}

// ======================= fused score + top-k sort (one block per graph) =======================
__global__ __launch_bounds__(512) void k_scoresort(
    const bf16* __restrict__ h, const float* __restrict__ bnacc, int M,
    const float* __restrict__ g_, const float* __restrict__ be, const float* __restrict__ p,
    int n_per, int K, int* __restrict__ map,
    int* __restrict__ topi, float* __restrict__ tops){
  int g = blockIdx.x, t = threadIdx.x;
  __shared__ float w[512];
  __shared__ float redb[8], redp[8];
  __shared__ float sk[512];
  __shared__ int si[512];
  float fM = (float)M;
  float mean, inv; bn_from_acc(bnacc, t, fM, mean, inv);
  float gc = g_[t], pc = p[t];
  float ig = inv * gc;
  w[t] = ig * pc;
  float bt = (be[t] - mean * ig) * pc;
  float b_ = wred64(bt);
  float pp = wred64(pc * pc);
  int lane = t & 63, wv = t >> 6;
  if (lane == 0){ redb[wv] = b_; redp[wv] = pp; }
  __syncthreads();
  float B0 = 0.f, pn2 = 0.f;
  #pragma unroll
  for (int u = 0; u < 8; u++){ B0 += redb[u]; pn2 += redp[u]; }
  float pn = sqrtf(pn2);
  float score = -INFINITY; int idx = 0x7fffffff;
  if (t < n_per){
    const unsigned short* hr = (const unsigned short*)h + (size_t)(g*n_per + t)*EMB;
    float dot = 0.f;
    #pragma unroll 4
    for (int c = 0; c < 512; c += 8){
      us4 v0 = *(const us4*)(hr + c);
      us4 v1 = *(const us4*)(hr + c + 4);
      dot += b2f_raw(v0.x)*w[c]   + b2f_raw(v0.y)*w[c+1]
           + b2f_raw(v0.z)*w[c+2] + b2f_raw(v0.w)*w[c+3]
           + b2f_raw(v1.x)*w[c+4] + b2f_raw(v1.y)*w[c+5]
           + b2f_raw(v1.z)*w[c+6] + b2f_raw(v1.w)*w[c+7];
    }
    score = tanhf((dot + B0) / pn);
    idx = t;
  }
  sk[t] = score; si[t] = idx;
  __syncthreads();
  for (int k = 2; k <= 512; k <<= 1){
    for (int j = k >> 1; j > 0; j >>= 1){
      int l = t ^ j;
      if (l > t){
        float ki = sk[t], kl = sk[l]; int ii = si[t], il = si[l];
        bool before_l = (kl > ki) || (kl == ki && il < ii);
        bool up = ((t & k) == 0);
        if (up == before_l){ sk[t]=kl; sk[l]=ki; si[t]=il; si[l]=ii; }
      }
      __syncthreads();
    }
  }
  if (t < K){
    if (map) map[g*n_per + si[t]] = g*K + t;
    topi[g*K + t] = si[t];
    tops[g*K + t] = sk[t];
  }
}

// gather + inline BN + scale -> bf16; fused layer-2 attention dots; fused count2 tail
__global__ __launch_bounds__(256) void k_gather_c2(
    const bf16* __restrict__ h, const float* __restrict__ bnacc, int M,
    const float* __restrict__ gm, const float* __restrict__ be,
    const int* __restrict__ topi, const float* __restrict__ tops,
    bf16* __restrict__ xn, int n_per, int K,
    const float* __restrict__ was2, const float* __restrict__ wad2,
    float* __restrict__ aso, float* __restrict__ ado,
    const int* __restrict__ src0, const int* __restrict__ tgt0,
    const int* __restrict__ map, int* __restrict__ cnt2, int nblk_g){
  int row = blockIdx.x, t = threadIdx.x;
  if (row >= nblk_g){                      // count2 tail
    int i = (row - nblk_g)*256 + t;
    if (i < E_EDGES){
      int s = map[src0[i]], tg = map[tgt0[i]];
      if (s >= 0 && tg >= 0) atomicAdd(&cnt2[tg], 1);
    }
    return;
  }
  int gr = row / K, i = row - gr*K;
  int sidx = topi[gr*K + i];
  float s = tops[gr*K + i];
  const bf16* src = h + ((size_t)(gr*n_per + sidx))*EMB;
  bf16* dst = xn + (size_t)row*EMB;
  int c0 = t, c1 = t + 256;
  float fM = (float)M;
  float mean0, inv0, mean1, inv1;
  bn_from_acc(bnacc, c0, fM, mean0, inv0);
  bn_from_acc(bnacc, c1, fM, mean1, inv1);
  float v0 = ((__bfloat162float(src[c0]) - mean0) * inv0 * gm[c0] + be[c0]) * s;
  float v1 = ((__bfloat162float(src[c1]) - mean1) * inv1 * gm[c1] + be[c1]) * s;
  dst[c0] = __float2bfloat16(v0);
  dst[c1] = __float2bfloat16(v1);
  {
    float a[6];
    #pragma unroll
    for (int hh = 0; hh < 3; hh++){
      a[hh]   = v0*was2[hh*512 + c0] + v1*was2[hh*512 + c1];
      a[3+hh] = v0*wad2[hh*512 + c0] + v1*wad2[hh*512 + c1];
    }
    __shared__ float red[6][4];
    int lane = t & 63, wv = t >> 6;
    #pragma unroll
    for (int q = 0; q < 6; q++){ float v = wred64(a[q]); if (lane==0) red[q][wv]=v; }
    __syncthreads();
    if (t < 6){
      float sm = red[t][0]+red[t][1]+red[t][2]+red[t][3];
      if (t < 3) aso[row*3+t] = sm; else ado[row*3+(t-3)] = sm;
    }
  }
}

// ======================= CSR (layer 2) =======================
__device__ inline void scan_body(const int* __restrict__ counts, int* __restrict__ off,
                                 int* __restrict__ cur, int n, int* __restrict__ sh){
  int t = threadIdx.x;
  int chunk = (n + 1023) >> 10;
  int b = t * chunk; int e = b + chunk; if (e > n) e = n;
  int s = 0;
  for (int i = b; i < e; i++) s += counts[i];
  sh[t] = s; __syncthreads();
  for (int o = 1; o < 1024; o <<= 1){
    int v = (t >= o) ? sh[t-o] : 0;
    __syncthreads();
    sh[t] += v;
    __syncthreads();
  }
  int run = (t > 0) ? sh[t-1] : 0;
  for (int i = b; i < e; i++){ int c = counts[i]; off[i] = run; cur[i] = run; run += c; }
  if (t == 1023) off[n] = sh[1023];
}
__global__ void k_fill2(const int* __restrict__ src0, const int* __restrict__ tgt0,
                        const int* __restrict__ map, int* __restrict__ cur,
                        int* __restrict__ esrc, int E, int nn){
  int i = blockIdx.x*blockDim.x + threadIdx.x;
  if (i >= E + nn) return;
  int s, tg;
  if (i < E){
    s = map[src0[i]]; tg = map[tgt0[i]];
    if (s < 0 || tg < 0) return;
  } else { s = i - E; tg = s; }
  int pos = atomicAdd(&cur[tg], 1);
  esrc[pos] = s;
}

// ======================= pooling =======================
// blocks [0,64): poolA over xn1; block 64: scan(cnt2)
__global__ __launch_bounds__(1024) void k_poolA_scan(const bf16* __restrict__ xn,
    float* __restrict__ cat, int K,
    const int* __restrict__ cnt2, int* __restrict__ off2, int* __restrict__ cur2){
  __shared__ int shi[1024];
  __shared__ float smax[8][128];
  __shared__ float ssum[8][128];
  int b = blockIdx.x, t = threadIdx.x;
  if (b == 64){ scan_body(cnt2, off2, cur2, NN2, shi); return; }
  int g = b >> 2, cb = b & 3;
  int c = t & 127, rg = t >> 7;
  int col = cb*128 + c;
  const unsigned short* p = (const unsigned short*)xn + (size_t)g*K*EMB + col;
  float mx = -INFINITY, sm = 0.f;
  for (int r = rg; r < K; r += 8){
    float v = b2f_raw(p[(size_t)r*EMB]);
    mx = fmaxf(mx, v); sm += v;
  }
  smax[rg][c] = mx; ssum[rg][c] = sm;
  __syncthreads();
  if (rg == 0){
    #pragma unroll
    for (int u = 1; u < 8; u++){ mx = fmaxf(mx, smax[u][c]); sm += ssum[u][c]; }
    cat[g*1024 + col] = mx;
    cat[g*1024 + 512 + col] = sm / (float)K;
  }
}
// layer-2: fused gather + inline BN + scale + max/mean pool directly from Cc
__global__ __launch_bounds__(1024) void k_poolB(const bf16* __restrict__ h,
    const float* __restrict__ bnacc, int M,
    const float* __restrict__ gm, const float* __restrict__ be,
    const int* __restrict__ topi, const float* __restrict__ tops,
    float* __restrict__ cat, int n_per, int K){
  __shared__ int sti[256];
  __shared__ float sts[256];
  __shared__ float smax[8][128];
  __shared__ float ssum[8][128];
  int b = blockIdx.x, t = threadIdx.x;
  int g = b >> 2, cb = b & 3;
  for (int r = t; r < K; r += 1024){ sti[r] = topi[g*K + r]; sts[r] = tops[g*K + r]; }
  __syncthreads();
  int c = t & 127, rg = t >> 7;
  int col = cb*128 + c;
  float fM = (float)M;
  float mean, inv; bn_from_acc(bnacc, col, fM, mean, inv);
  float gg = gm[col], bb = be[col];
  const unsigned short* hp = (const unsigned short*)h;
  float mx = -INFINITY, sm = 0.f;
  for (int r = rg; r < K; r += 8){
    float v = (b2f_raw(hp[(size_t)(g*n_per + sti[r])*EMB + col]) - mean) * inv * gg + bb;
    v *= sts[r];
    mx = fmaxf(mx, v); sm += v;
  }
  smax[rg][c] = mx; ssum[rg][c] = sm;
  __syncthreads();
  if (rg == 0){
    #pragma unroll
    for (int u = 1; u < 8; u++){ mx = fmaxf(mx, smax[u][c]); sm += ssum[u][c]; }
    cat[g*1024 + col] = mx;
    cat[g*1024 + 512 + col] = sm / (float)K;
  }
}

// ======================= layer 2 aggregation =======================
__global__ __launch_bounds__(256) void k_agg2(
    const bf16* __restrict__ xn, const float* __restrict__ aso, const float* __restrict__ ado,
    const int* __restrict__ off, const int* __restrict__ esrc,
    bf16* __restrict__ oh){
  int n = blockIdx.x, t = threadIdx.x;
  __shared__ int srcs[MAXDEG];
  __shared__ float al[MAXDEG*3];
  __shared__ float mh[3], dh[3];
  int s0 = off[n]; int deg = off[n+1] - s0; if (deg > MAXDEG) deg = MAXDEG;
  for (int e = t; e < deg; e += 256) srcs[e] = esrc[s0 + e];
  __syncthreads();
  float ad0 = ado[n*3+0], ad1 = ado[n*3+1], ad2 = ado[n*3+2];
  for (int e = t; e < deg; e += 256){
    int s = srcs[e];
    float v0 = aso[s*3+0] + ad0, v1 = aso[s*3+1] + ad1, v2 = aso[s*3+2] + ad2;
    al[e*3+0] = v0 > 0.f ? v0 : 0.2f*v0;
    al[e*3+1] = v1 > 0.f ? v1 : 0.2f*v1;
    al[e*3+2] = v2 > 0.f ? v2 : 0.2f*v2;
  }
  __syncthreads();
  if (t < 3){
    float m = -INFINITY;
    for (int e = 0; e < deg; e++) m = fmaxf(m, al[e*3+t]);
    float d = 0.f;
    for (int e = 0; e < deg; e++) d += expf(al[e*3+t] - m);
    mh[t] = m; dh[t] = 1.f / fmaxf(d, 1e-16f);
  }
  __syncthreads();
  for (int e = t; e < deg; e += 256){
    al[e*3+0] = expf(al[e*3+0]-mh[0])*dh[0];
    al[e*3+1] = expf(al[e*3+1]-mh[1])*dh[1];
    al[e*3+2] = expf(al[e*3+2]-mh[2])*dh[2];
  }
  __syncthreads();
  float acc[2][3] = {};
  for (int e = 0; e < deg; e++){
    int s = srcs[e];
    float a0 = al[e*3], a1 = al[e*3+1], a2 = al[e*3+2];
    #pragma unroll
    for (int k = 0; k < 2; k++){
      float v = __bfloat162float(xn[(size_t)s*512 + t + k*256]);
      acc[k][0] += a0*v; acc[k][1] += a1*v; acc[k][2] += a2*v;
    }
  }
  #pragma unroll
  for (int k = 0; k < 2; k++){
    int c = t + k*256;
    #pragma unroll
    for (int h = 0; h < 3; h++)
      oh[(size_t)n*1536 + h*512 + c] = __float2bfloat16(acc[k][h]);
  }
}

// ======================= bf16-A x split-bf16-B MFMA GEMM (XCD-swizzled) =======================
__global__ __launch_bounds__(256, 2) void k_gemm_mfma(
    const bf16* __restrict__ Ah,
    const bf16* __restrict__ Bh, const bf16* __restrict__ Bl,   // [N][K] row-major
    const float* __restrict__ bias, bf16* __restrict__ C,
    float* __restrict__ bnacc,
    int M, int N, int K, int Mtiles){
  // XCD-aware mapping: all 8 bn-tiles of a given bm land on the same XCD,
  // so the A-tile is fetched ~once into that XCD's L2.
  int xcd = (int)blockIdx.x & 7;
  int ii  = (int)blockIdx.x >> 3;
  int bni = ii & 7;
  int bmi = xcd + 8*(ii >> 3);
  if (bmi >= Mtiles) return;
  __shared__ __align__(16) unsigned short lds[2][16384];   // 64 KB total
  int t = threadIdx.x, w = t >> 6, lane = t & 63;
  int q = lane >> 4, l16 = lane & 15;
  int bm = bmi * 128, bn = bni * 64;

  int lr = lane >> 3, lc = lane & 7;
  int kg = ((lc ^ lr) & 7) * 8;
  int ro = w*8 + lr;
  int m0 = bm + ro, m1 = bm + 32 + ro, m2 = bm + 64 + ro, m3 = bm + 96 + ro;
  if (m0 >= M) m0 = M-1;  if (m1 >= M) m1 = M-1;
  if (m2 >= M) m2 = M-1;  if (m3 >= M) m3 = M-1;
  int n0 = bn + ro, n1 = bn + 32 + ro;
  const bf16* ptr[8];
  ptr[0] = Ah + (size_t)m0*K + kg;
  ptr[1] = Ah + (size_t)m1*K + kg;
  ptr[2] = Ah + (size_t)m2*K + kg;
  ptr[3] = Ah + (size_t)m3*K + kg;
  ptr[4] = Bh + (size_t)n0*K + kg;
  ptr[5] = Bh + (size_t)n1*K + kg;
  ptr[6] = Bl + (size_t)n0*K + kg;
  ptr[7] = Bl + (size_t)n1*K + kg;
  const int dof[8] = {0, 2048, 4096, 6144, 8192, 10240, 12288, 14336};

  int wm = (w >> 1) * 64, wn = (w & 1) * 32;
  f32x4 acc[4][2];
  #pragma unroll
  for (int i = 0; i < 4; i++)
    #pragma unroll
    for (int j = 0; j < 2; j++)
      acc[i][j] = (f32x4){0.f, 0.f, 0.f, 0.f};

  #pragma unroll
  for (int u = 0; u < 8; u++){
    gld16(ptr[u], &lds[0][dof[u] + w*512]);
    ptr[u] += 64;
  }

  int nit = K >> 6;
  for (int it = 0; it < nit; it++){
    __syncthreads();
    int cur = it & 1;
    if (it + 1 < nit){
      int nxt = cur ^ 1;
      #pragma unroll
      for (int u = 0; u < 8; u++){
        gld16(ptr[u], &lds[nxt][dof[u] + w*512]);
        ptr[u] += 64;
      }
    }
    const unsigned short* L = lds[cur];
    #pragma unroll
    for (int ks = 0; ks < 2; ks++){
      short8 ah[4], bh2[2], bl2[2];
      int gc = ks*4 + q;
      #pragma unroll
      for (int i = 0; i < 4; i++){
        int r = wm + i*16 + l16;
        ah[i] = *(const short8*)(L + r*64 + ((gc ^ (r & 7)) << 3));
      }
      #pragma unroll
      for (int j = 0; j < 2; j++){
        int r = wn + j*16 + l16;
        int so = ((gc ^ (r & 7)) << 3);
        bh2[j] = *(const short8*)(L + 8192  + r*64 + so);
        bl2[j] = *(const short8*)(L + 12288 + r*64 + so);
      }
      #pragma unroll
      for (int i = 0; i < 4; i++)
        #pragma unroll
        for (int j = 0; j < 2; j++){
          acc[i][j] = __builtin_amdgcn_mfma_f32_16x16x32_bf16(ah[i], bh2[j], acc[i][j], 0, 0, 0);
          acc[i][j] = __builtin_amdgcn_mfma_f32_16x16x32_bf16(ah[i], bl2[j], acc[i][j], 0, 0, 0);
        }
    }
  }

  __syncthreads();
  float* cs = (float*)&lds[0][0];
  float* cq = cs + 128;
  int slot = w >> 1;
  #pragma unroll
  for (int j = 0; j < 2; j++){
    int c_local = wn + j*16 + l16;
    int c = bn + c_local;
    float bv = 0.f;
    if (bias){
      #pragma unroll
      for (int kc = 0; kc < 8; kc++) bv += bias[kc*512 + c];
    }
    float ls = 0.f, lq = 0.f;
    #pragma unroll
    for (int i = 0; i < 4; i++){
      int rb = bm + wm + i*16 + q*4;
      #pragma unroll
      for (int e = 0; e < 4; e++){
        int r = rb + e;
        if (r < M){
          float v = fmaxf(acc[i][j][e] + bv, 0.f);
          C[(size_t)r*N + c] = __float2bfloat16(v);
          ls += v; lq += v*v;
        }
      }
    }
    ls += __shfl_xor(ls, 16); ls += __shfl_xor(ls, 32);
    lq += __shfl_xor(lq, 16); lq += __shfl_xor(lq, 32);
    if (q == 0){ cs[slot*64 + c_local] = ls; cq[slot*64 + c_local] = lq; }
  }
  __syncthreads();
  if (t < 64){
    atomicAdd(&bnacc[bn + t],        cs[t] + cs[64 + t]);
    atomicAdd(&bnacc[512 + bn + t],  cq[t] + cq[64 + t]);
  }
}

// ======================= fused head (one block per graph) =======================
__global__ __launch_bounds__(1024) void k_head(const float* __restrict__ c1,
    const float* __restrict__ c2, const float* __restrict__ Wl1,
    const float* __restrict__ bl1, const float* __restrict__ Wl2,
    const float* __restrict__ bl2, float* __restrict__ out){
  int g = blockIdx.x, t = threadIdx.x;
  __shared__ float xg[1024];
  __shared__ float t1[512];
  __shared__ float part[2][512];
  xg[t] = c1[g*1024 + t] + c2[g*1024 + t];
  __syncthreads();
  int c = t & 511, kc = t >> 9;
  float acc = 0.f;
  #pragma unroll 8
  for (int k = kc*512; k < kc*512 + 512; k++)
    acc += xg[k] * Wl1[(size_t)k*512 + c];
  part[kc][c] = acc;
  __syncthreads();
  if (kc == 0) t1[c] = fmaxf(part[0][c] + part[1][c] + bl1[c], 0.f);
  __syncthreads();
  if (t < 512){
    int c2i = t & 255, k2 = t >> 8;
    float a = 0.f;
    #pragma unroll 8
    for (int k = k2*256; k < k2*256 + 256; k++)
      a += t1[k] * Wl2[(size_t)k*256 + c2i];
    part[k2][c2i] = a;
  }
  __syncthreads();
  if (t < 256)
    out[g*256 + t] = part[0][t] + part[1][t] + bl2[t];
}

extern "C" void kernel_launch(void* const* d_in, const int* in_sizes, int n_in,
                              void* d_out, int out_size, void* d_ws, size_t ws_size,
                              hipStream_t stream){
  const float* x   = (const float*)d_in[0];
  const int*   ei  = (const int*)d_in[1];
  const float* W1  = (const float*)d_in[2];
  const float* as1 = (const float*)d_in[3];
  const float* ad1 = (const float*)d_in[4];
  const float* bc1 = (const float*)d_in[5];
  const float* Wh1 = (const float*)d_in[6];
  const float* bh1 = (const float*)d_in[7];
  const float* g1  = (const float*)d_in[8];
  const float* be1 = (const float*)d_in[9];
  const float* p1  = (const float*)d_in[10];
  const float* W2  = (const float*)d_in[11];
  const float* as2 = (const float*)d_in[12];
  const float* ad2 = (const float*)d_in[13];
  const float* bc2 = (const float*)d_in[14];
  const float* Wh2 = (const float*)d_in[15];
  const float* bh2 = (const float*)d_in[16];
  const float* g2  = (const float*)d_in[17];
  const float* be2 = (const float*)d_in[18];
  const float* p2  = (const float*)d_in[19];
  const float* Wl1 = (const float*)d_in[20];
  const float* bl1 = (const float*)d_in[21];
  const float* Wl2 = (const float*)d_in[22];
  const float* bl2 = (const float*)d_in[23];
  float* out = (float*)d_out;

  const int* src0 = ei;
  const int* tgt0 = ei + E_EDGES;

  // ---- workspace layout ----
  bf16* Cc      = (bf16*)d_ws;                       // NN1*EMB
  bf16* xn1     = Cc + (size_t)NN1*EMB;              // NN2*EMB
  bf16* aggx2h  = xn1 + (size_t)NN2*EMB;             // NN2*F1
  bf16* M2Th    = aggx2h + (size_t)NN2*F1;           // EMB*F1
  bf16* M2Tl    = M2Th + (size_t)EMB*F1;             // EMB*F1
  float* holeA  = (float*)(M2Tl + (size_t)EMB*F1);   // (old num/den hole, 122880 floats)
  float* bnacc1 = holeA + 122880;                    // 1024
  float* bnacc  = bnacc1 + 1024;                     // 1024
  float* M1p    = bnacc + 1024;                      // 4*4608
  float* cvp    = M1p + 4*4608;                      // 16*512 (cvp2 = cvp + 8*512)
  float* was2   = cvp + 16*512;                      // 3*512
  float* wad2   = was2 + 3*512;                      // 3*512
  float* was1   = wad2 + 3*512;                      // 16
  float* wad1   = was1 + 16;                         // 16
  float* aso2   = wad1 + 16;                         // NN2*3
  float* ado2   = aso2 + (size_t)NN2*3;              // NN2*3
  float* tops   = ado2 + (size_t)NN2*3;              // NG*KP1
  float* cat1   = tops + NG*KP1;                     // 16*1024
  float* cat2   = cat1 + NG*1024;                    // 16*1024
  int* topi     = (int*)(cat2 + NG*1024);            // NG*KP1
  int* map      = topi + NG*KP1;                     // NN1
  int* cnt2     = map + NN1;                         // NN2
  int* off2     = cnt2 + NN2;                        // NN2+8
  int* cur2     = off2 + NN2 + 8;                    // NN2
  int* esrc2    = cur2 + NN2;                        // E+NN2 (+pad 137700)
  float* nump   = (float*)(esrc2 + 137700);          // 256*4608 (chunk partials)
  float* denp   = nump + (size_t)256*4608;           // 256*1536
  float* cvp2   = cvp + 8*512;

  // 1. mega precompute: init + watt + M1p/cvp + gemm_s
  k_pre<<<428,256,0,stream>>>(W1,as1,ad1,Wh1,bc1,bh1, W2,as2,ad2,Wh2,bc2,bh2,
                              was1,wad1,M1p,cvp,was2,wad2,
                              bnacc1,cnt2,map,M2Th,M2Tl);
  // 2. layer-1 segment softmax: 16 chunks/graph, LDS-private, no global atomics
  k_edge<<<256,256,0,stream>>>(src0,tgt0,x,was1,wad1,denp,nump);
  // 3. h1 + chunk reduction + BN partials
  k_h1<<<NN1/32,256,0,stream>>>(nump,denp,M1p,cvp,Cc,bnacc1);
  // 4. fused score+sort (layer 1)
  k_scoresort<<<NG,512,0,stream>>>(Cc,bnacc1,NN1,g1,be1,p1,NP1,KP1,map,topi,tops);
  // 5. gather + attention dots + count2
  k_gather_c2<<<NG*KP1+512,256,0,stream>>>(Cc,bnacc1,NN1,g1,be1,topi,tops,xn1,NP1,KP1,
      was2,wad2,aso2,ado2, src0,tgt0,map,cnt2,NG*KP1);
  // 6. poolA + scan2
  k_poolA_scan<<<65,1024,0,stream>>>(xn1,cat1,KP1, cnt2,off2,cur2);
  // 7. fill2
  k_fill2<<<(E_EDGES+NN2+255)/256,256,0,stream>>>(src0,tgt0,map,cur2,esrc2,E_EDGES,NN2);
  // 8. agg2
  k_agg2<<<NN2,256,0,stream>>>(xn1,aso2,ado2,off2,esrc2,aggx2h);
  // 9. big GEMM (XCD-swizzled, grid 56*8 with guard)
  k_gemm_mfma<<<448,256,0,stream>>>(aggx2h,M2Th,M2Tl,cvp2,Cc,bnacc,NN2,EMB,F1,52);
  // 10. fused score+sort (layer 2)
  k_scoresort<<<NG,512,0,stream>>>(Cc,bnacc,NN2,g2,be2,p2,KP1,KP2,(int*)nullptr,topi,tops);
  // 11. poolB
  k_poolB<<<64,1024,0,stream>>>(Cc,bnacc,NN2,g2,be2,topi,tops,cat2,KP1,KP2);
  // 12. fused head
  k_head<<<NG,1024,0,stream>>>(cat1,cat2,Wl1,bl1,Wl2,bl2,out);
}

// Round 8
// 314.201 us; speedup vs baseline: 1.4444x; 1.0516x over previous
//
#include <hip/hip_runtime.h>
#include <hip/hip_bf16.h>
#include <math.h>

#define E_EDGES 131072
#define NN1 8192
#define NN2 6560          // 16*410
#define NG 16
#define NP1 512
#define KP1 410
#define KP2 205
#define F1 1536
#define EMB 512
#define MAXDEG 256

typedef __hip_bfloat16 bf16;
typedef __attribute__((ext_vector_type(8))) short short8;
typedef __attribute__((ext_vector_type(4))) float f32x4;
typedef __attribute__((ext_vector_type(4))) unsigned short us4;

__device__ inline float wred64(float v){
  #pragma unroll
  for (int o = 32; o; o >>= 1) v += __shfl_down(v, o);
  return v;
}
__device__ inline float b2f_raw(unsigned short u){
  return __uint_as_float((unsigned)u << 16);
}
union BFU { bf16 b; unsigned short u; };
__device__ inline unsigned short f2u(float v){ BFU x; x.b = __float2bfloat16(v); return x.u; }

__device__ __forceinline__ void gld16(const void* g, void* l){
  __builtin_amdgcn_global_load_lds(
      (const __attribute__((address_space(1))) void*)g,
      (__attribute__((address_space(3))) void*)l, 16, 0, 0);
}

__device__ inline void split_store(float v, bf16* __restrict__ ph, bf16* __restrict__ pl){
  bf16 hi = __float2bfloat16(v);
  *ph = hi;
  *pl = __float2bfloat16(v - __bfloat162float(hi));
}

// inline BN stats from raw sums
__device__ inline void bn_from_acc(const float* __restrict__ bnacc, int c, float fM,
                                   float& mean, float& inv){
  mean = bnacc[c] / fM;
  float var = fmaxf(bnacc[512+c]/fM - mean*mean, 0.f);
  inv = 1.f / sqrtf(var + 1e-5f);
}

// ======================= mega precompute =======================
// [0,24): M1 partials  [24,56): cvec partials  [56,152): watt2
// [152,170): watt1     [170,236): init (bnacc zero / cnt2=1 / map=-1)
// [236,428): gemm_s 64x64 split-bf16 MFMA tiles (W2@Wh2 -> M2T split)
__global__ __launch_bounds__(256) void k_pre(
    const float* __restrict__ W1, const float* __restrict__ as1, const float* __restrict__ ad1,
    const float* __restrict__ Wh1, const float* __restrict__ bc1, const float* __restrict__ bh1,
    const float* __restrict__ W2, const float* __restrict__ as2, const float* __restrict__ ad2,
    const float* __restrict__ Wh2, const float* __restrict__ bc2, const float* __restrict__ bh2,
    float* __restrict__ was1, float* __restrict__ wad1, float* __restrict__ M1p,
    float* __restrict__ cvp,
    float* __restrict__ was2, float* __restrict__ wad2,
    float* __restrict__ Zb, int* __restrict__ cnt2, int* __restrict__ map,
    bf16* __restrict__ Th, bf16* __restrict__ Tl){
  int b = blockIdx.x, t = threadIdx.x;
  if (b < 24){                               // M1 partials
    int h = b / 8, rem = b % 8, jh = rem >> 2, kc = rem & 3;
    int j = jh*256 + t, c0 = kc*128;
    __shared__ float w1s[3][128];
    for (int i = t; i < 384; i += 256)
      w1s[i>>7][i&127] = W1[(i>>7)*1536 + h*512 + c0 + (i&127)];
    __syncthreads();
    const float* whc = Wh1 + (size_t)(h*512 + c0)*512 + j;
    float a0=0.f, a1=0.f, a2=0.f;
    #pragma unroll 8
    for (int c = 0; c < 128; c++){
      float v = whc[(size_t)c*512];
      a0 += w1s[0][c]*v; a1 += w1s[1][c]*v; a2 += w1s[2][c]*v;
    }
    float* dst = M1p + (size_t)kc*4608;
    dst[(h*3+0)*512 + j] = a0;
    dst[(h*3+1)*512 + j] = a1;
    dst[(h*3+2)*512 + j] = a2;
  } else if (b < 56){                        // cvec partials
    int b2 = b - 24;
    int which = b2 >> 4, rem = b2 & 15, jh = rem >> 3, kc = rem & 7;
    const float* bc = which ? bc2 : bc1;
    const float* Wh = which ? Wh2 : Wh1;
    const float* bh = which ? bh2 : bh1;
    int j = jh*256 + t, i0 = kc*192;
    float acc = (kc == 0) ? bh[j] : 0.f;
    #pragma unroll 8
    for (int i = 0; i < 192; i++)
      acc += bc[i0+i] * Wh[(size_t)(i0+i)*512 + j];
    cvp[(size_t)(which*8 + kc)*512 + j] = acc;
  } else if (b < 152){                       // watt2
    int b3 = b - 56;
    int y = b3 >> 4, et = b3 & 15;
    int kind = y / 3, h = y % 3;
    int w = t >> 6, lane = t & 63;
    const float* att = kind ? ad2 : as2;
    float a[8];
    #pragma unroll
    for (int u = 0; u < 8; u++) a[u] = att[h*512 + lane*8 + u];
    for (int r = w; r < 32; r += 4){
      int e = et*32 + r;
      const float4* row = (const float4*)(W2 + (size_t)e*1536 + h*512) + lane*2;
      float4 v0 = row[0], v1 = row[1];
      float d = v0.x*a[0]+v0.y*a[1]+v0.z*a[2]+v0.w*a[3]
              + v1.x*a[4]+v1.y*a[5]+v1.z*a[6]+v1.w*a[7];
      d = wred64(d);
      if (lane == 0) (kind ? wad2 : was2)[h*512 + e] = d;
    }
  } else if (b < 170){                       // watt1
    if (t < 64){
      int bb = b - 152;
      int kind = bb / 9, r = bb % 9, h = r / 3, f = r % 3;
      const float* att = kind ? ad1 : as1;
      float s = 0.f;
      for (int c = t; c < 512; c += 64) s += W1[f*1536 + h*512 + c] * att[h*512 + c];
      s = wred64(s);
      if (t == 0) (kind ? wad1 : was1)[h*3 + f] = s;
    }
  } else if (b < 236){                       // init
    int i = (b - 170)*256 + t;
    if (i < 2048){ Zb[i] = 0.f; }                         // bnacc1|bnacc
    else if (i < 2048 + NN2){ cnt2[i - 2048] = 1; }
    else if (i < 2048 + NN2 + NN1){ map[i - 2048 - NN2] = -1; }
  } else {                                   // gemm_s tiles
    int bb = b - 236;
    int z = bb % 3; int rr = bb / 3; int by = rr >> 3, bx = rr & 7;
    const float* A = W2 + (size_t)z*512;            // row stride 1536
    const float* B = Wh2 + (size_t)z*512*512;       // row stride 512
    __shared__ __align__(16) short sAh[4096], sAl[4096], sBh[4096], sBl[4096];
    int w = t >> 6, lane = t & 63;
    int l16 = lane & 15, q = lane >> 4;
    int bm = by*64, bn = bx*64;
    int am  = t >> 2, akw = (t & 3)*16;
    int bnl = t & 63, bkq = (t >> 6)*16;
    f32x4 acc[4];
    #pragma unroll
    for (int nf = 0; nf < 4; nf++) acc[nf] = (f32x4){0.f,0.f,0.f,0.f};
    float va[16], vb[16];
    #define GS_LOAD(K0) do { \
      _Pragma("unroll") for (int u = 0; u < 4; u++){ \
        float4 v4 = *(const float4*)(A + (size_t)(bm+am)*1536 + (K0) + akw + u*4); \
        va[u*4]=v4.x; va[u*4+1]=v4.y; va[u*4+2]=v4.z; va[u*4+3]=v4.w; } \
      _Pragma("unroll") for (int u = 0; u < 16; u++) \
        vb[u] = B[(size_t)((K0) + bkq + u)*512 + bn + bnl]; \
    } while(0)
    GS_LOAD(0);
    for (int it = 0; it < 8; it++){
      #pragma unroll
      for (int hh = 0; hh < 2; hh++){
        short8 ah_, al_, bh_, bl_;
        #pragma unroll
        for (int jj = 0; jj < 8; jj++){
          float v = va[hh*8+jj];
          unsigned short hu = f2u(v);
          ah_[jj] = (short)hu; al_[jj] = (short)f2u(v - b2f_raw(hu));
          v = vb[hh*8+jj];
          hu = f2u(v);
          bh_[jj] = (short)hu; bl_[jj] = (short)f2u(v - b2f_raw(hu));
        }
        int aoff = am*64  + ((((akw>>3) + hh) ^ (am  & 7)) << 3);
        *(short8*)(sAh + aoff) = ah_;
        *(short8*)(sAl + aoff) = al_;
        int boff = bnl*64 + ((((bkq>>3) + hh) ^ (bnl & 7)) << 3);
        *(short8*)(sBh + boff) = bh_;
        *(short8*)(sBl + boff) = bl_;
      }
      __syncthreads();
      if (it < 7) GS_LOAD((it+1)*64);
      #pragma unroll
      for (int ks = 0; ks < 2; ks++){
        int gc = ks*4 + q;
        int ar = w*16 + l16;
        int ao = ar*64 + ((gc ^ (ar & 7)) << 3);
        short8 afh = *(const short8*)(sAh + ao);
        short8 afl = *(const short8*)(sAl + ao);
        #pragma unroll
        for (int nf = 0; nf < 4; nf++){
          int br = nf*16 + l16;
          int bo = br*64 + ((gc ^ (br & 7)) << 3);
          short8 bfh = *(const short8*)(sBh + bo);
          short8 bfl = *(const short8*)(sBl + bo);
          acc[nf] = __builtin_amdgcn_mfma_f32_16x16x32_bf16(afh, bfh, acc[nf], 0, 0, 0);
          acc[nf] = __builtin_amdgcn_mfma_f32_16x16x32_bf16(afh, bfl, acc[nf], 0, 0, 0);
          acc[nf] = __builtin_amdgcn_mfma_f32_16x16x32_bf16(afl, bfh, acc[nf], 0, 0, 0);
        }
      }
      __syncthreads();
    }
    #undef GS_LOAD
    int m0 = bm + w*16 + q*4;
    #pragma unroll
    for (int nf = 0; nf < 4; nf++){
      int n = bn + nf*16 + l16;
      size_t base = (size_t)n*1536 + (size_t)z*512 + m0;
      #pragma unroll
      for (int e = 0; e < 4; e++)
        split_store(acc[nf][e], &Th[base+e], &Tl[base+e]);
    }
  }
}

// ======================= layer-1 segment softmax, chunked LDS-private =======================
// 16 chunks per graph (256 blocks, 1/CU). Single pass: logits are
// leaky_relu of tiny dot products (|v| < ~1) so exp without max-subtraction is
// exactly equivalent (the max cancels in the softmax ratio) and numerically safe.
__global__ __launch_bounds__(256) void k_edge(
    const int* __restrict__ src0, const int* __restrict__ tgt0, const float* __restrict__ x,
    const float* __restrict__ was, const float* __restrict__ wad,
    float* __restrict__ denp, float* __restrict__ nump){
  int b = blockIdx.x, t = threadIdx.x;
  int g = b >> 4, ch = b & 15;
  __shared__ float lden[1536];
  __shared__ float lnum[4608];
  for (int i = t; i < 1536; i += 256) lden[i] = 0.f;
  for (int i = t; i < 4608; i += 256) lnum[i] = 0.f;
  __syncthreads();
  int base = g*8192;
  int it0 = ch*544;                       // 16*544 = 8704 items (8192 edges + 512 self-loops)
  for (int k = t; k < 544; k += 256){
    int it = it0 + k;
    int s, tl;
    if (it < 8192){ s = src0[base+it]; tl = tgt0[base+it] & 511; }
    else { tl = it - 8192; s = g*512 + tl; }
    float xs0 = x[s*3], xs1 = x[s*3+1], xs2 = x[s*3+2];
    int tg = g*512 + tl;
    float xt0 = x[tg*3], xt1 = x[tg*3+1], xt2 = x[tg*3+2];
    #pragma unroll
    for (int h = 0; h < 3; h++){
      float v = xs0*was[h*3]+xs1*was[h*3+1]+xs2*was[h*3+2]
              + xt0*wad[h*3]+xt1*wad[h*3+1]+xt2*wad[h*3+2];
      v = v > 0.f ? v : 0.2f*v;
      float pe = expf(v);
      atomicAdd(&lden[tl*3 + h], pe);
      atomicAdd(&lnum[tl*9 + h*3 + 0], pe * xs0);
      atomicAdd(&lnum[tl*9 + h*3 + 1], pe * xs1);
      atomicAdd(&lnum[tl*9 + h*3 + 2], pe * xs2);
    }
  }
  __syncthreads();
  for (int i = t; i < 4608; i += 256) nump[(size_t)b*4608 + i] = lnum[i];
  for (int i = t; i < 1536; i += 256) denp[(size_t)b*1536 + i] = lden[i];
}

// h1[n,j] = relu(cvec[j] + sum_q (num/den)[n,q]*M1[q,j]) -> bf16 ; fused BN partials.
__global__ __launch_bounds__(256) void k_h1(
    const float* __restrict__ nump, const float* __restrict__ denp,
    const float* __restrict__ M1p, const float* __restrict__ cvp1, bf16* __restrict__ hout,
    float* __restrict__ bnacc1){
  __shared__ float sM[9*512];
  __shared__ float sC[512];
  __shared__ float sA[32*9];
  int t = threadIdx.x; int n0 = blockIdx.x*32;
  for (int i = t; i < 9*512; i += 256)
    sM[i] = M1p[i] + M1p[4608 + i] + M1p[2*4608 + i] + M1p[3*4608 + i];
  for (int i = t; i < 512; i += 256){
    float s = 0.f;
    #pragma unroll
    for (int kc = 0; kc < 8; kc++) s += cvp1[kc*512 + i];
    sC[i] = s;
  }
  for (int i = t; i < 288; i += 256){
    int node = i / 9, q = i % 9, hh = q / 3;
    int gn = n0 + node;
    int g = gn >> 9, nl = gn & 511;
    float ns = 0.f, ds = 0.f;
    #pragma unroll 4
    for (int ch = 0; ch < 16; ch++){
      ns += nump[(size_t)(g*16 + ch)*4608 + nl*9 + q];
      ds += denp[(size_t)(g*16 + ch)*1536 + nl*3 + hh];
    }
    sA[i] = ns / fmaxf(ds, 1e-16f);
  }
  __syncthreads();
  float c0v = sC[t], c1v = sC[t+256];
  float ls0=0.f, lq0=0.f, ls1=0.f, lq1=0.f;
  #pragma unroll 4
  for (int i = 0; i < 32; i++){
    float a0 = c0v, a1 = c1v;
    #pragma unroll
    for (int q = 0; q < 9; q++){
      float av = sA[i*9+q];
      a0 += av * sM[q*512 + t];
      a1 += av * sM[q*512 + t + 256];
    }
    a0 = fmaxf(a0, 0.f); a1 = fmaxf(a1, 0.f);
    hout[(size_t)(n0+i)*512 + t]       = __float2bfloat16(a0);
    hout[(size_t)(n0+i)*512 + t + 256] = __float2bfloat16(a1);
    ls0 += a0; lq0 += a0*a0; ls1 += a1; lq1 += a1*a1;
  }
  atomicAdd(&bnacc1[t],           ls0);
  atomicAdd(&bnacc1[t+256],       ls1);
  atomicAdd(&bnacc1[512 + t],     lq0);
  atomicAdd(&bnacc1[512 + t+256], lq1);
}

// ======================= fused score + top-k sort (one block per graph) =======================
__global__ __launch_bounds__(512) void k_scoresort(
    const bf16* __restrict__ h, const float* __restrict__ bnacc, int M,
    const float* __restrict__ g_, const float* __restrict__ be, const float* __restrict__ p,
    int n_per, int K, int* __restrict__ map,
    int* __restrict__ topi, float* __restrict__ tops){
  int g = blockIdx.x, t = threadIdx.x;
  __shared__ float w[512];
  __shared__ float redb[8], redp[8];
  __shared__ float sk[512];
  __shared__ int si[512];
  float fM = (float)M;
  float mean, inv; bn_from_acc(bnacc, t, fM, mean, inv);
  float gc = g_[t], pc = p[t];
  float ig = inv * gc;
  w[t] = ig * pc;
  float bt = (be[t] - mean * ig) * pc;
  float b_ = wred64(bt);
  float pp = wred64(pc * pc);
  int lane = t & 63, wv = t >> 6;
  if (lane == 0){ redb[wv] = b_; redp[wv] = pp; }
  __syncthreads();
  float B0 = 0.f, pn2 = 0.f;
  #pragma unroll
  for (int u = 0; u < 8; u++){ B0 += redb[u]; pn2 += redp[u]; }
  float pn = sqrtf(pn2);
  float score = -INFINITY; int idx = 0x7fffffff;
  if (t < n_per){
    const unsigned short* hr = (const unsigned short*)h + (size_t)(g*n_per + t)*EMB;
    float dot = 0.f;
    #pragma unroll 4
    for (int c = 0; c < 512; c += 8){
      us4 v0 = *(const us4*)(hr + c);
      us4 v1 = *(const us4*)(hr + c + 4);
      dot += b2f_raw(v0.x)*w[c]   + b2f_raw(v0.y)*w[c+1]
           + b2f_raw(v0.z)*w[c+2] + b2f_raw(v0.w)*w[c+3]
           + b2f_raw(v1.x)*w[c+4] + b2f_raw(v1.y)*w[c+5]
           + b2f_raw(v1.z)*w[c+6] + b2f_raw(v1.w)*w[c+7];
    }
    score = tanhf((dot + B0) / pn);
    idx = t;
  }
  sk[t] = score; si[t] = idx;
  __syncthreads();
  for (int k = 2; k <= 512; k <<= 1){
    for (int j = k >> 1; j > 0; j >>= 1){
      int l = t ^ j;
      if (l > t){
        float ki = sk[t], kl = sk[l]; int ii = si[t], il = si[l];
        bool before_l = (kl > ki) || (kl == ki && il < ii);
        bool up = ((t & k) == 0);
        if (up == before_l){ sk[t]=kl; sk[l]=ki; si[t]=il; si[l]=ii; }
      }
      __syncthreads();
    }
  }
  if (t < K){
    if (map) map[g*n_per + si[t]] = g*K + t;
    topi[g*K + t] = si[t];
    tops[g*K + t] = sk[t];
  }
}

// gather + inline BN + scale -> bf16; fused layer-2 attention dots; fused count2 tail
__global__ __launch_bounds__(256) void k_gather_c2(
    const bf16* __restrict__ h, const float* __restrict__ bnacc, int M,
    const float* __restrict__ gm, const float* __restrict__ be,
    const int* __restrict__ topi, const float* __restrict__ tops,
    bf16* __restrict__ xn, int n_per, int K,
    const float* __restrict__ was2, const float* __restrict__ wad2,
    float* __restrict__ aso, float* __restrict__ ado,
    const int* __restrict__ src0, const int* __restrict__ tgt0,
    const int* __restrict__ map, int* __restrict__ cnt2, int nblk_g){
  int row = blockIdx.x, t = threadIdx.x;
  if (row >= nblk_g){                      // count2 tail
    int i = (row - nblk_g)*256 + t;
    if (i < E_EDGES){
      int s = map[src0[i]], tg = map[tgt0[i]];
      if (s >= 0 && tg >= 0) atomicAdd(&cnt2[tg], 1);
    }
    return;
  }
  int gr = row / K, i = row - gr*K;
  int sidx = topi[gr*K + i];
  float s = tops[gr*K + i];
  const bf16* src = h + ((size_t)(gr*n_per + sidx))*EMB;
  bf16* dst = xn + (size_t)row*EMB;
  int c0 = t, c1 = t + 256;
  float fM = (float)M;
  float mean0, inv0, mean1, inv1;
  bn_from_acc(bnacc, c0, fM, mean0, inv0);
  bn_from_acc(bnacc, c1, fM, mean1, inv1);
  float v0 = ((__bfloat162float(src[c0]) - mean0) * inv0 * gm[c0] + be[c0]) * s;
  float v1 = ((__bfloat162float(src[c1]) - mean1) * inv1 * gm[c1] + be[c1]) * s;
  dst[c0] = __float2bfloat16(v0);
  dst[c1] = __float2bfloat16(v1);
  {
    float a[6];
    #pragma unroll
    for (int hh = 0; hh < 3; hh++){
      a[hh]   = v0*was2[hh*512 + c0] + v1*was2[hh*512 + c1];
      a[3+hh] = v0*wad2[hh*512 + c0] + v1*wad2[hh*512 + c1];
    }
    __shared__ float red[6][4];
    int lane = t & 63, wv = t >> 6;
    #pragma unroll
    for (int q = 0; q < 6; q++){ float v = wred64(a[q]); if (lane==0) red[q][wv]=v; }
    __syncthreads();
    if (t < 6){
      float sm = red[t][0]+red[t][1]+red[t][2]+red[t][3];
      if (t < 3) aso[row*3+t] = sm; else ado[row*3+(t-3)] = sm;
    }
  }
}

// ======================= CSR (layer 2) =======================
__device__ inline void scan_body(const int* __restrict__ counts, int* __restrict__ off,
                                 int* __restrict__ cur, int n, int* __restrict__ sh){
  int t = threadIdx.x;
  int chunk = (n + 1023) >> 10;
  int b = t * chunk; int e = b + chunk; if (e > n) e = n;
  int s = 0;
  for (int i = b; i < e; i++) s += counts[i];
  sh[t] = s; __syncthreads();
  for (int o = 1; o < 1024; o <<= 1){
    int v = (t >= o) ? sh[t-o] : 0;
    __syncthreads();
    sh[t] += v;
    __syncthreads();
  }
  int run = (t > 0) ? sh[t-1] : 0;
  for (int i = b; i < e; i++){ int c = counts[i]; off[i] = run; cur[i] = run; run += c; }
  if (t == 1023) off[n] = sh[1023];
}
__global__ void k_fill2(const int* __restrict__ src0, const int* __restrict__ tgt0,
                        const int* __restrict__ map, int* __restrict__ cur,
                        int* __restrict__ esrc, int E, int nn){
  int i = blockIdx.x*blockDim.x + threadIdx.x;
  if (i >= E + nn) return;
  int s, tg;
  if (i < E){
    s = map[src0[i]]; tg = map[tgt0[i]];
    if (s < 0 || tg < 0) return;
  } else { s = i - E; tg = s; }
  int pos = atomicAdd(&cur[tg], 1);
  esrc[pos] = s;
}

// ======================= pooling =======================
// blocks [0,64): poolA over xn1; block 64: scan(cnt2)
__global__ __launch_bounds__(1024) void k_poolA_scan(const bf16* __restrict__ xn,
    float* __restrict__ cat, int K,
    const int* __restrict__ cnt2, int* __restrict__ off2, int* __restrict__ cur2){
  __shared__ int shi[1024];
  __shared__ float smax[8][128];
  __shared__ float ssum[8][128];
  int b = blockIdx.x, t = threadIdx.x;
  if (b == 64){ scan_body(cnt2, off2, cur2, NN2, shi); return; }
  int g = b >> 2, cb = b & 3;
  int c = t & 127, rg = t >> 7;
  int col = cb*128 + c;
  const unsigned short* p = (const unsigned short*)xn + (size_t)g*K*EMB + col;
  float mx = -INFINITY, sm = 0.f;
  for (int r = rg; r < K; r += 8){
    float v = b2f_raw(p[(size_t)r*EMB]);
    mx = fmaxf(mx, v); sm += v;
  }
  smax[rg][c] = mx; ssum[rg][c] = sm;
  __syncthreads();
  if (rg == 0){
    #pragma unroll
    for (int u = 1; u < 8; u++){ mx = fmaxf(mx, smax[u][c]); sm += ssum[u][c]; }
    cat[g*1024 + col] = mx;
    cat[g*1024 + 512 + col] = sm / (float)K;
  }
}
// layer-2: fused gather + inline BN + scale + max/mean pool directly from Cc
__global__ __launch_bounds__(1024) void k_poolB(const bf16* __restrict__ h,
    const float* __restrict__ bnacc, int M,
    const float* __restrict__ gm, const float* __restrict__ be,
    const int* __restrict__ topi, const float* __restrict__ tops,
    float* __restrict__ cat, int n_per, int K){
  __shared__ int sti[256];
  __shared__ float sts[256];
  __shared__ float smax[8][128];
  __shared__ float ssum[8][128];
  int b = blockIdx.x, t = threadIdx.x;
  int g = b >> 2, cb = b & 3;
  for (int r = t; r < K; r += 1024){ sti[r] = topi[g*K + r]; sts[r] = tops[g*K + r]; }
  __syncthreads();
  int c = t & 127, rg = t >> 7;
  int col = cb*128 + c;
  float fM = (float)M;
  float mean, inv; bn_from_acc(bnacc, col, fM, mean, inv);
  float gg = gm[col], bb = be[col];
  const unsigned short* hp = (const unsigned short*)h;
  float mx = -INFINITY, sm = 0.f;
  for (int r = rg; r < K; r += 8){
    float v = (b2f_raw(hp[(size_t)(g*n_per + sti[r])*EMB + col]) - mean) * inv * gg + bb;
    v *= sts[r];
    mx = fmaxf(mx, v); sm += v;
  }
  smax[rg][c] = mx; ssum[rg][c] = sm;
  __syncthreads();
  if (rg == 0){
    #pragma unroll
    for (int u = 1; u < 8; u++){ mx = fmaxf(mx, smax[u][c]); sm += ssum[u][c]; }
    cat[g*1024 + col] = mx;
    cat[g*1024 + 512 + col] = sm / (float)K;
  }
}

// ======================= layer 2 aggregation =======================
__global__ __launch_bounds__(256) void k_agg2(
    const bf16* __restrict__ xn, const float* __restrict__ aso, const float* __restrict__ ado,
    const int* __restrict__ off, const int* __restrict__ esrc,
    bf16* __restrict__ oh){
  int n = blockIdx.x, t = threadIdx.x;
  __shared__ int srcs[MAXDEG];
  __shared__ float al[MAXDEG*3];
  __shared__ float mh[3], dh[3];
  int s0 = off[n]; int deg = off[n+1] - s0; if (deg > MAXDEG) deg = MAXDEG;
  for (int e = t; e < deg; e += 256) srcs[e] = esrc[s0 + e];
  __syncthreads();
  float ad0 = ado[n*3+0], ad1 = ado[n*3+1], ad2 = ado[n*3+2];
  for (int e = t; e < deg; e += 256){
    int s = srcs[e];
    float v0 = aso[s*3+0] + ad0, v1 = aso[s*3+1] + ad1, v2 = aso[s*3+2] + ad2;
    al[e*3+0] = v0 > 0.f ? v0 : 0.2f*v0;
    al[e*3+1] = v1 > 0.f ? v1 : 0.2f*v1;
    al[e*3+2] = v2 > 0.f ? v2 : 0.2f*v2;
  }
  __syncthreads();
  if (t < 3){
    float m = -INFINITY;
    for (int e = 0; e < deg; e++) m = fmaxf(m, al[e*3+t]);
    float d = 0.f;
    for (int e = 0; e < deg; e++) d += expf(al[e*3+t] - m);
    mh[t] = m; dh[t] = 1.f / fmaxf(d, 1e-16f);
  }
  __syncthreads();
  for (int e = t; e < deg; e += 256){
    al[e*3+0] = expf(al[e*3+0]-mh[0])*dh[0];
    al[e*3+1] = expf(al[e*3+1]-mh[1])*dh[1];
    al[e*3+2] = expf(al[e*3+2]-mh[2])*dh[2];
  }
  __syncthreads();
  float acc[2][3] = {};
  for (int e = 0; e < deg; e++){
    int s = srcs[e];
    float a0 = al[e*3], a1 = al[e*3+1], a2 = al[e*3+2];
    #pragma unroll
    for (int k = 0; k < 2; k++){
      float v = __bfloat162float(xn[(size_t)s*512 + t + k*256]);
      acc[k][0] += a0*v; acc[k][1] += a1*v; acc[k][2] += a2*v;
    }
  }
  #pragma unroll
  for (int k = 0; k < 2; k++){
    int c = t + k*256;
    #pragma unroll
    for (int h = 0; h < 3; h++)
      oh[(size_t)n*1536 + h*512 + c] = __float2bfloat16(acc[k][h]);
  }
}

// ======================= bf16-A x split-bf16-B MFMA GEMM (XCD-swizzled) =======================
__global__ __launch_bounds__(256, 2) void k_gemm_mfma(
    const bf16* __restrict__ Ah,
    const bf16* __restrict__ Bh, const bf16* __restrict__ Bl,   // [N][K] row-major
    const float* __restrict__ bias, bf16* __restrict__ C,
    float* __restrict__ bnacc,
    int M, int N, int K, int Mtiles){
  int xcd = (int)blockIdx.x & 7;
  int ii  = (int)blockIdx.x >> 3;
  int bni = ii & 7;
  int bmi = xcd + 8*(ii >> 3);
  if (bmi >= Mtiles) return;
  __shared__ __align__(16) unsigned short lds[2][16384];   // 64 KB total
  int t = threadIdx.x, w = t >> 6, lane = t & 63;
  int q = lane >> 4, l16 = lane & 15;
  int bm = bmi * 128, bn = bni * 64;

  int lr = lane >> 3, lc = lane & 7;
  int kg = ((lc ^ lr) & 7) * 8;
  int ro = w*8 + lr;
  int m0 = bm + ro, m1 = bm + 32 + ro, m2 = bm + 64 + ro, m3 = bm + 96 + ro;
  if (m0 >= M) m0 = M-1;  if (m1 >= M) m1 = M-1;
  if (m2 >= M) m2 = M-1;  if (m3 >= M) m3 = M-1;
  int n0 = bn + ro, n1 = bn + 32 + ro;
  const bf16* ptr[8];
  ptr[0] = Ah + (size_t)m0*K + kg;
  ptr[1] = Ah + (size_t)m1*K + kg;
  ptr[2] = Ah + (size_t)m2*K + kg;
  ptr[3] = Ah + (size_t)m3*K + kg;
  ptr[4] = Bh + (size_t)n0*K + kg;
  ptr[5] = Bh + (size_t)n1*K + kg;
  ptr[6] = Bl + (size_t)n0*K + kg;
  ptr[7] = Bl + (size_t)n1*K + kg;
  const int dof[8] = {0, 2048, 4096, 6144, 8192, 10240, 12288, 14336};

  int wm = (w >> 1) * 64, wn = (w & 1) * 32;
  f32x4 acc[4][2];
  #pragma unroll
  for (int i = 0; i < 4; i++)
    #pragma unroll
    for (int j = 0; j < 2; j++)
      acc[i][j] = (f32x4){0.f, 0.f, 0.f, 0.f};

  #pragma unroll
  for (int u = 0; u < 8; u++){
    gld16(ptr[u], &lds[0][dof[u] + w*512]);
    ptr[u] += 64;
  }

  int nit = K >> 6;
  for (int it = 0; it < nit; it++){
    __syncthreads();
    int cur = it & 1;
    if (it + 1 < nit){
      int nxt = cur ^ 1;
      #pragma unroll
      for (int u = 0; u < 8; u++){
        gld16(ptr[u], &lds[nxt][dof[u] + w*512]);
        ptr[u] += 64;
      }
    }
    const unsigned short* L = lds[cur];
    #pragma unroll
    for (int ks = 0; ks < 2; ks++){
      short8 ah[4], bh2[2], bl2[2];
      int gc = ks*4 + q;
      #pragma unroll
      for (int i = 0; i < 4; i++){
        int r = wm + i*16 + l16;
        ah[i] = *(const short8*)(L + r*64 + ((gc ^ (r & 7)) << 3));
      }
      #pragma unroll
      for (int j = 0; j < 2; j++){
        int r = wn + j*16 + l16;
        int so = ((gc ^ (r & 7)) << 3);
        bh2[j] = *(const short8*)(L + 8192  + r*64 + so);
        bl2[j] = *(const short8*)(L + 12288 + r*64 + so);
      }
      #pragma unroll
      for (int i = 0; i < 4; i++)
        #pragma unroll
        for (int j = 0; j < 2; j++){
          acc[i][j] = __builtin_amdgcn_mfma_f32_16x16x32_bf16(ah[i], bh2[j], acc[i][j], 0, 0, 0);
          acc[i][j] = __builtin_amdgcn_mfma_f32_16x16x32_bf16(ah[i], bl2[j], acc[i][j], 0, 0, 0);
        }
    }
  }

  __syncthreads();
  float* cs = (float*)&lds[0][0];
  float* cq = cs + 128;
  int slot = w >> 1;
  #pragma unroll
  for (int j = 0; j < 2; j++){
    int c_local = wn + j*16 + l16;
    int c = bn + c_local;
    float bv = 0.f;
    if (bias){
      #pragma unroll
      for (int kc = 0; kc < 8; kc++) bv += bias[kc*512 + c];
    }
    float ls = 0.f, lq = 0.f;
    #pragma unroll
    for (int i = 0; i < 4; i++){
      int rb = bm + wm + i*16 + q*4;
      #pragma unroll
      for (int e = 0; e < 4; e++){
        int r = rb + e;
        if (r < M){
          float v = fmaxf(acc[i][j][e] + bv, 0.f);
          C[(size_t)r*N + c] = __float2bfloat16(v);
          ls += v; lq += v*v;
        }
      }
    }
    ls += __shfl_xor(ls, 16); ls += __shfl_xor(ls, 32);
    lq += __shfl_xor(lq, 16); lq += __shfl_xor(lq, 32);
    if (q == 0){ cs[slot*64 + c_local] = ls; cq[slot*64 + c_local] = lq; }
  }
  __syncthreads();
  if (t < 64){
    atomicAdd(&bnacc[bn + t],        cs[t] + cs[64 + t]);
    atomicAdd(&bnacc[512 + bn + t],  cq[t] + cq[64 + t]);
  }
}

// ======================= head, re-parallelized =======================
// head1p: grid (8 j-tiles x 8 k-chunks) = 64 blocks, 256 thr.
// Each block: Wl1 slice [128k x 64j] in LDS (read ONCE chip-wide) applied to
// all 16 graphs' xg k-slices -> plain-store partials t1p[kc][g][j].
__global__ __launch_bounds__(256) void k_head1p(const float* __restrict__ c1,
    const float* __restrict__ c2, const float* __restrict__ Wl1,
    float* __restrict__ t1p){
  __shared__ float wl[128][64];
  __shared__ float xgs[16][128];
  int b = blockIdx.x, t = threadIdx.x;
  int jt = b >> 3, kc = b & 7;
  int j0 = jt*64, k0 = kc*128;
  for (int i = t; i < 8192; i += 256){
    int k = i >> 6, j = i & 63;
    wl[k][j] = Wl1[(size_t)(k0 + k)*512 + j0 + j];
  }
  for (int i = t; i < 2048; i += 256){
    int g = i >> 7, k = i & 127;
    int idx = g*1024 + k0 + k;
    xgs[g][k] = c1[idx] + c2[idx];
  }
  __syncthreads();
  #pragma unroll
  for (int u = 0; u < 4; u++){
    int p = t + u*256;
    int g = p >> 6, j = p & 63;
    float acc = 0.f;
    #pragma unroll 8
    for (int k = 0; k < 128; k++)
      acc += xgs[g][k] * wl[k][j];
    t1p[(size_t)(kc*16 + g)*512 + j0 + j] = acc;
  }
}
// head2p: one block per graph (16 x 512 thr): reduce 8 partials + bias + relu
// into LDS, then 512x256 GEMM vs Wl2 (L2-resident).
__global__ __launch_bounds__(512) void k_head2p(const float* __restrict__ t1p,
    const float* __restrict__ bl1, const float* __restrict__ Wl2,
    const float* __restrict__ bl2, float* __restrict__ out){
  __shared__ float t1s[512];
  __shared__ float part[2][256];
  int g = blockIdx.x, t = threadIdx.x;
  float acc = bl1[t];
  #pragma unroll
  for (int kc = 0; kc < 8; kc++)
    acc += t1p[(size_t)(kc*16 + g)*512 + t];
  t1s[t] = fmaxf(acc, 0.f);
  __syncthreads();
  int c = t & 255, half = t >> 8;
  float a = 0.f;
  #pragma unroll 8
  for (int k = half*256; k < half*256 + 256; k++)
    a += t1s[k] * Wl2[(size_t)k*256 + c];
  part[half][c] = a;
  __syncthreads();
  if (half == 0)
    out[g*256 + c] = part[0][c] + part[1][c] + bl2[c];
}

extern "C" void kernel_launch(void* const* d_in, const int* in_sizes, int n_in,
                              void* d_out, int out_size, void* d_ws, size_t ws_size,
                              hipStream_t stream){
  const float* x   = (const float*)d_in[0];
  const int*   ei  = (const int*)d_in[1];
  const float* W1  = (const float*)d_in[2];
  const float* as1 = (const float*)d_in[3];
  const float* ad1 = (const float*)d_in[4];
  const float* bc1 = (const float*)d_in[5];
  const float* Wh1 = (const float*)d_in[6];
  const float* bh1 = (const float*)d_in[7];
  const float* g1  = (const float*)d_in[8];
  const float* be1 = (const float*)d_in[9];
  const float* p1  = (const float*)d_in[10];
  const float* W2  = (const float*)d_in[11];
  const float* as2 = (const float*)d_in[12];
  const float* ad2 = (const float*)d_in[13];
  const float* bc2 = (const float*)d_in[14];
  const float* Wh2 = (const float*)d_in[15];
  const float* bh2 = (const float*)d_in[16];
  const float* g2  = (const float*)d_in[17];
  const float* be2 = (const float*)d_in[18];
  const float* p2  = (const float*)d_in[19];
  const float* Wl1 = (const float*)d_in[20];
  const float* bl1 = (const float*)d_in[21];
  const float* Wl2 = (const float*)d_in[22];
  const float* bl2 = (const float*)d_in[23];
  float* out = (float*)d_out;

  const int* src0 = ei;
  const int* tgt0 = ei + E_EDGES;

  // ---- workspace layout ----
  bf16* Cc      = (bf16*)d_ws;                       // NN1*EMB
  bf16* xn1     = Cc + (size_t)NN1*EMB;              // NN2*EMB
  bf16* aggx2h  = xn1 + (size_t)NN2*EMB;             // NN2*F1
  bf16* M2Th    = aggx2h + (size_t)NN2*F1;           // EMB*F1
  bf16* M2Tl    = M2Th + (size_t)EMB*F1;             // EMB*F1
  float* holeA  = (float*)(M2Tl + (size_t)EMB*F1);   // hole (122880 floats)
  float* t1p    = holeA;                             // 8*16*512 = 65536 floats
  float* bnacc1 = holeA + 122880;                    // 1024
  float* bnacc  = bnacc1 + 1024;                     // 1024
  float* M1p    = bnacc + 1024;                      // 4*4608
  float* cvp    = M1p + 4*4608;                      // 16*512 (cvp2 = cvp + 8*512)
  float* was2   = cvp + 16*512;                      // 3*512
  float* wad2   = was2 + 3*512;                      // 3*512
  float* was1   = wad2 + 3*512;                      // 16
  float* wad1   = was1 + 16;                         // 16
  float* aso2   = wad1 + 16;                         // NN2*3
  float* ado2   = aso2 + (size_t)NN2*3;              // NN2*3
  float* tops   = ado2 + (size_t)NN2*3;              // NG*KP1
  float* cat1   = tops + NG*KP1;                     // 16*1024
  float* cat2   = cat1 + NG*1024;                    // 16*1024
  int* topi     = (int*)(cat2 + NG*1024);            // NG*KP1
  int* map      = topi + NG*KP1;                     // NN1
  int* cnt2     = map + NN1;                         // NN2
  int* off2     = cnt2 + NN2;                        // NN2+8
  int* cur2     = off2 + NN2 + 8;                    // NN2
  int* esrc2    = cur2 + NN2;                        // E+NN2 (+pad 137700)
  float* nump   = (float*)(esrc2 + 137700);          // 256*4608 (chunk partials)
  float* denp   = nump + (size_t)256*4608;           // 256*1536
  float* cvp2   = cvp + 8*512;

  // 1. mega precompute: init + watt + M1p/cvp + gemm_s
  k_pre<<<428,256,0,stream>>>(W1,as1,ad1,Wh1,bc1,bh1, W2,as2,ad2,Wh2,bc2,bh2,
                              was1,wad1,M1p,cvp,was2,wad2,
                              bnacc1,cnt2,map,M2Th,M2Tl);
  // 2. layer-1 segment softmax: 16 chunks/graph, LDS-private, no global atomics
  k_edge<<<256,256,0,stream>>>(src0,tgt0,x,was1,wad1,denp,nump);
  // 3. h1 + chunk reduction + BN partials
  k_h1<<<NN1/32,256,0,stream>>>(nump,denp,M1p,cvp,Cc,bnacc1);
  // 4. fused score+sort (layer 1)
  k_scoresort<<<NG,512,0,stream>>>(Cc,bnacc1,NN1,g1,be1,p1,NP1,KP1,map,topi,tops);
  // 5. gather + attention dots + count2
  k_gather_c2<<<NG*KP1+512,256,0,stream>>>(Cc,bnacc1,NN1,g1,be1,topi,tops,xn1,NP1,KP1,
      was2,wad2,aso2,ado2, src0,tgt0,map,cnt2,NG*KP1);
  // 6. poolA + scan2
  k_poolA_scan<<<65,1024,0,stream>>>(xn1,cat1,KP1, cnt2,off2,cur2);
  // 7. fill2
  k_fill2<<<(E_EDGES+NN2+255)/256,256,0,stream>>>(src0,tgt0,map,cur2,esrc2,E_EDGES,NN2);
  // 8. agg2
  k_agg2<<<NN2,256,0,stream>>>(xn1,aso2,ado2,off2,esrc2,aggx2h);
  // 9. big GEMM (XCD-swizzled, grid 56*8 with guard)
  k_gemm_mfma<<<448,256,0,stream>>>(aggx2h,M2Th,M2Tl,cvp2,Cc,bnacc,NN2,EMB,F1,52);
  // 10. fused score+sort (layer 2)
  k_scoresort<<<NG,512,0,stream>>>(Cc,bnacc,NN2,g2,be2,p2,KP1,KP2,(int*)nullptr,topi,tops);
  // 11. poolB
  k_poolB<<<64,1024,0,stream>>>(Cc,bnacc,NN2,g2,be2,topi,tops,cat2,KP1,KP2);
  // 12-13. head (re-parallelized, weight reads amortized over graphs)
  k_head1p<<<64,256,0,stream>>>(cat1,cat2,Wl1,t1p);
  k_head2p<<<NG,512,0,stream>>>(t1p,bl1,Wl2,bl2,out);
}

// Round 9
// 310.043 us; speedup vs baseline: 1.4638x; 1.0134x over previous
//
#include <hip/hip_runtime.h>
#include <hip/hip_bf16.h>
#include <math.h>

#define E_EDGES 131072
#define NN1 8192
#define NN2 6560          // 16*410
#define NG 16
#define NP1 512
#define KP1 410
#define KP2 205
#define F1 1536
#define EMB 512
#define MAXDEG 256

typedef __hip_bfloat16 bf16;
typedef __attribute__((ext_vector_type(8))) short short8;
typedef __attribute__((ext_vector_type(4))) float f32x4;
typedef __attribute__((ext_vector_type(4))) unsigned short us4;

__device__ inline float wred64(float v){
  #pragma unroll
  for (int o = 32; o; o >>= 1) v += __shfl_down(v, o);
  return v;
}
__device__ inline float b2f_raw(unsigned short u){
  return __uint_as_float((unsigned)u << 16);
}
union BFU { bf16 b; unsigned short u; };
__device__ inline unsigned short f2u(float v){ BFU x; x.b = __float2bfloat16(v); return x.u; }

__device__ __forceinline__ void gld16(const void* g, void* l){
  __builtin_amdgcn_global_load_lds(
      (const __attribute__((address_space(1))) void*)g,
      (__attribute__((address_space(3))) void*)l, 16, 0, 0);
}

__device__ inline void split_store(float v, bf16* __restrict__ ph, bf16* __restrict__ pl){
  bf16 hi = __float2bfloat16(v);
  *ph = hi;
  *pl = __float2bfloat16(v - __bfloat162float(hi));
}

// inline BN stats from raw sums
__device__ inline void bn_from_acc(const float* __restrict__ bnacc, int c, float fM,
                                   float& mean, float& inv){
  mean = bnacc[c] / fM;
  float var = fmaxf(bnacc[512+c]/fM - mean*mean, 0.f);
  inv = 1.f / sqrtf(var + 1e-5f);
}

// ======================= mega precompute (+ fused layer-1 segment softmax) =======================
// [0,24): M1 partials   [24,56): cvec partials   [56,152): watt2
// [152,218): init (bnacc zero / cnt2=1 / map=-1)
// [218,474): layer-1 edge chunks (16 graphs x 16 chunks, LDS-private, local watt1)
// [474,666): gemm_s 64x64 split-bf16 MFMA tiles (W2@Wh2 -> M2T split)
__global__ __launch_bounds__(256) void k_pre(
    const float* __restrict__ W1, const float* __restrict__ as1, const float* __restrict__ ad1,
    const float* __restrict__ Wh1, const float* __restrict__ bc1, const float* __restrict__ bh1,
    const float* __restrict__ W2, const float* __restrict__ as2, const float* __restrict__ ad2,
    const float* __restrict__ Wh2, const float* __restrict__ bc2, const float* __restrict__ bh2,
    const int* __restrict__ src0, const int* __restrict__ tgt0, const float* __restrict__ x,
    float* __restrict__ M1p, float* __restrict__ cvp,
    float* __restrict__ was2, float* __restrict__ wad2,
    float* __restrict__ Zb, int* __restrict__ cnt2, int* __restrict__ map,
    bf16* __restrict__ Th, bf16* __restrict__ Tl,
    float* __restrict__ denp, float* __restrict__ nump){
  int b = blockIdx.x, t = threadIdx.x;
  if (b < 24){                               // M1 partials
    int h = b / 8, rem = b % 8, jh = rem >> 2, kc = rem & 3;
    int j = jh*256 + t, c0 = kc*128;
    __shared__ float w1s[3][128];
    for (int i = t; i < 384; i += 256)
      w1s[i>>7][i&127] = W1[(i>>7)*1536 + h*512 + c0 + (i&127)];
    __syncthreads();
    const float* whc = Wh1 + (size_t)(h*512 + c0)*512 + j;
    float a0=0.f, a1=0.f, a2=0.f;
    #pragma unroll 8
    for (int c = 0; c < 128; c++){
      float v = whc[(size_t)c*512];
      a0 += w1s[0][c]*v; a1 += w1s[1][c]*v; a2 += w1s[2][c]*v;
    }
    float* dst = M1p + (size_t)kc*4608;
    dst[(h*3+0)*512 + j] = a0;
    dst[(h*3+1)*512 + j] = a1;
    dst[(h*3+2)*512 + j] = a2;
  } else if (b < 56){                        // cvec partials
    int b2 = b - 24;
    int which = b2 >> 4, rem = b2 & 15, jh = rem >> 3, kc = rem & 7;
    const float* bc = which ? bc2 : bc1;
    const float* Wh = which ? Wh2 : Wh1;
    const float* bh = which ? bh2 : bh1;
    int j = jh*256 + t, i0 = kc*192;
    float acc = (kc == 0) ? bh[j] : 0.f;
    #pragma unroll 8
    for (int i = 0; i < 192; i++)
      acc += bc[i0+i] * Wh[(size_t)(i0+i)*512 + j];
    cvp[(size_t)(which*8 + kc)*512 + j] = acc;
  } else if (b < 152){                       // watt2
    int b3 = b - 56;
    int y = b3 >> 4, et = b3 & 15;
    int kind = y / 3, h = y % 3;
    int w = t >> 6, lane = t & 63;
    const float* att = kind ? ad2 : as2;
    float a[8];
    #pragma unroll
    for (int u = 0; u < 8; u++) a[u] = att[h*512 + lane*8 + u];
    for (int r = w; r < 32; r += 4){
      int e = et*32 + r;
      const float4* row = (const float4*)(W2 + (size_t)e*1536 + h*512) + lane*2;
      float4 v0 = row[0], v1 = row[1];
      float d = v0.x*a[0]+v0.y*a[1]+v0.z*a[2]+v0.w*a[3]
              + v1.x*a[4]+v1.y*a[5]+v1.z*a[6]+v1.w*a[7];
      d = wred64(d);
      if (lane == 0) (kind ? wad2 : was2)[h*512 + e] = d;
    }
  } else if (b < 218){                       // init
    int i = (b - 152)*256 + t;
    if (i < 2048){ Zb[i] = 0.f; }                         // bnacc1|bnacc
    else if (i < 2048 + NN2){ cnt2[i - 2048] = 1; }
    else if (i < 2048 + NN2 + NN1){ map[i - 2048 - NN2] = -1; }
  } else if (b < 474){                       // layer-1 edge chunk (LDS-private)
    __shared__ float sww[18];                // [kind*9 + h*3 + f]
    __shared__ float lden[1536];
    __shared__ float lnum[4608];
    int wv_ = t >> 6, lane = t & 63;
    for (int combo = wv_*5; combo < wv_*5+5 && combo < 18; combo++){
      int kind = combo/9, rr = combo%9, h = rr/3, f = rr%3;
      const float* att = kind ? ad1 : as1;
      float s = 0.f;
      #pragma unroll
      for (int c = lane; c < 512; c += 64) s += W1[f*1536 + h*512 + c] * att[h*512 + c];
      s = wred64(s);
      if (lane == 0) sww[combo] = s;
    }
    for (int i = t; i < 1536; i += 256) lden[i] = 0.f;
    for (int i = t; i < 4608; i += 256) lnum[i] = 0.f;
    __syncthreads();
    int eb = b - 218;
    int g = eb >> 4, ch = eb & 15;
    int base = g*8192;
    int it0 = ch*544;                        // 16*544 = 8704 items (8192 edges + 512 self-loops)
    for (int k = t; k < 544; k += 256){
      int it = it0 + k;
      int s, tl;
      if (it < 8192){ s = src0[base+it]; tl = tgt0[base+it] & 511; }
      else { tl = it - 8192; s = g*512 + tl; }
      float xs0 = x[s*3], xs1 = x[s*3+1], xs2 = x[s*3+2];
      int tg = g*512 + tl;
      float xt0 = x[tg*3], xt1 = x[tg*3+1], xt2 = x[tg*3+2];
      #pragma unroll
      for (int h = 0; h < 3; h++){
        float v = xs0*sww[h*3]+xs1*sww[h*3+1]+xs2*sww[h*3+2]
                + xt0*sww[9+h*3]+xt1*sww[9+h*3+1]+xt2*sww[9+h*3+2];
        v = v > 0.f ? v : 0.2f*v;
        float pe = expf(v);                  // |v|<~1: max-subtraction cancels in ratio
        atomicAdd(&lden[tl*3 + h], pe);
        atomicAdd(&lnum[tl*9 + h*3 + 0], pe * xs0);
        atomicAdd(&lnum[tl*9 + h*3 + 1], pe * xs1);
        atomicAdd(&lnum[tl*9 + h*3 + 2], pe * xs2);
      }
    }
    __syncthreads();
    for (int i = t; i < 4608; i += 256) nump[(size_t)eb*4608 + i] = lnum[i];
    for (int i = t; i < 1536; i += 256) denp[(size_t)eb*1536 + i] = lden[i];
  } else {                                   // gemm_s tiles
    int bb = b - 474;
    int z = bb % 3; int rr = bb / 3; int by = rr >> 3, bx = rr & 7;
    const float* A = W2 + (size_t)z*512;            // row stride 1536
    const float* B = Wh2 + (size_t)z*512*512;       // row stride 512
    __shared__ __align__(16) short sAh[4096], sAl[4096], sBh[4096], sBl[4096];
    int w = t >> 6, lane = t & 63;
    int l16 = lane & 15, q = lane >> 4;
    int bm = by*64, bn = bx*64;
    int am  = t >> 2, akw = (t & 3)*16;
    int bnl = t & 63, bkq = (t >> 6)*16;
    f32x4 acc[4];
    #pragma unroll
    for (int nf = 0; nf < 4; nf++) acc[nf] = (f32x4){0.f,0.f,0.f,0.f};
    float va[16], vb[16];
    #define GS_LOAD(K0) do { \
      _Pragma("unroll") for (int u = 0; u < 4; u++){ \
        float4 v4 = *(const float4*)(A + (size_t)(bm+am)*1536 + (K0) + akw + u*4); \
        va[u*4]=v4.x; va[u*4+1]=v4.y; va[u*4+2]=v4.z; va[u*4+3]=v4.w; } \
      _Pragma("unroll") for (int u = 0; u < 16; u++) \
        vb[u] = B[(size_t)((K0) + bkq + u)*512 + bn + bnl]; \
    } while(0)
    GS_LOAD(0);
    for (int it = 0; it < 8; it++){
      #pragma unroll
      for (int hh = 0; hh < 2; hh++){
        short8 ah_, al_, bh_, bl_;
        #pragma unroll
        for (int jj = 0; jj < 8; jj++){
          float v = va[hh*8+jj];
          unsigned short hu = f2u(v);
          ah_[jj] = (short)hu; al_[jj] = (short)f2u(v - b2f_raw(hu));
          v = vb[hh*8+jj];
          hu = f2u(v);
          bh_[jj] = (short)hu; bl_[jj] = (short)f2u(v - b2f_raw(hu));
        }
        int aoff = am*64  + ((((akw>>3) + hh) ^ (am  & 7)) << 3);
        *(short8*)(sAh + aoff) = ah_;
        *(short8*)(sAl + aoff) = al_;
        int boff = bnl*64 + ((((bkq>>3) + hh) ^ (bnl & 7)) << 3);
        *(short8*)(sBh + boff) = bh_;
        *(short8*)(sBl + boff) = bl_;
      }
      __syncthreads();
      if (it < 7) GS_LOAD((it+1)*64);
      #pragma unroll
      for (int ks = 0; ks < 2; ks++){
        int gc = ks*4 + q;
        int ar = w*16 + l16;
        int ao = ar*64 + ((gc ^ (ar & 7)) << 3);
        short8 afh = *(const short8*)(sAh + ao);
        short8 afl = *(const short8*)(sAl + ao);
        #pragma unroll
        for (int nf = 0; nf < 4; nf++){
          int br = nf*16 + l16;
          int bo = br*64 + ((gc ^ (br & 7)) << 3);
          short8 bfh = *(const short8*)(sBh + bo);
          short8 bfl = *(const short8*)(sBl + bo);
          acc[nf] = __builtin_amdgcn_mfma_f32_16x16x32_bf16(afh, bfh, acc[nf], 0, 0, 0);
          acc[nf] = __builtin_amdgcn_mfma_f32_16x16x32_bf16(afh, bfl, acc[nf], 0, 0, 0);
          acc[nf] = __builtin_amdgcn_mfma_f32_16x16x32_bf16(afl, bfh, acc[nf], 0, 0, 0);
        }
      }
      __syncthreads();
    }
    #undef GS_LOAD
    int m0 = bm + w*16 + q*4;
    #pragma unroll
    for (int nf = 0; nf < 4; nf++){
      int n = bn + nf*16 + l16;
      size_t base = (size_t)n*1536 + (size_t)z*512 + m0;
      #pragma unroll
      for (int e = 0; e < 4; e++)
        split_store(acc[nf][e], &Th[base+e], &Tl[base+e]);
    }
  }
}

// h1[n,j] = relu(cvec[j] + sum_q (num/den)[n,q]*M1[q,j]) -> bf16 ; fused BN partials.
__global__ __launch_bounds__(256) void k_h1(
    const float* __restrict__ nump, const float* __restrict__ denp,
    const float* __restrict__ M1p, const float* __restrict__ cvp1, bf16* __restrict__ hout,
    float* __restrict__ bnacc1){
  __shared__ float sM[9*512];
  __shared__ float sC[512];
  __shared__ float sA[32*9];
  int t = threadIdx.x; int n0 = blockIdx.x*32;
  for (int i = t; i < 9*512; i += 256)
    sM[i] = M1p[i] + M1p[4608 + i] + M1p[2*4608 + i] + M1p[3*4608 + i];
  for (int i = t; i < 512; i += 256){
    float s = 0.f;
    #pragma unroll
    for (int kc = 0; kc < 8; kc++) s += cvp1[kc*512 + i];
    sC[i] = s;
  }
  for (int i = t; i < 288; i += 256){
    int node = i / 9, q = i % 9, hh = q / 3;
    int gn = n0 + node;
    int g = gn >> 9, nl = gn & 511;
    float ns = 0.f, ds = 0.f;
    #pragma unroll 4
    for (int ch = 0; ch < 16; ch++){
      ns += nump[(size_t)(g*16 + ch)*4608 + nl*9 + q];
      ds += denp[(size_t)(g*16 + ch)*1536 + nl*3 + hh];
    }
    sA[i] = ns / fmaxf(ds, 1e-16f);
  }
  __syncthreads();
  float c0v = sC[t], c1v = sC[t+256];
  float ls0=0.f, lq0=0.f, ls1=0.f, lq1=0.f;
  #pragma unroll 4
  for (int i = 0; i < 32; i++){
    float a0 = c0v, a1 = c1v;
    #pragma unroll
    for (int q = 0; q < 9; q++){
      float av = sA[i*9+q];
      a0 += av * sM[q*512 + t];
      a1 += av * sM[q*512 + t + 256];
    }
    a0 = fmaxf(a0, 0.f); a1 = fmaxf(a1, 0.f);
    hout[(size_t)(n0+i)*512 + t]       = __float2bfloat16(a0);
    hout[(size_t)(n0+i)*512 + t + 256] = __float2bfloat16(a1);
    ls0 += a0; lq0 += a0*a0; ls1 += a1; lq1 += a1*a1;
  }
  atomicAdd(&bnacc1[t],           ls0);
  atomicAdd(&bnacc1[t+256],       ls1);
  atomicAdd(&bnacc1[512 + t],     lq0);
  atomicAdd(&bnacc1[512 + t+256], lq1);
}

// ======================= fused score + top-k sort (+ optional fused pool) ==================
// cat==nullptr: write map/topi/tops (layer 1).  cat!=nullptr: skip global top-k,
// directly gather+BN+scale+max/mean-pool the top-K rows into cat (layer 2).
__global__ __launch_bounds__(512) void k_scoresort(
    const bf16* __restrict__ h, const float* __restrict__ bnacc, int M,
    const float* __restrict__ g_, const float* __restrict__ be, const float* __restrict__ p,
    int n_per, int K, int* __restrict__ map,
    int* __restrict__ topi, float* __restrict__ tops, float* __restrict__ cat){
  int g = blockIdx.x, t = threadIdx.x;
  __shared__ float w[512];
  __shared__ float redb[8], redp[8];
  __shared__ float sk[512];
  __shared__ int si[512];
  float fM = (float)M;
  float mean, inv; bn_from_acc(bnacc, t, fM, mean, inv);
  float gc = g_[t], pc = p[t], bec = be[t];
  float ig = inv * gc;
  w[t] = ig * pc;
  float bt = (bec - mean * ig) * pc;
  float b_ = wred64(bt);
  float pp = wred64(pc * pc);
  int lane = t & 63, wv = t >> 6;
  if (lane == 0){ redb[wv] = b_; redp[wv] = pp; }
  __syncthreads();
  float B0 = 0.f, pn2 = 0.f;
  #pragma unroll
  for (int u = 0; u < 8; u++){ B0 += redb[u]; pn2 += redp[u]; }
  float pn = sqrtf(pn2);
  float score = -INFINITY; int idx = 0x7fffffff;
  if (t < n_per){
    const unsigned short* hr = (const unsigned short*)h + (size_t)(g*n_per + t)*EMB;
    float dot = 0.f;
    #pragma unroll 4
    for (int c = 0; c < 512; c += 8){
      us4 v0 = *(const us4*)(hr + c);
      us4 v1 = *(const us4*)(hr + c + 4);
      dot += b2f_raw(v0.x)*w[c]   + b2f_raw(v0.y)*w[c+1]
           + b2f_raw(v0.z)*w[c+2] + b2f_raw(v0.w)*w[c+3]
           + b2f_raw(v1.x)*w[c+4] + b2f_raw(v1.y)*w[c+5]
           + b2f_raw(v1.z)*w[c+6] + b2f_raw(v1.w)*w[c+7];
    }
    score = tanhf((dot + B0) / pn);
    idx = t;
  }
  sk[t] = score; si[t] = idx;
  __syncthreads();
  for (int k = 2; k <= 512; k <<= 1){
    for (int j = k >> 1; j > 0; j >>= 1){
      int l = t ^ j;
      if (l > t){
        float ki = sk[t], kl = sk[l]; int ii = si[t], il = si[l];
        bool before_l = (kl > ki) || (kl == ki && il < ii);
        bool up = ((t & k) == 0);
        if (up == before_l){ sk[t]=kl; sk[l]=ki; si[t]=il; si[l]=ii; }
      }
      __syncthreads();
    }
  }
  if (cat == nullptr){
    if (t < K){
      if (map) map[g*n_per + si[t]] = g*K + t;
      topi[g*K + t] = si[t];
      tops[g*K + t] = sk[t];
    }
  } else {
    // fused gather + BN + scale + max/mean pool (each thread owns column t)
    const unsigned short* hp = (const unsigned short*)h;
    float mx = -INFINITY, sm = 0.f;
    for (int r = 0; r < K; r++){
      float v = (b2f_raw(hp[(size_t)(g*n_per + si[r])*EMB + t]) - mean) * ig + bec;
      v *= sk[r];
      mx = fmaxf(mx, v); sm += v;
    }
    cat[g*1024 + t] = mx;
    cat[g*1024 + 512 + t] = sm / (float)K;
  }
}

// gather + inline BN + scale -> bf16; fused layer-2 attention dots; fused count2 tail
__global__ __launch_bounds__(256) void k_gather_c2(
    const bf16* __restrict__ h, const float* __restrict__ bnacc, int M,
    const float* __restrict__ gm, const float* __restrict__ be,
    const int* __restrict__ topi, const float* __restrict__ tops,
    bf16* __restrict__ xn, int n_per, int K,
    const float* __restrict__ was2, const float* __restrict__ wad2,
    float* __restrict__ aso, float* __restrict__ ado,
    const int* __restrict__ src0, const int* __restrict__ tgt0,
    const int* __restrict__ map, int* __restrict__ cnt2, int nblk_g){
  int row = blockIdx.x, t = threadIdx.x;
  if (row >= nblk_g){                      // count2 tail
    int i = (row - nblk_g)*256 + t;
    if (i < E_EDGES){
      int s = map[src0[i]], tg = map[tgt0[i]];
      if (s >= 0 && tg >= 0) atomicAdd(&cnt2[tg], 1);
    }
    return;
  }
  int gr = row / K, i = row - gr*K;
  int sidx = topi[gr*K + i];
  float s = tops[gr*K + i];
  const bf16* src = h + ((size_t)(gr*n_per + sidx))*EMB;
  bf16* dst = xn + (size_t)row*EMB;
  int c0 = t, c1 = t + 256;
  float fM = (float)M;
  float mean0, inv0, mean1, inv1;
  bn_from_acc(bnacc, c0, fM, mean0, inv0);
  bn_from_acc(bnacc, c1, fM, mean1, inv1);
  float v0 = ((__bfloat162float(src[c0]) - mean0) * inv0 * gm[c0] + be[c0]) * s;
  float v1 = ((__bfloat162float(src[c1]) - mean1) * inv1 * gm[c1] + be[c1]) * s;
  dst[c0] = __float2bfloat16(v0);
  dst[c1] = __float2bfloat16(v1);
  {
    float a[6];
    #pragma unroll
    for (int hh = 0; hh < 3; hh++){
      a[hh]   = v0*was2[hh*512 + c0] + v1*was2[hh*512 + c1];
      a[3+hh] = v0*wad2[hh*512 + c0] + v1*wad2[hh*512 + c1];
    }
    __shared__ float red[6][4];
    int lane = t & 63, wv = t >> 6;
    #pragma unroll
    for (int q = 0; q < 6; q++){ float v = wred64(a[q]); if (lane==0) red[q][wv]=v; }
    __syncthreads();
    if (t < 6){
      float sm = red[t][0]+red[t][1]+red[t][2]+red[t][3];
      if (t < 3) aso[row*3+t] = sm; else ado[row*3+(t-3)] = sm;
    }
  }
}

// ======================= CSR (layer 2) =======================
__device__ inline void scan_body(const int* __restrict__ counts, int* __restrict__ off,
                                 int* __restrict__ cur, int n, int* __restrict__ sh){
  int t = threadIdx.x;
  int chunk = (n + 1023) >> 10;
  int b = t * chunk; int e = b + chunk; if (e > n) e = n;
  int s = 0;
  for (int i = b; i < e; i++) s += counts[i];
  sh[t] = s; __syncthreads();
  for (int o = 1; o < 1024; o <<= 1){
    int v = (t >= o) ? sh[t-o] : 0;
    __syncthreads();
    sh[t] += v;
    __syncthreads();
  }
  int run = (t > 0) ? sh[t-1] : 0;
  for (int i = b; i < e; i++){ int c = counts[i]; off[i] = run; cur[i] = run; run += c; }
  if (t == 1023) off[n] = sh[1023];
}
__global__ void k_fill2(const int* __restrict__ src0, const int* __restrict__ tgt0,
                        const int* __restrict__ map, int* __restrict__ cur,
                        int* __restrict__ esrc, int E, int nn){
  int i = blockIdx.x*blockDim.x + threadIdx.x;
  if (i >= E + nn) return;
  int s, tg;
  if (i < E){
    s = map[src0[i]]; tg = map[tgt0[i]];
    if (s < 0 || tg < 0) return;
  } else { s = i - E; tg = s; }
  int pos = atomicAdd(&cur[tg], 1);
  esrc[pos] = s;
}

// ======================= pooling (layer 1) =======================
// blocks [0,64): poolA over xn1; block 64: scan(cnt2)
__global__ __launch_bounds__(1024) void k_poolA_scan(const bf16* __restrict__ xn,
    float* __restrict__ cat, int K,
    const int* __restrict__ cnt2, int* __restrict__ off2, int* __restrict__ cur2){
  __shared__ int shi[1024];
  __shared__ float smax[8][128];
  __shared__ float ssum[8][128];
  int b = blockIdx.x, t = threadIdx.x;
  if (b == 64){ scan_body(cnt2, off2, cur2, NN2, shi); return; }
  int g = b >> 2, cb = b & 3;
  int c = t & 127, rg = t >> 7;
  int col = cb*128 + c;
  const unsigned short* p = (const unsigned short*)xn + (size_t)g*K*EMB + col;
  float mx = -INFINITY, sm = 0.f;
  for (int r = rg; r < K; r += 8){
    float v = b2f_raw(p[(size_t)r*EMB]);
    mx = fmaxf(mx, v); sm += v;
  }
  smax[rg][c] = mx; ssum[rg][c] = sm;
  __syncthreads();
  if (rg == 0){
    #pragma unroll
    for (int u = 1; u < 8; u++){ mx = fmaxf(mx, smax[u][c]); sm += ssum[u][c]; }
    cat[g*1024 + col] = mx;
    cat[g*1024 + 512 + col] = sm / (float)K;
  }
}

// ======================= layer 2 aggregation =======================
__global__ __launch_bounds__(256) void k_agg2(
    const bf16* __restrict__ xn, const float* __restrict__ aso, const float* __restrict__ ado,
    const int* __restrict__ off, const int* __restrict__ esrc,
    bf16* __restrict__ oh){
  int n = blockIdx.x, t = threadIdx.x;
  __shared__ int srcs[MAXDEG];
  __shared__ float al[MAXDEG*3];
  __shared__ float mh[3], dh[3];
  int s0 = off[n]; int deg = off[n+1] - s0; if (deg > MAXDEG) deg = MAXDEG;
  for (int e = t; e < deg; e += 256) srcs[e] = esrc[s0 + e];
  __syncthreads();
  float ad0 = ado[n*3+0], ad1 = ado[n*3+1], ad2 = ado[n*3+2];
  for (int e = t; e < deg; e += 256){
    int s = srcs[e];
    float v0 = aso[s*3+0] + ad0, v1 = aso[s*3+1] + ad1, v2 = aso[s*3+2] + ad2;
    al[e*3+0] = v0 > 0.f ? v0 : 0.2f*v0;
    al[e*3+1] = v1 > 0.f ? v1 : 0.2f*v1;
    al[e*3+2] = v2 > 0.f ? v2 : 0.2f*v2;
  }
  __syncthreads();
  if (t < 3){
    float m = -INFINITY;
    for (int e = 0; e < deg; e++) m = fmaxf(m, al[e*3+t]);
    float d = 0.f;
    for (int e = 0; e < deg; e++) d += expf(al[e*3+t] - m);
    mh[t] = m; dh[t] = 1.f / fmaxf(d, 1e-16f);
  }
  __syncthreads();
  for (int e = t; e < deg; e += 256){
    al[e*3+0] = expf(al[e*3+0]-mh[0])*dh[0];
    al[e*3+1] = expf(al[e*3+1]-mh[1])*dh[1];
    al[e*3+2] = expf(al[e*3+2]-mh[2])*dh[2];
  }
  __syncthreads();
  float acc[2][3] = {};
  for (int e = 0; e < deg; e++){
    int s = srcs[e];
    float a0 = al[e*3], a1 = al[e*3+1], a2 = al[e*3+2];
    #pragma unroll
    for (int k = 0; k < 2; k++){
      float v = __bfloat162float(xn[(size_t)s*512 + t + k*256]);
      acc[k][0] += a0*v; acc[k][1] += a1*v; acc[k][2] += a2*v;
    }
  }
  #pragma unroll
  for (int k = 0; k < 2; k++){
    int c = t + k*256;
    #pragma unroll
    for (int h = 0; h < 3; h++)
      oh[(size_t)n*1536 + h*512 + c] = __float2bfloat16(acc[k][h]);
  }
}

// ======================= bf16-A x split-bf16-B MFMA GEMM (XCD-swizzled) =======================
__global__ __launch_bounds__(256, 2) void k_gemm_mfma(
    const bf16* __restrict__ Ah,
    const bf16* __restrict__ Bh, const bf16* __restrict__ Bl,   // [N][K] row-major
    const float* __restrict__ bias, bf16* __restrict__ C,
    float* __restrict__ bnacc,
    int M, int N, int K, int Mtiles){
  int xcd = (int)blockIdx.x & 7;
  int ii  = (int)blockIdx.x >> 3;
  int bni = ii & 7;
  int bmi = xcd + 8*(ii >> 3);
  if (bmi >= Mtiles) return;
  __shared__ __align__(16) unsigned short lds[2][16384];   // 64 KB total
  int t = threadIdx.x, w = t >> 6, lane = t & 63;
  int q = lane >> 4, l16 = lane & 15;
  int bm = bmi * 128, bn = bni * 64;

  int lr = lane >> 3, lc = lane & 7;
  int kg = ((lc ^ lr) & 7) * 8;
  int ro = w*8 + lr;
  int m0 = bm + ro, m1 = bm + 32 + ro, m2 = bm + 64 + ro, m3 = bm + 96 + ro;
  if (m0 >= M) m0 = M-1;  if (m1 >= M) m1 = M-1;
  if (m2 >= M) m2 = M-1;  if (m3 >= M) m3 = M-1;
  int n0 = bn + ro, n1 = bn + 32 + ro;
  const bf16* ptr[8];
  ptr[0] = Ah + (size_t)m0*K + kg;
  ptr[1] = Ah + (size_t)m1*K + kg;
  ptr[2] = Ah + (size_t)m2*K + kg;
  ptr[3] = Ah + (size_t)m3*K + kg;
  ptr[4] = Bh + (size_t)n0*K + kg;
  ptr[5] = Bh + (size_t)n1*K + kg;
  ptr[6] = Bl + (size_t)n0*K + kg;
  ptr[7] = Bl + (size_t)n1*K + kg;
  const int dof[8] = {0, 2048, 4096, 6144, 8192, 10240, 12288, 14336};

  int wm = (w >> 1) * 64, wn = (w & 1) * 32;
  f32x4 acc[4][2];
  #pragma unroll
  for (int i = 0; i < 4; i++)
    #pragma unroll
    for (int j = 0; j < 2; j++)
      acc[i][j] = (f32x4){0.f, 0.f, 0.f, 0.f};

  #pragma unroll
  for (int u = 0; u < 8; u++){
    gld16(ptr[u], &lds[0][dof[u] + w*512]);
    ptr[u] += 64;
  }

  int nit = K >> 6;
  for (int it = 0; it < nit; it++){
    __syncthreads();
    int cur = it & 1;
    if (it + 1 < nit){
      int nxt = cur ^ 1;
      #pragma unroll
      for (int u = 0; u < 8; u++){
        gld16(ptr[u], &lds[nxt][dof[u] + w*512]);
        ptr[u] += 64;
      }
    }
    const unsigned short* L = lds[cur];
    #pragma unroll
    for (int ks = 0; ks < 2; ks++){
      short8 ah[4], bh2[2], bl2[2];
      int gc = ks*4 + q;
      #pragma unroll
      for (int i = 0; i < 4; i++){
        int r = wm + i*16 + l16;
        ah[i] = *(const short8*)(L + r*64 + ((gc ^ (r & 7)) << 3));
      }
      #pragma unroll
      for (int j = 0; j < 2; j++){
        int r = wn + j*16 + l16;
        int so = ((gc ^ (r & 7)) << 3);
        bh2[j] = *(const short8*)(L + 8192  + r*64 + so);
        bl2[j] = *(const short8*)(L + 12288 + r*64 + so);
      }
      #pragma unroll
      for (int i = 0; i < 4; i++)
        #pragma unroll
        for (int j = 0; j < 2; j++){
          acc[i][j] = __builtin_amdgcn_mfma_f32_16x16x32_bf16(ah[i], bh2[j], acc[i][j], 0, 0, 0);
          acc[i][j] = __builtin_amdgcn_mfma_f32_16x16x32_bf16(ah[i], bl2[j], acc[i][j], 0, 0, 0);
        }
    }
  }

  __syncthreads();
  float* cs = (float*)&lds[0][0];
  float* cq = cs + 128;
  int slot = w >> 1;
  #pragma unroll
  for (int j = 0; j < 2; j++){
    int c_local = wn + j*16 + l16;
    int c = bn + c_local;
    float bv = 0.f;
    if (bias){
      #pragma unroll
      for (int kc = 0; kc < 8; kc++) bv += bias[kc*512 + c];
    }
    float ls = 0.f, lq = 0.f;
    #pragma unroll
    for (int i = 0; i < 4; i++){
      int rb = bm + wm + i*16 + q*4;
      #pragma unroll
      for (int e = 0; e < 4; e++){
        int r = rb + e;
        if (r < M){
          float v = fmaxf(acc[i][j][e] + bv, 0.f);
          C[(size_t)r*N + c] = __float2bfloat16(v);
          ls += v; lq += v*v;
        }
      }
    }
    ls += __shfl_xor(ls, 16); ls += __shfl_xor(ls, 32);
    lq += __shfl_xor(lq, 16); lq += __shfl_xor(lq, 32);
    if (q == 0){ cs[slot*64 + c_local] = ls; cq[slot*64 + c_local] = lq; }
  }
  __syncthreads();
  if (t < 64){
    atomicAdd(&bnacc[bn + t],        cs[t] + cs[64 + t]);
    atomicAdd(&bnacc[512 + bn + t],  cq[t] + cq[64 + t]);
  }
}

// ======================= head, re-parallelized =======================
__global__ __launch_bounds__(256) void k_head1p(const float* __restrict__ c1,
    const float* __restrict__ c2, const float* __restrict__ Wl1,
    float* __restrict__ t1p){
  __shared__ float wl[128][64];
  __shared__ float xgs[16][128];
  int b = blockIdx.x, t = threadIdx.x;
  int jt = b >> 3, kc = b & 7;
  int j0 = jt*64, k0 = kc*128;
  for (int i = t; i < 8192; i += 256){
    int k = i >> 6, j = i & 63;
    wl[k][j] = Wl1[(size_t)(k0 + k)*512 + j0 + j];
  }
  for (int i = t; i < 2048; i += 256){
    int g = i >> 7, k = i & 127;
    int idx = g*1024 + k0 + k;
    xgs[g][k] = c1[idx] + c2[idx];
  }
  __syncthreads();
  #pragma unroll
  for (int u = 0; u < 4; u++){
    int p = t + u*256;
    int g = p >> 6, j = p & 63;
    float acc = 0.f;
    #pragma unroll 8
    for (int k = 0; k < 128; k++)
      acc += xgs[g][k] * wl[k][j];
    t1p[(size_t)(kc*16 + g)*512 + j0 + j] = acc;
  }
}
__global__ __launch_bounds__(512) void k_head2p(const float* __restrict__ t1p,
    const float* __restrict__ bl1, const float* __restrict__ Wl2,
    const float* __restrict__ bl2, float* __restrict__ out){
  __shared__ float t1s[512];
  __shared__ float part[2][256];
  int g = blockIdx.x, t = threadIdx.x;
  float acc = bl1[t];
  #pragma unroll
  for (int kc = 0; kc < 8; kc++)
    acc += t1p[(size_t)(kc*16 + g)*512 + t];
  t1s[t] = fmaxf(acc, 0.f);
  __syncthreads();
  int c = t & 255, half = t >> 8;
  float a = 0.f;
  #pragma unroll 8
  for (int k = half*256; k < half*256 + 256; k++)
    a += t1s[k] * Wl2[(size_t)k*256 + c];
  part[half][c] = a;
  __syncthreads();
  if (half == 0)
    out[g*256 + c] = part[0][c] + part[1][c] + bl2[c];
}

extern "C" void kernel_launch(void* const* d_in, const int* in_sizes, int n_in,
                              void* d_out, int out_size, void* d_ws, size_t ws_size,
                              hipStream_t stream){
  const float* x   = (const float*)d_in[0];
  const int*   ei  = (const int*)d_in[1];
  const float* W1  = (const float*)d_in[2];
  const float* as1 = (const float*)d_in[3];
  const float* ad1 = (const float*)d_in[4];
  const float* bc1 = (const float*)d_in[5];
  const float* Wh1 = (const float*)d_in[6];
  const float* bh1 = (const float*)d_in[7];
  const float* g1  = (const float*)d_in[8];
  const float* be1 = (const float*)d_in[9];
  const float* p1  = (const float*)d_in[10];
  const float* W2  = (const float*)d_in[11];
  const float* as2 = (const float*)d_in[12];
  const float* ad2 = (const float*)d_in[13];
  const float* bc2 = (const float*)d_in[14];
  const float* Wh2 = (const float*)d_in[15];
  const float* bh2 = (const float*)d_in[16];
  const float* g2  = (const float*)d_in[17];
  const float* be2 = (const float*)d_in[18];
  const float* p2  = (const float*)d_in[19];
  const float* Wl1 = (const float*)d_in[20];
  const float* bl1 = (const float*)d_in[21];
  const float* Wl2 = (const float*)d_in[22];
  const float* bl2 = (const float*)d_in[23];
  float* out = (float*)d_out;

  const int* src0 = ei;
  const int* tgt0 = ei + E_EDGES;

  // ---- workspace layout ----
  bf16* Cc      = (bf16*)d_ws;                       // NN1*EMB
  bf16* xn1     = Cc + (size_t)NN1*EMB;              // NN2*EMB
  bf16* aggx2h  = xn1 + (size_t)NN2*EMB;             // NN2*F1
  bf16* M2Th    = aggx2h + (size_t)NN2*F1;           // EMB*F1
  bf16* M2Tl    = M2Th + (size_t)EMB*F1;             // EMB*F1
  float* holeA  = (float*)(M2Tl + (size_t)EMB*F1);   // hole (122880 floats)
  float* t1p    = holeA;                             // 8*16*512 = 65536 floats
  float* bnacc1 = holeA + 122880;                    // 1024
  float* bnacc  = bnacc1 + 1024;                     // 1024
  float* M1p    = bnacc + 1024;                      // 4*4608
  float* cvp    = M1p + 4*4608;                      // 16*512 (cvp2 = cvp + 8*512)
  float* was2   = cvp + 16*512;                      // 3*512
  float* wad2   = was2 + 3*512;                      // 3*512
  float* hole16 = wad2 + 3*512;                      // (old was1/wad1 slots)
  float* aso2   = hole16 + 32;                       // NN2*3
  float* ado2   = aso2 + (size_t)NN2*3;              // NN2*3
  float* tops   = ado2 + (size_t)NN2*3;              // NG*KP1
  float* cat1   = tops + NG*KP1;                     // 16*1024
  float* cat2   = cat1 + NG*1024;                    // 16*1024
  int* topi     = (int*)(cat2 + NG*1024);            // NG*KP1
  int* map      = topi + NG*KP1;                     // NN1
  int* cnt2     = map + NN1;                         // NN2
  int* off2     = cnt2 + NN2;                        // NN2+8
  int* cur2     = off2 + NN2 + 8;                    // NN2
  int* esrc2    = cur2 + NN2;                        // E+NN2 (+pad 137700)
  float* nump   = (float*)(esrc2 + 137700);          // 256*4608 (chunk partials)
  float* denp   = nump + (size_t)256*4608;           // 256*1536
  float* cvp2   = cvp + 8*512;

  // 1. mega precompute: init + watt2 + M1p/cvp + layer-1 edge softmax + gemm_s
  k_pre<<<666,256,0,stream>>>(W1,as1,ad1,Wh1,bc1,bh1, W2,as2,ad2,Wh2,bc2,bh2,
                              src0,tgt0,x,
                              M1p,cvp,was2,wad2,
                              bnacc1,cnt2,map,M2Th,M2Tl, denp,nump);
  // 2. h1 + chunk reduction + BN partials
  k_h1<<<NN1/32,256,0,stream>>>(nump,denp,M1p,cvp,Cc,bnacc1);
  // 3. fused score+sort (layer 1)
  k_scoresort<<<NG,512,0,stream>>>(Cc,bnacc1,NN1,g1,be1,p1,NP1,KP1,map,topi,tops,
                                   (float*)nullptr);
  // 4. gather + attention dots + count2
  k_gather_c2<<<NG*KP1+512,256,0,stream>>>(Cc,bnacc1,NN1,g1,be1,topi,tops,xn1,NP1,KP1,
      was2,wad2,aso2,ado2, src0,tgt0,map,cnt2,NG*KP1);
  // 5. poolA + scan2
  k_poolA_scan<<<65,1024,0,stream>>>(xn1,cat1,KP1, cnt2,off2,cur2);
  // 6. fill2
  k_fill2<<<(E_EDGES+NN2+255)/256,256,0,stream>>>(src0,tgt0,map,cur2,esrc2,E_EDGES,NN2);
  // 7. agg2
  k_agg2<<<NN2,256,0,stream>>>(xn1,aso2,ado2,off2,esrc2,aggx2h);
  // 8. big GEMM (XCD-swizzled, grid 56*8 with guard)
  k_gemm_mfma<<<448,256,0,stream>>>(aggx2h,M2Th,M2Tl,cvp2,Cc,bnacc,NN2,EMB,F1,52);
  // 9. fused score+sort+pool (layer 2) -> cat2 directly
  k_scoresort<<<NG,512,0,stream>>>(Cc,bnacc,NN2,g2,be2,p2,KP1,KP2,(int*)nullptr,
                                   (int*)nullptr,(float*)nullptr,cat2);
  // 10-11. head (re-parallelized, weight reads amortized over graphs)
  k_head1p<<<64,256,0,stream>>>(cat1,cat2,Wl1,t1p);
  k_head2p<<<NG,512,0,stream>>>(t1p,bl1,Wl2,bl2,out);
}

// Round 10
// 306.856 us; speedup vs baseline: 1.4790x; 1.0104x over previous
//
#include <hip/hip_runtime.h>
#include <hip/hip_bf16.h>
#include <math.h>

#define E_EDGES 131072
#define NN1 8192
#define NN2 6560          // 16*410
#define NG 16
#define NP1 512
#define KP1 410
#define KP2 205
#define F1 1536
#define EMB 512
#define MAXDEG 256

typedef __hip_bfloat16 bf16;
typedef __attribute__((ext_vector_type(8))) short short8;
typedef __attribute__((ext_vector_type(4))) float f32x4;
typedef __attribute__((ext_vector_type(4))) unsigned short us4;

__device__ inline float wred64(float v){
  #pragma unroll
  for (int o = 32; o; o >>= 1) v += __shfl_down(v, o);
  return v;
}
__device__ inline float b2f_raw(unsigned short u){
  return __uint_as_float((unsigned)u << 16);
}
union BFU { bf16 b; unsigned short u; };
__device__ inline unsigned short f2u(float v){ BFU x; x.b = __float2bfloat16(v); return x.u; }

__device__ __forceinline__ void gld16(const void* g, void* l){
  __builtin_amdgcn_global_load_lds(
      (const __attribute__((address_space(1))) void*)g,
      (__attribute__((address_space(3))) void*)l, 16, 0, 0);
}

__device__ inline void split_store(float v, bf16* __restrict__ ph, bf16* __restrict__ pl){
  bf16 hi = __float2bfloat16(v);
  *ph = hi;
  *pl = __float2bfloat16(v - __bfloat162float(hi));
}

// inline BN stats from raw sums
__device__ inline void bn_from_acc(const float* __restrict__ bnacc, int c, float fM,
                                   float& mean, float& inv){
  mean = bnacc[c] / fM;
  float var = fmaxf(bnacc[512+c]/fM - mean*mean, 0.f);
  inv = 1.f / sqrtf(var + 1e-5f);
}

// ======================= mega precompute (+ fused layer-1 segment softmax) =======================
// [0,24): M1 partials   [24,56): cvec partials   [56,152): watt2
// [152,218): init (bnacc zero / cnt2=1 / map=-1)
// [218,474): layer-1 edge chunks (16 graphs x 16 chunks, LDS-private, local watt1)
// [474,666): gemm_s 64x64 split-bf16 MFMA tiles (W2@Wh2 -> M2T split)
__global__ __launch_bounds__(256) void k_pre(
    const float* __restrict__ W1, const float* __restrict__ as1, const float* __restrict__ ad1,
    const float* __restrict__ Wh1, const float* __restrict__ bc1, const float* __restrict__ bh1,
    const float* __restrict__ W2, const float* __restrict__ as2, const float* __restrict__ ad2,
    const float* __restrict__ Wh2, const float* __restrict__ bc2, const float* __restrict__ bh2,
    const int* __restrict__ src0, const int* __restrict__ tgt0, const float* __restrict__ x,
    float* __restrict__ M1p, float* __restrict__ cvp,
    float* __restrict__ was2, float* __restrict__ wad2,
    float* __restrict__ Zb, int* __restrict__ cnt2, int* __restrict__ map,
    bf16* __restrict__ Th, bf16* __restrict__ Tl,
    float* __restrict__ denp, float* __restrict__ nump){
  int b = blockIdx.x, t = threadIdx.x;
  if (b < 24){                               // M1 partials
    int h = b / 8, rem = b % 8, jh = rem >> 2, kc = rem & 3;
    int j = jh*256 + t, c0 = kc*128;
    __shared__ float w1s[3][128];
    for (int i = t; i < 384; i += 256)
      w1s[i>>7][i&127] = W1[(i>>7)*1536 + h*512 + c0 + (i&127)];
    __syncthreads();
    const float* whc = Wh1 + (size_t)(h*512 + c0)*512 + j;
    float a0=0.f, a1=0.f, a2=0.f;
    #pragma unroll 8
    for (int c = 0; c < 128; c++){
      float v = whc[(size_t)c*512];
      a0 += w1s[0][c]*v; a1 += w1s[1][c]*v; a2 += w1s[2][c]*v;
    }
    float* dst = M1p + (size_t)kc*4608;
    dst[(h*3+0)*512 + j] = a0;
    dst[(h*3+1)*512 + j] = a1;
    dst[(h*3+2)*512 + j] = a2;
  } else if (b < 56){                        // cvec partials
    int b2 = b - 24;
    int which = b2 >> 4, rem = b2 & 15, jh = rem >> 3, kc = rem & 7;
    const float* bc = which ? bc2 : bc1;
    const float* Wh = which ? Wh2 : Wh1;
    const float* bh = which ? bh2 : bh1;
    int j = jh*256 + t, i0 = kc*192;
    float acc = (kc == 0) ? bh[j] : 0.f;
    #pragma unroll 8
    for (int i = 0; i < 192; i++)
      acc += bc[i0+i] * Wh[(size_t)(i0+i)*512 + j];
    cvp[(size_t)(which*8 + kc)*512 + j] = acc;
  } else if (b < 152){                       // watt2
    int b3 = b - 56;
    int y = b3 >> 4, et = b3 & 15;
    int kind = y / 3, h = y % 3;
    int w = t >> 6, lane = t & 63;
    const float* att = kind ? ad2 : as2;
    float a[8];
    #pragma unroll
    for (int u = 0; u < 8; u++) a[u] = att[h*512 + lane*8 + u];
    for (int r = w; r < 32; r += 4){
      int e = et*32 + r;
      const float4* row = (const float4*)(W2 + (size_t)e*1536 + h*512) + lane*2;
      float4 v0 = row[0], v1 = row[1];
      float d = v0.x*a[0]+v0.y*a[1]+v0.z*a[2]+v0.w*a[3]
              + v1.x*a[4]+v1.y*a[5]+v1.z*a[6]+v1.w*a[7];
      d = wred64(d);
      if (lane == 0) (kind ? wad2 : was2)[h*512 + e] = d;
    }
  } else if (b < 218){                       // init
    int i = (b - 152)*256 + t;
    if (i < 2048){ Zb[i] = 0.f; }                         // bnacc1|bnacc
    else if (i < 2048 + NN2){ cnt2[i - 2048] = 1; }
    else if (i < 2048 + NN2 + NN1){ map[i - 2048 - NN2] = -1; }
  } else if (b < 474){                       // layer-1 edge chunk (LDS-private)
    __shared__ float sww[18];                // [kind*9 + h*3 + f]
    __shared__ float lden[1536];
    __shared__ float lnum[4608];
    int wv_ = t >> 6, lane = t & 63;
    for (int combo = wv_*5; combo < wv_*5+5 && combo < 18; combo++){
      int kind = combo/9, rr = combo%9, h = rr/3, f = rr%3;
      const float* att = kind ? ad1 : as1;
      float s = 0.f;
      #pragma unroll
      for (int c = lane; c < 512; c += 64) s += W1[f*1536 + h*512 + c] * att[h*512 + c];
      s = wred64(s);
      if (lane == 0) sww[combo] = s;
    }
    for (int i = t; i < 1536; i += 256) lden[i] = 0.f;
    for (int i = t; i < 4608; i += 256) lnum[i] = 0.f;
    __syncthreads();
    int eb = b - 218;
    int g = eb >> 4, ch = eb & 15;
    int base = g*8192;
    int it0 = ch*544;                        // 16*544 = 8704 items (8192 edges + 512 self-loops)
    for (int k = t; k < 544; k += 256){
      int it = it0 + k;
      int s, tl;
      if (it < 8192){ s = src0[base+it]; tl = tgt0[base+it] & 511; }
      else { tl = it - 8192; s = g*512 + tl; }
      float xs0 = x[s*3], xs1 = x[s*3+1], xs2 = x[s*3+2];
      int tg = g*512 + tl;
      float xt0 = x[tg*3], xt1 = x[tg*3+1], xt2 = x[tg*3+2];
      #pragma unroll
      for (int h = 0; h < 3; h++){
        float v = xs0*sww[h*3]+xs1*sww[h*3+1]+xs2*sww[h*3+2]
                + xt0*sww[9+h*3]+xt1*sww[9+h*3+1]+xt2*sww[9+h*3+2];
        v = v > 0.f ? v : 0.2f*v;
        float pe = expf(v);                  // |v|<~1: max-subtraction cancels in ratio
        atomicAdd(&lden[tl*3 + h], pe);
        atomicAdd(&lnum[tl*9 + h*3 + 0], pe * xs0);
        atomicAdd(&lnum[tl*9 + h*3 + 1], pe * xs1);
        atomicAdd(&lnum[tl*9 + h*3 + 2], pe * xs2);
      }
    }
    __syncthreads();
    for (int i = t; i < 4608; i += 256) nump[(size_t)eb*4608 + i] = lnum[i];
    for (int i = t; i < 1536; i += 256) denp[(size_t)eb*1536 + i] = lden[i];
  } else {                                   // gemm_s tiles
    int bb = b - 474;
    int z = bb % 3; int rr = bb / 3; int by = rr >> 3, bx = rr & 7;
    const float* A = W2 + (size_t)z*512;            // row stride 1536
    const float* B = Wh2 + (size_t)z*512*512;       // row stride 512
    __shared__ __align__(16) short sAh[4096], sAl[4096], sBh[4096], sBl[4096];
    int w = t >> 6, lane = t & 63;
    int l16 = lane & 15, q = lane >> 4;
    int bm = by*64, bn = bx*64;
    int am  = t >> 2, akw = (t & 3)*16;
    int bnl = t & 63, bkq = (t >> 6)*16;
    f32x4 acc[4];
    #pragma unroll
    for (int nf = 0; nf < 4; nf++) acc[nf] = (f32x4){0.f,0.f,0.f,0.f};
    float va[16], vb[16];
    #define GS_LOAD(K0) do { \
      _Pragma("unroll") for (int u = 0; u < 4; u++){ \
        float4 v4 = *(const float4*)(A + (size_t)(bm+am)*1536 + (K0) + akw + u*4); \
        va[u*4]=v4.x; va[u*4+1]=v4.y; va[u*4+2]=v4.z; va[u*4+3]=v4.w; } \
      _Pragma("unroll") for (int u = 0; u < 16; u++) \
        vb[u] = B[(size_t)((K0) + bkq + u)*512 + bn + bnl]; \
    } while(0)
    GS_LOAD(0);
    for (int it = 0; it < 8; it++){
      #pragma unroll
      for (int hh = 0; hh < 2; hh++){
        short8 ah_, al_, bh_, bl_;
        #pragma unroll
        for (int jj = 0; jj < 8; jj++){
          float v = va[hh*8+jj];
          unsigned short hu = f2u(v);
          ah_[jj] = (short)hu; al_[jj] = (short)f2u(v - b2f_raw(hu));
          v = vb[hh*8+jj];
          hu = f2u(v);
          bh_[jj] = (short)hu; bl_[jj] = (short)f2u(v - b2f_raw(hu));
        }
        int aoff = am*64  + ((((akw>>3) + hh) ^ (am  & 7)) << 3);
        *(short8*)(sAh + aoff) = ah_;
        *(short8*)(sAl + aoff) = al_;
        int boff = bnl*64 + ((((bkq>>3) + hh) ^ (bnl & 7)) << 3);
        *(short8*)(sBh + boff) = bh_;
        *(short8*)(sBl + boff) = bl_;
      }
      __syncthreads();
      if (it < 7) GS_LOAD((it+1)*64);
      #pragma unroll
      for (int ks = 0; ks < 2; ks++){
        int gc = ks*4 + q;
        int ar = w*16 + l16;
        int ao = ar*64 + ((gc ^ (ar & 7)) << 3);
        short8 afh = *(const short8*)(sAh + ao);
        short8 afl = *(const short8*)(sAl + ao);
        #pragma unroll
        for (int nf = 0; nf < 4; nf++){
          int br = nf*16 + l16;
          int bo = br*64 + ((gc ^ (br & 7)) << 3);
          short8 bfh = *(const short8*)(sBh + bo);
          short8 bfl = *(const short8*)(sBl + bo);
          acc[nf] = __builtin_amdgcn_mfma_f32_16x16x32_bf16(afh, bfh, acc[nf], 0, 0, 0);
          acc[nf] = __builtin_amdgcn_mfma_f32_16x16x32_bf16(afh, bfl, acc[nf], 0, 0, 0);
          acc[nf] = __builtin_amdgcn_mfma_f32_16x16x32_bf16(afl, bfh, acc[nf], 0, 0, 0);
        }
      }
      __syncthreads();
    }
    #undef GS_LOAD
    int m0 = bm + w*16 + q*4;
    #pragma unroll
    for (int nf = 0; nf < 4; nf++){
      int n = bn + nf*16 + l16;
      size_t base = (size_t)n*1536 + (size_t)z*512 + m0;
      #pragma unroll
      for (int e = 0; e < 4; e++)
        split_store(acc[nf][e], &Th[base+e], &Tl[base+e]);
    }
  }
}

// h1[n,j] = relu(cvec[j] + sum_q (num/den)[n,q]*M1[q,j]) -> bf16 ; fused BN partials.
__global__ __launch_bounds__(256) void k_h1(
    const float* __restrict__ nump, const float* __restrict__ denp,
    const float* __restrict__ M1p, const float* __restrict__ cvp1, bf16* __restrict__ hout,
    float* __restrict__ bnacc1){
  __shared__ float sM[9*512];
  __shared__ float sC[512];
  __shared__ float sA[32*9];
  int t = threadIdx.x; int n0 = blockIdx.x*32;
  for (int i = t; i < 9*512; i += 256)
    sM[i] = M1p[i] + M1p[4608 + i] + M1p[2*4608 + i] + M1p[3*4608 + i];
  for (int i = t; i < 512; i += 256){
    float s = 0.f;
    #pragma unroll
    for (int kc = 0; kc < 8; kc++) s += cvp1[kc*512 + i];
    sC[i] = s;
  }
  for (int i = t; i < 288; i += 256){
    int node = i / 9, q = i % 9, hh = q / 3;
    int gn = n0 + node;
    int g = gn >> 9, nl = gn & 511;
    float ns = 0.f, ds = 0.f;
    #pragma unroll 4
    for (int ch = 0; ch < 16; ch++){
      ns += nump[(size_t)(g*16 + ch)*4608 + nl*9 + q];
      ds += denp[(size_t)(g*16 + ch)*1536 + nl*3 + hh];
    }
    sA[i] = ns / fmaxf(ds, 1e-16f);
  }
  __syncthreads();
  float c0v = sC[t], c1v = sC[t+256];
  float ls0=0.f, lq0=0.f, ls1=0.f, lq1=0.f;
  #pragma unroll 4
  for (int i = 0; i < 32; i++){
    float a0 = c0v, a1 = c1v;
    #pragma unroll
    for (int q = 0; q < 9; q++){
      float av = sA[i*9+q];
      a0 += av * sM[q*512 + t];
      a1 += av * sM[q*512 + t + 256];
    }
    a0 = fmaxf(a0, 0.f); a1 = fmaxf(a1, 0.f);
    hout[(size_t)(n0+i)*512 + t]       = __float2bfloat16(a0);
    hout[(size_t)(n0+i)*512 + t + 256] = __float2bfloat16(a1);
    ls0 += a0; lq0 += a0*a0; ls1 += a1; lq1 += a1*a1;
  }
  atomicAdd(&bnacc1[t],           ls0);
  atomicAdd(&bnacc1[t+256],       ls1);
  atomicAdd(&bnacc1[512 + t],     lq0);
  atomicAdd(&bnacc1[512 + t+256], lq1);
}

// ======================= chip-wide scoring =======================
// One block = 32 rows (4 waves x 8 rows); lane reads 8 contiguous bf16.
__global__ __launch_bounds__(256) void k_score(
    const bf16* __restrict__ h, const float* __restrict__ bnacc, int M,
    const float* __restrict__ g_, const float* __restrict__ be, const float* __restrict__ p,
    float* __restrict__ score, int NR){
  __shared__ float w[512];
  __shared__ float rb[4], rp[4];
  int t = threadIdx.x;
  int lane = t & 63, wv = t >> 6;
  float fM = (float)M;
  float bt = 0.f, pp = 0.f;
  #pragma unroll
  for (int k = 0; k < 2; k++){
    int c = t + k*256;
    float mean, inv; bn_from_acc(bnacc, c, fM, mean, inv);
    float gc = g_[c], pc = p[c];
    float ig = inv * gc;
    w[c] = ig * pc;
    bt += (be[c] - mean * ig) * pc;
    pp += pc * pc;
  }
  bt = wred64(bt); pp = wred64(pp);
  if (lane == 0){ rb[wv] = bt; rp[wv] = pp; }
  __syncthreads();
  float B0 = rb[0]+rb[1]+rb[2]+rb[3];
  float pn = sqrtf(rp[0]+rp[1]+rp[2]+rp[3]);
  float wl[8];
  #pragma unroll
  for (int u = 0; u < 8; u++) wl[u] = w[lane*8 + u];
  int rbase = blockIdx.x*32 + wv*8;
  for (int rr = 0; rr < 8; rr++){
    int r = rbase + rr;
    if (r >= NR) break;
    const unsigned short* hr = (const unsigned short*)h + (size_t)r*EMB + lane*8;
    us4 v0 = *(const us4*)(hr);
    us4 v1 = *(const us4*)(hr + 4);
    float dot = b2f_raw(v0.x)*wl[0] + b2f_raw(v0.y)*wl[1]
              + b2f_raw(v0.z)*wl[2] + b2f_raw(v0.w)*wl[3]
              + b2f_raw(v1.x)*wl[4] + b2f_raw(v1.y)*wl[5]
              + b2f_raw(v1.z)*wl[6] + b2f_raw(v1.w)*wl[7];
    dot = wred64(dot);
    if (lane == 0) score[r] = tanhf((dot + B0) / pn);
  }
}

// ======================= top-k sort (layer 1) =======================
__global__ __launch_bounds__(512) void k_sort1(
    const float* __restrict__ score, int n_per, int K,
    int* __restrict__ map, int* __restrict__ topi, float* __restrict__ tops){
  int g = blockIdx.x, t = threadIdx.x;
  __shared__ float sk[512];
  __shared__ int si[512];
  if (t < n_per){ sk[t] = score[g*n_per + t]; si[t] = t; }
  else { sk[t] = -INFINITY; si[t] = 0x7fffffff; }
  __syncthreads();
  for (int k = 2; k <= 512; k <<= 1){
    for (int j = k >> 1; j > 0; j >>= 1){
      int l = t ^ j;
      if (l > t){
        float ki = sk[t], kl = sk[l]; int ii = si[t], il = si[l];
        bool before_l = (kl > ki) || (kl == ki && il < ii);
        bool up = ((t & k) == 0);
        if (up == before_l){ sk[t]=kl; sk[l]=ki; si[t]=il; si[l]=ii; }
      }
      __syncthreads();
    }
  }
  if (t < K){
    map[g*n_per + si[t]] = g*K + t;
    topi[g*K + t] = si[t];
    tops[g*K + t] = sk[t];
  }
}

// ======================= top-k sort + fused gather/BN/pool (layer 2) =======================
__global__ __launch_bounds__(512) void k_sortpool2(
    const bf16* __restrict__ h, const float* __restrict__ score,
    const float* __restrict__ bnacc, int M,
    const float* __restrict__ g_, const float* __restrict__ be,
    int n_per, int K, float* __restrict__ cat){
  int g = blockIdx.x, t = threadIdx.x;
  __shared__ float sk[512];
  __shared__ int si[512];
  if (t < n_per){ sk[t] = score[g*n_per + t]; si[t] = t; }
  else { sk[t] = -INFINITY; si[t] = 0x7fffffff; }
  __syncthreads();
  for (int k = 2; k <= 512; k <<= 1){
    for (int j = k >> 1; j > 0; j >>= 1){
      int l = t ^ j;
      if (l > t){
        float ki = sk[t], kl = sk[l]; int ii = si[t], il = si[l];
        bool before_l = (kl > ki) || (kl == ki && il < ii);
        bool up = ((t & k) == 0);
        if (up == before_l){ sk[t]=kl; sk[l]=ki; si[t]=il; si[l]=ii; }
      }
      __syncthreads();
    }
  }
  float fM = (float)M;
  float mean, inv; bn_from_acc(bnacc, t, fM, mean, inv);
  float ig = inv * g_[t], bec = be[t];
  const unsigned short* hp = (const unsigned short*)h;
  float mx = -INFINITY, sm = 0.f;
  for (int r = 0; r < K; r++){
    float v = (b2f_raw(hp[(size_t)(g*n_per + si[r])*EMB + t]) - mean) * ig + bec;
    v *= sk[r];
    mx = fmaxf(mx, v); sm += v;
  }
  cat[g*1024 + t] = mx;
  cat[g*1024 + 512 + t] = sm / (float)K;
}

// gather + inline BN + scale -> bf16; fused layer-2 attention dots; fused count2 tail
__global__ __launch_bounds__(256) void k_gather_c2(
    const bf16* __restrict__ h, const float* __restrict__ bnacc, int M,
    const float* __restrict__ gm, const float* __restrict__ be,
    const int* __restrict__ topi, const float* __restrict__ tops,
    bf16* __restrict__ xn, int n_per, int K,
    const float* __restrict__ was2, const float* __restrict__ wad2,
    float* __restrict__ aso, float* __restrict__ ado,
    const int* __restrict__ src0, const int* __restrict__ tgt0,
    const int* __restrict__ map, int* __restrict__ cnt2, int nblk_g){
  int row = blockIdx.x, t = threadIdx.x;
  if (row >= nblk_g){                      // count2 tail
    int i = (row - nblk_g)*256 + t;
    if (i < E_EDGES){
      int s = map[src0[i]], tg = map[tgt0[i]];
      if (s >= 0 && tg >= 0) atomicAdd(&cnt2[tg], 1);
    }
    return;
  }
  int gr = row / K, i = row - gr*K;
  int sidx = topi[gr*K + i];
  float s = tops[gr*K + i];
  const bf16* src = h + ((size_t)(gr*n_per + sidx))*EMB;
  bf16* dst = xn + (size_t)row*EMB;
  int c0 = t, c1 = t + 256;
  float fM = (float)M;
  float mean0, inv0, mean1, inv1;
  bn_from_acc(bnacc, c0, fM, mean0, inv0);
  bn_from_acc(bnacc, c1, fM, mean1, inv1);
  float v0 = ((__bfloat162float(src[c0]) - mean0) * inv0 * gm[c0] + be[c0]) * s;
  float v1 = ((__bfloat162float(src[c1]) - mean1) * inv1 * gm[c1] + be[c1]) * s;
  dst[c0] = __float2bfloat16(v0);
  dst[c1] = __float2bfloat16(v1);
  {
    float a[6];
    #pragma unroll
    for (int hh = 0; hh < 3; hh++){
      a[hh]   = v0*was2[hh*512 + c0] + v1*was2[hh*512 + c1];
      a[3+hh] = v0*wad2[hh*512 + c0] + v1*wad2[hh*512 + c1];
    }
    __shared__ float red[6][4];
    int lane = t & 63, wv = t >> 6;
    #pragma unroll
    for (int q = 0; q < 6; q++){ float v = wred64(a[q]); if (lane==0) red[q][wv]=v; }
    __syncthreads();
    if (t < 6){
      float sm = red[t][0]+red[t][1]+red[t][2]+red[t][3];
      if (t < 3) aso[row*3+t] = sm; else ado[row*3+(t-3)] = sm;
    }
  }
}

// ======================= CSR (layer 2) =======================
__device__ inline void scan_body(const int* __restrict__ counts, int* __restrict__ off,
                                 int* __restrict__ cur, int n, int* __restrict__ sh){
  int t = threadIdx.x;
  int chunk = (n + 1023) >> 10;
  int b = t * chunk; int e = b + chunk; if (e > n) e = n;
  int s = 0;
  for (int i = b; i < e; i++) s += counts[i];
  sh[t] = s; __syncthreads();
  for (int o = 1; o < 1024; o <<= 1){
    int v = (t >= o) ? sh[t-o] : 0;
    __syncthreads();
    sh[t] += v;
    __syncthreads();
  }
  int run = (t > 0) ? sh[t-1] : 0;
  for (int i = b; i < e; i++){ int c = counts[i]; off[i] = run; cur[i] = run; run += c; }
  if (t == 1023) off[n] = sh[1023];
}
__global__ void k_fill2(const int* __restrict__ src0, const int* __restrict__ tgt0,
                        const int* __restrict__ map, int* __restrict__ cur,
                        int* __restrict__ esrc, int E, int nn){
  int i = blockIdx.x*blockDim.x + threadIdx.x;
  if (i >= E + nn) return;
  int s, tg;
  if (i < E){
    s = map[src0[i]]; tg = map[tgt0[i]];
    if (s < 0 || tg < 0) return;
  } else { s = i - E; tg = s; }
  int pos = atomicAdd(&cur[tg], 1);
  esrc[pos] = s;
}

// ======================= pooling (layer 1) =======================
// blocks [0,64): poolA over xn1; block 64: scan(cnt2)
__global__ __launch_bounds__(1024) void k_poolA_scan(const bf16* __restrict__ xn,
    float* __restrict__ cat, int K,
    const int* __restrict__ cnt2, int* __restrict__ off2, int* __restrict__ cur2){
  __shared__ int shi[1024];
  __shared__ float smax[8][128];
  __shared__ float ssum[8][128];
  int b = blockIdx.x, t = threadIdx.x;
  if (b == 64){ scan_body(cnt2, off2, cur2, NN2, shi); return; }
  int g = b >> 2, cb = b & 3;
  int c = t & 127, rg = t >> 7;
  int col = cb*128 + c;
  const unsigned short* p = (const unsigned short*)xn + (size_t)g*K*EMB + col;
  float mx = -INFINITY, sm = 0.f;
  for (int r = rg; r < K; r += 8){
    float v = b2f_raw(p[(size_t)r*EMB]);
    mx = fmaxf(mx, v); sm += v;
  }
  smax[rg][c] = mx; ssum[rg][c] = sm;
  __syncthreads();
  if (rg == 0){
    #pragma unroll
    for (int u = 1; u < 8; u++){ mx = fmaxf(mx, smax[u][c]); sm += ssum[u][c]; }
    cat[g*1024 + col] = mx;
    cat[g*1024 + 512 + col] = sm / (float)K;
  }
}

// ======================= layer 2 aggregation =======================
__global__ __launch_bounds__(256) void k_agg2(
    const bf16* __restrict__ xn, const float* __restrict__ aso, const float* __restrict__ ado,
    const int* __restrict__ off, const int* __restrict__ esrc,
    bf16* __restrict__ oh){
  int n = blockIdx.x, t = threadIdx.x;
  __shared__ int srcs[MAXDEG];
  __shared__ float al[MAXDEG*3];
  __shared__ float mh[3], dh[3];
  int s0 = off[n]; int deg = off[n+1] - s0; if (deg > MAXDEG) deg = MAXDEG;
  for (int e = t; e < deg; e += 256) srcs[e] = esrc[s0 + e];
  __syncthreads();
  float ad0 = ado[n*3+0], ad1 = ado[n*3+1], ad2 = ado[n*3+2];
  for (int e = t; e < deg; e += 256){
    int s = srcs[e];
    float v0 = aso[s*3+0] + ad0, v1 = aso[s*3+1] + ad1, v2 = aso[s*3+2] + ad2;
    al[e*3+0] = v0 > 0.f ? v0 : 0.2f*v0;
    al[e*3+1] = v1 > 0.f ? v1 : 0.2f*v1;
    al[e*3+2] = v2 > 0.f ? v2 : 0.2f*v2;
  }
  __syncthreads();
  if (t < 3){
    float m = -INFINITY;
    for (int e = 0; e < deg; e++) m = fmaxf(m, al[e*3+t]);
    float d = 0.f;
    for (int e = 0; e < deg; e++) d += expf(al[e*3+t] - m);
    mh[t] = m; dh[t] = 1.f / fmaxf(d, 1e-16f);
  }
  __syncthreads();
  for (int e = t; e < deg; e += 256){
    al[e*3+0] = expf(al[e*3+0]-mh[0])*dh[0];
    al[e*3+1] = expf(al[e*3+1]-mh[1])*dh[1];
    al[e*3+2] = expf(al[e*3+2]-mh[2])*dh[2];
  }
  __syncthreads();
  float acc[2][3] = {};
  for (int e = 0; e < deg; e++){
    int s = srcs[e];
    float a0 = al[e*3], a1 = al[e*3+1], a2 = al[e*3+2];
    #pragma unroll
    for (int k = 0; k < 2; k++){
      float v = __bfloat162float(xn[(size_t)s*512 + t + k*256]);
      acc[k][0] += a0*v; acc[k][1] += a1*v; acc[k][2] += a2*v;
    }
  }
  #pragma unroll
  for (int k = 0; k < 2; k++){
    int c = t + k*256;
    #pragma unroll
    for (int h = 0; h < 3; h++)
      oh[(size_t)n*1536 + h*512 + c] = __float2bfloat16(acc[k][h]);
  }
}

// ======================= bf16-A x split-bf16-B MFMA GEMM (XCD-swizzled) =======================
__global__ __launch_bounds__(256, 2) void k_gemm_mfma(
    const bf16* __restrict__ Ah,
    const bf16* __restrict__ Bh, const bf16* __restrict__ Bl,   // [N][K] row-major
    const float* __restrict__ bias, bf16* __restrict__ C,
    float* __restrict__ bnacc,
    int M, int N, int K, int Mtiles){
  int xcd = (int)blockIdx.x & 7;
  int ii  = (int)blockIdx.x >> 3;
  int bni = ii & 7;
  int bmi = xcd + 8*(ii >> 3);
  if (bmi >= Mtiles) return;
  __shared__ __align__(16) unsigned short lds[2][16384];   // 64 KB total
  int t = threadIdx.x, w = t >> 6, lane = t & 63;
  int q = lane >> 4, l16 = lane & 15;
  int bm = bmi * 128, bn = bni * 64;

  int lr = lane >> 3, lc = lane & 7;
  int kg = ((lc ^ lr) & 7) * 8;
  int ro = w*8 + lr;
  int m0 = bm + ro, m1 = bm + 32 + ro, m2 = bm + 64 + ro, m3 = bm + 96 + ro;
  if (m0 >= M) m0 = M-1;  if (m1 >= M) m1 = M-1;
  if (m2 >= M) m2 = M-1;  if (m3 >= M) m3 = M-1;
  int n0 = bn + ro, n1 = bn + 32 + ro;
  const bf16* ptr[8];
  ptr[0] = Ah + (size_t)m0*K + kg;
  ptr[1] = Ah + (size_t)m1*K + kg;
  ptr[2] = Ah + (size_t)m2*K + kg;
  ptr[3] = Ah + (size_t)m3*K + kg;
  ptr[4] = Bh + (size_t)n0*K + kg;
  ptr[5] = Bh + (size_t)n1*K + kg;
  ptr[6] = Bl + (size_t)n0*K + kg;
  ptr[7] = Bl + (size_t)n1*K + kg;
  const int dof[8] = {0, 2048, 4096, 6144, 8192, 10240, 12288, 14336};

  int wm = (w >> 1) * 64, wn = (w & 1) * 32;
  f32x4 acc[4][2];
  #pragma unroll
  for (int i = 0; i < 4; i++)
    #pragma unroll
    for (int j = 0; j < 2; j++)
      acc[i][j] = (f32x4){0.f, 0.f, 0.f, 0.f};

  #pragma unroll
  for (int u = 0; u < 8; u++){
    gld16(ptr[u], &lds[0][dof[u] + w*512]);
    ptr[u] += 64;
  }

  int nit = K >> 6;
  for (int it = 0; it < nit; it++){
    __syncthreads();
    int cur = it & 1;
    if (it + 1 < nit){
      int nxt = cur ^ 1;
      #pragma unroll
      for (int u = 0; u < 8; u++){
        gld16(ptr[u], &lds[nxt][dof[u] + w*512]);
        ptr[u] += 64;
      }
    }
    const unsigned short* L = lds[cur];
    #pragma unroll
    for (int ks = 0; ks < 2; ks++){
      short8 ah[4], bh2[2], bl2[2];
      int gc = ks*4 + q;
      #pragma unroll
      for (int i = 0; i < 4; i++){
        int r = wm + i*16 + l16;
        ah[i] = *(const short8*)(L + r*64 + ((gc ^ (r & 7)) << 3));
      }
      #pragma unroll
      for (int j = 0; j < 2; j++){
        int r = wn + j*16 + l16;
        int so = ((gc ^ (r & 7)) << 3);
        bh2[j] = *(const short8*)(L + 8192  + r*64 + so);
        bl2[j] = *(const short8*)(L + 12288 + r*64 + so);
      }
      #pragma unroll
      for (int i = 0; i < 4; i++)
        #pragma unroll
        for (int j = 0; j < 2; j++){
          acc[i][j] = __builtin_amdgcn_mfma_f32_16x16x32_bf16(ah[i], bh2[j], acc[i][j], 0, 0, 0);
          acc[i][j] = __builtin_amdgcn_mfma_f32_16x16x32_bf16(ah[i], bl2[j], acc[i][j], 0, 0, 0);
        }
    }
  }

  __syncthreads();
  float* cs = (float*)&lds[0][0];
  float* cq = cs + 128;
  int slot = w >> 1;
  #pragma unroll
  for (int j = 0; j < 2; j++){
    int c_local = wn + j*16 + l16;
    int c = bn + c_local;
    float bv = 0.f;
    if (bias){
      #pragma unroll
      for (int kc = 0; kc < 8; kc++) bv += bias[kc*512 + c];
    }
    float ls = 0.f, lq = 0.f;
    #pragma unroll
    for (int i = 0; i < 4; i++){
      int rb = bm + wm + i*16 + q*4;
      #pragma unroll
      for (int e = 0; e < 4; e++){
        int r = rb + e;
        if (r < M){
          float v = fmaxf(acc[i][j][e] + bv, 0.f);
          C[(size_t)r*N + c] = __float2bfloat16(v);
          ls += v; lq += v*v;
        }
      }
    }
    ls += __shfl_xor(ls, 16); ls += __shfl_xor(ls, 32);
    lq += __shfl_xor(lq, 16); lq += __shfl_xor(lq, 32);
    if (q == 0){ cs[slot*64 + c_local] = ls; cq[slot*64 + c_local] = lq; }
  }
  __syncthreads();
  if (t < 64){
    atomicAdd(&bnacc[bn + t],        cs[t] + cs[64 + t]);
    atomicAdd(&bnacc[512 + bn + t],  cq[t] + cq[64 + t]);
  }
}

// ======================= head, re-parallelized =======================
__global__ __launch_bounds__(256) void k_head1p(const float* __restrict__ c1,
    const float* __restrict__ c2, const float* __restrict__ Wl1,
    float* __restrict__ t1p){
  __shared__ float wl[128][64];
  __shared__ float xgs[16][128];
  int b = blockIdx.x, t = threadIdx.x;
  int jt = b >> 3, kc = b & 7;
  int j0 = jt*64, k0 = kc*128;
  for (int i = t; i < 8192; i += 256){
    int k = i >> 6, j = i & 63;
    wl[k][j] = Wl1[(size_t)(k0 + k)*512 + j0 + j];
  }
  for (int i = t; i < 2048; i += 256){
    int g = i >> 7, k = i & 127;
    int idx = g*1024 + k0 + k;
    xgs[g][k] = c1[idx] + c2[idx];
  }
  __syncthreads();
  #pragma unroll
  for (int u = 0; u < 4; u++){
    int p = t + u*256;
    int g = p >> 6, j = p & 63;
    float acc = 0.f;
    #pragma unroll 8
    for (int k = 0; k < 128; k++)
      acc += xgs[g][k] * wl[k][j];
    t1p[(size_t)(kc*16 + g)*512 + j0 + j] = acc;
  }
}
__global__ __launch_bounds__(512) void k_head2p(const float* __restrict__ t1p,
    const float* __restrict__ bl1, const float* __restrict__ Wl2,
    const float* __restrict__ bl2, float* __restrict__ out){
  __shared__ float t1s[512];
  __shared__ float part[2][256];
  int g = blockIdx.x, t = threadIdx.x;
  float acc = bl1[t];
  #pragma unroll
  for (int kc = 0; kc < 8; kc++)
    acc += t1p[(size_t)(kc*16 + g)*512 + t];
  t1s[t] = fmaxf(acc, 0.f);
  __syncthreads();
  int c = t & 255, half = t >> 8;
  float a = 0.f;
  #pragma unroll 8
  for (int k = half*256; k < half*256 + 256; k++)
    a += t1s[k] * Wl2[(size_t)k*256 + c];
  part[half][c] = a;
  __syncthreads();
  if (half == 0)
    out[g*256 + c] = part[0][c] + part[1][c] + bl2[c];
}

extern "C" void kernel_launch(void* const* d_in, const int* in_sizes, int n_in,
                              void* d_out, int out_size, void* d_ws, size_t ws_size,
                              hipStream_t stream){
  const float* x   = (const float*)d_in[0];
  const int*   ei  = (const int*)d_in[1];
  const float* W1  = (const float*)d_in[2];
  const float* as1 = (const float*)d_in[3];
  const float* ad1 = (const float*)d_in[4];
  const float* bc1 = (const float*)d_in[5];
  const float* Wh1 = (const float*)d_in[6];
  const float* bh1 = (const float*)d_in[7];
  const float* g1  = (const float*)d_in[8];
  const float* be1 = (const float*)d_in[9];
  const float* p1  = (const float*)d_in[10];
  const float* W2  = (const float*)d_in[11];
  const float* as2 = (const float*)d_in[12];
  const float* ad2 = (const float*)d_in[13];
  const float* bc2 = (const float*)d_in[14];
  const float* Wh2 = (const float*)d_in[15];
  const float* bh2 = (const float*)d_in[16];
  const float* g2  = (const float*)d_in[17];
  const float* be2 = (const float*)d_in[18];
  const float* p2  = (const float*)d_in[19];
  const float* Wl1 = (const float*)d_in[20];
  const float* bl1 = (const float*)d_in[21];
  const float* Wl2 = (const float*)d_in[22];
  const float* bl2 = (const float*)d_in[23];
  float* out = (float*)d_out;

  const int* src0 = ei;
  const int* tgt0 = ei + E_EDGES;

  // ---- workspace layout ----
  bf16* Cc      = (bf16*)d_ws;                       // NN1*EMB
  bf16* xn1     = Cc + (size_t)NN1*EMB;              // NN2*EMB
  bf16* aggx2h  = xn1 + (size_t)NN2*EMB;             // NN2*F1
  bf16* M2Th    = aggx2h + (size_t)NN2*F1;           // EMB*F1
  bf16* M2Tl    = M2Th + (size_t)EMB*F1;             // EMB*F1
  float* holeA  = (float*)(M2Tl + (size_t)EMB*F1);   // hole (122880 floats)
  float* t1p    = holeA;                             // 65536 floats
  float* score  = holeA + 65536;                     // 8192 floats
  float* bnacc1 = holeA + 122880;                    // 1024
  float* bnacc  = bnacc1 + 1024;                     // 1024
  float* M1p    = bnacc + 1024;                      // 4*4608
  float* cvp    = M1p + 4*4608;                      // 16*512 (cvp2 = cvp + 8*512)
  float* was2   = cvp + 16*512;                      // 3*512
  float* wad2   = was2 + 3*512;                      // 3*512
  float* hole16 = wad2 + 3*512;                      // (old was1/wad1 slots)
  float* aso2   = hole16 + 32;                       // NN2*3
  float* ado2   = aso2 + (size_t)NN2*3;              // NN2*3
  float* tops   = ado2 + (size_t)NN2*3;              // NG*KP1
  float* cat1   = tops + NG*KP1;                     // 16*1024
  float* cat2   = cat1 + NG*1024;                    // 16*1024
  int* topi     = (int*)(cat2 + NG*1024);            // NG*KP1
  int* map      = topi + NG*KP1;                     // NN1
  int* cnt2     = map + NN1;                         // NN2
  int* off2     = cnt2 + NN2;                        // NN2+8
  int* cur2     = off2 + NN2 + 8;                    // NN2
  int* esrc2    = cur2 + NN2;                        // E+NN2 (+pad 137700)
  float* nump   = (float*)(esrc2 + 137700);          // 256*4608 (chunk partials)
  float* denp   = nump + (size_t)256*4608;           // 256*1536
  float* cvp2   = cvp + 8*512;

  // 1. mega precompute: init + watt2 + M1p/cvp + layer-1 edge softmax + gemm_s
  k_pre<<<666,256,0,stream>>>(W1,as1,ad1,Wh1,bc1,bh1, W2,as2,ad2,Wh2,bc2,bh2,
                              src0,tgt0,x,
                              M1p,cvp,was2,wad2,
                              bnacc1,cnt2,map,M2Th,M2Tl, denp,nump);
  // 2. h1 + chunk reduction + BN partials
  k_h1<<<NN1/32,256,0,stream>>>(nump,denp,M1p,cvp,Cc,bnacc1);
  // 3. chip-wide scoring (layer 1)
  k_score<<<NN1/32,256,0,stream>>>(Cc,bnacc1,NN1,g1,be1,p1,score,NN1);
  // 4. top-k sort (layer 1)
  k_sort1<<<NG,512,0,stream>>>(score,NP1,KP1,map,topi,tops);
  // 5. gather + attention dots + count2
  k_gather_c2<<<NG*KP1+512,256,0,stream>>>(Cc,bnacc1,NN1,g1,be1,topi,tops,xn1,NP1,KP1,
      was2,wad2,aso2,ado2, src0,tgt0,map,cnt2,NG*KP1);
  // 6. poolA + scan2
  k_poolA_scan<<<65,1024,0,stream>>>(xn1,cat1,KP1, cnt2,off2,cur2);
  // 7. fill2
  k_fill2<<<(E_EDGES+NN2+255)/256,256,0,stream>>>(src0,tgt0,map,cur2,esrc2,E_EDGES,NN2);
  // 8. agg2
  k_agg2<<<NN2,256,0,stream>>>(xn1,aso2,ado2,off2,esrc2,aggx2h);
  // 9. big GEMM (XCD-swizzled, grid 56*8 with guard)
  k_gemm_mfma<<<448,256,0,stream>>>(aggx2h,M2Th,M2Tl,cvp2,Cc,bnacc,NN2,EMB,F1,52);
  // 10. chip-wide scoring (layer 2)
  k_score<<<(NN2+31)/32,256,0,stream>>>(Cc,bnacc,NN2,g2,be2,p2,score,NN2);
  // 11. top-k sort + fused gather/BN/pool (layer 2) -> cat2
  k_sortpool2<<<NG,512,0,stream>>>(Cc,score,bnacc,NN2,g2,be2,KP1,KP2,cat2);
  // 12-13. head
  k_head1p<<<64,256,0,stream>>>(cat1,cat2,Wl1,t1p);
  k_head2p<<<NG,512,0,stream>>>(t1p,bl1,Wl2,bl2,out);
}